// Round 9
// baseline (569.531 us; speedup 1.0000x reference)
//
#include <hip/hip_runtime.h>
#include <math.h>

#define N_NODES 50000
#define N_EDGES 800000
#define IN_DIM 128
#define HID 256
#define NCLASS 40

#define SCAN_NBLK 49   // ceil(50000 / 1024)

// ---------- bf16 helpers (RNE pack, cheap unpack) ----------
__device__ inline unsigned bf16pair(float a, float b) {
    unsigned ua = __float_as_uint(a), ub = __float_as_uint(b);
    ua = (ua + 0x7fffu + ((ua >> 16) & 1u)) >> 16;
    ub = (ub + 0x7fffu + ((ub >> 16) & 1u)) >> 16;
    return ua | (ub << 16);
}
__device__ inline float bf_lo(unsigned u) { return __uint_as_float(u << 16); }
__device__ inline float bf_hi(unsigned u) { return __uint_as_float(u & 0xffff0000u); }

// ---------------- convert feats -> bf16 (packed) ----------------
__global__ void to_bf16_kernel(const float4* __restrict__ f4,
                               uint2* __restrict__ o) {
    int i = blockIdx.x * blockDim.x + threadIdx.x;   // 1.6M float4s
    float4 v = f4[i];
    o[i] = make_uint2(bf16pair(v.x, v.y), bf16pair(v.z, v.w));
}

// ---------------- CSR build: count ----------------
__global__ void count_kernel(const int* __restrict__ rows,
                             int* __restrict__ counts) {
    int e = blockIdx.x * blockDim.x + threadIdx.x;
    if (e < N_EDGES) atomicAdd(&counts[rows[e]], 1);
}

// ---------------- hierarchical scan, phase 1: per-block sums ----------------
__global__ void block_sum_kernel(const int* __restrict__ counts,
                                 int* __restrict__ blockSums) {
    int t = threadIdx.x;
    int base = blockIdx.x * 1024 + t * 4;
    int s = 0;
    if (base < N_NODES) {
        int4 c = *(const int4*)(counts + base);
        s = c.x + c.y + c.z + c.w;
    }
    #pragma unroll
    for (int off = 32; off >= 1; off >>= 1)
        s += __shfl_xor(s, off);
    __shared__ int wsum[4];
    int lane = t & 63, wid = t >> 6;
    if (lane == 0) wsum[wid] = s;
    __syncthreads();
    if (t == 0)
        blockSums[blockIdx.x] = wsum[0] + wsum[1] + wsum[2] + wsum[3];
}

// ---------------- phase 2: scan the 49 block sums (single wave) ----------------
__global__ void block_offset_kernel(const int* __restrict__ blockSums,
                                    int* __restrict__ blockOffs,
                                    int* __restrict__ row_start) {
    int lane = threadIdx.x;          // 64 threads
    int x = (lane < SCAN_NBLK) ? blockSums[lane] : 0;
    #pragma unroll
    for (int off = 1; off < 64; off <<= 1) {
        int y = __shfl_up(x, off);
        if (lane >= off) x += y;
    }
    int excl = __shfl_up(x, 1);
    if (lane == 0) excl = 0;
    if (lane < SCAN_NBLK) blockOffs[lane] = excl;
    if (lane == SCAN_NBLK - 1) row_start[N_NODES] = x;   // grand total
}

// ---------------- phase 3: local scan + block offset -> row_start, cursor ----------------
__global__ void local_scan_kernel(const int* __restrict__ counts,
                                  const int* __restrict__ blockOffs,
                                  int* __restrict__ row_start,
                                  int* __restrict__ cursor) {
    int t = threadIdx.x;
    int base = blockIdx.x * 1024 + t * 4;
    int4 c = make_int4(0, 0, 0, 0);
    if (base < N_NODES) c = *(const int4*)(counts + base);
    int s0 = c.x, s1 = s0 + c.y, s2 = s1 + c.z, s3 = s2 + c.w;
    int tsum = s3;
    int lane = t & 63, wid = t >> 6;
    int x = tsum;
    #pragma unroll
    for (int off = 1; off < 64; off <<= 1) {
        int y = __shfl_up(x, off);
        if (lane >= off) x += y;
    }
    __shared__ int wsum[4];
    if (lane == 63) wsum[wid] = x;
    __syncthreads();
    int woff = 0;
    for (int i = 0; i < 4; ++i)
        if (i < wid) woff += wsum[i];
    int excl = x - tsum + woff + blockOffs[blockIdx.x];
    if (base < N_NODES) {
        int4 rs = make_int4(excl, excl + s0, excl + s1, excl + s2);
        *(int4*)(row_start + base) = rs;
        *(int4*)(cursor + base) = rs;
    }
}

// ---------------- CSR build: scatter (interleaved col+val, single 8B store) ----------------
__global__ void scatter_kernel(const int* __restrict__ rows,
                               const int* __restrict__ cols,
                               const float* __restrict__ vals,
                               int* __restrict__ cursor,
                               int2* __restrict__ csr_cv) {
    int e = blockIdx.x * blockDim.x + threadIdx.x;
    if (e >= N_EDGES) return;
    int pos = atomicAdd(&cursor[rows[e]], 1);
    csr_cv[pos] = make_int2(cols[e], __float_as_int(vals[e]));
}

// ---------------- SpMM (CSR, bf16 gather, fp32 accumulate) ----------------
// MODE 0: Hout_b[r] = bf16(acc)                         (hop 2)
// MODE 1: Hout_b[r] = bf16(0.5*acc)                     (hop 1, folds input scale)
// MODE 2: Yout[r]   = 0.5*feats[r] + h1[r] + h2[r] + acc (hop 3, fp32 combine)
template <int MODE>
__global__ void spmm_csr(const int* __restrict__ row_start,
                         const int2* __restrict__ csr_cv,
                         const uint2* __restrict__ Hin_b,
                         uint2* __restrict__ Hout_b,
                         float* __restrict__ Yout,
                         const float* __restrict__ feats,
                         const uint2* __restrict__ h1b,
                         const uint2* __restrict__ h2b) {
    int wave = (blockIdx.x * blockDim.x + threadIdx.x) >> 6;
    int lane = threadIdx.x & 63;
    if (wave >= N_NODES) return;
    int p = lane >> 5;          // which edge of the pair
    int q = lane & 31;          // dim group (4 dims)
    int start = row_start[wave];
    int end   = row_start[wave + 1];
    float4 acc = make_float4(0.f, 0.f, 0.f, 0.f);
    for (int base = start; base < end; base += 64) {
        int idx = base + lane;
        int c = 0; float v = 0.f;
        if (idx < end) {
            int2 cv = csr_cv[idx];
            c = cv.x;
            v = __int_as_float(cv.y);
        }
        int cnt = min(64, end - base);
        for (int j = 0; j < cnt; j += 2) {
            int src = j + p;                   // v==0 beyond cnt
            int   cj = __shfl(c, src);
            float vj = __shfl(v, src);
            uint2 h = Hin_b[(size_t)cj * 32 + q];   // 4 bf16 = 8 B
            acc.x += vj * bf_lo(h.x);
            acc.y += vj * bf_hi(h.x);
            acc.z += vj * bf_lo(h.y);
            acc.w += vj * bf_hi(h.y);
        }
    }
    acc.x += __shfl_xor(acc.x, 32);
    acc.y += __shfl_xor(acc.y, 32);
    acc.z += __shfl_xor(acc.z, 32);
    acc.w += __shfl_xor(acc.w, 32);
    if (p == 0) {
        size_t o32 = (size_t)wave * 32 + q;
        if (MODE == 1) {
            acc.x *= 0.5f; acc.y *= 0.5f; acc.z *= 0.5f; acc.w *= 0.5f;
            Hout_b[o32] = make_uint2(bf16pair(acc.x, acc.y), bf16pair(acc.z, acc.w));
        } else if (MODE == 0) {
            Hout_b[o32] = make_uint2(bf16pair(acc.x, acc.y), bf16pair(acc.z, acc.w));
        } else {
            size_t o = (size_t)wave * IN_DIM + q * 4;
            float4 f = *(const float4*)(feats + o);
            uint2 a = h1b[o32];
            uint2 b = h2b[o32];
            acc.x += 0.5f * f.x + bf_lo(a.x) + bf_lo(b.x);
            acc.y += 0.5f * f.y + bf_hi(a.x) + bf_hi(b.x);
            acc.z += 0.5f * f.z + bf_lo(a.y) + bf_lo(b.y);
            acc.w += 0.5f * f.w + bf_hi(a.y) + bf_hi(b.y);
            *(float4*)(Yout + o) = acc;
        }
    }
}

// ---------------- GEMM1: H1b = bf16(relu((y*0.25) @ W1 + b1)) ----------------
// 128x128 tile, 8x8 per thread, BK=16. Bs chunk-swizzled (2-way max conflicts).
// Swizzle: 8-float chunk c8 lives at float-offset 8*c8 + 4*(c8>>2) (+4*half).
// Max store end = 8*15 + 4*3 + 4 + 4 = 140  ->  row width must be >= 140.
#define BM1 128
#define BN1 128
#define BK1 16
__global__ void gemm1_kernel(const float* __restrict__ Y,
                             const float* __restrict__ W1,
                             const float* __restrict__ bias1,
                             uint4* __restrict__ H1b4) {
    __shared__ float As[BK1][BM1 + 4];   // transposed A tile
    __shared__ float Bs[BK1][BN1 + 16];  // swizzled B tile, width 144 (fix: was 136, overflowed)
    int tid = threadIdx.x;               // 256
    int tr = tid >> 4, tc = tid & 15;    // 16x16 thread grid
    int row0 = blockIdx.x * BM1;
    int col0 = blockIdx.y * BN1;
    int sw_tc = 8 * tc + 4 * (tc >> 2);  // swizzled read base for this thread
    float acc[8][8] = {};
    for (int k0 = 0; k0 < IN_DIM; k0 += BK1) {   // 8 k-tiles
        #pragma unroll
        for (int i = tid; i < 512; i += 256) {
            int r = i >> 2, c4 = i & 3;
            int gr = row0 + r;
            float4 v = make_float4(0.f, 0.f, 0.f, 0.f);
            if (gr < N_NODES)
                v = *(const float4*)(Y + (size_t)gr * IN_DIM + k0 + c4 * 4);
            As[c4 * 4 + 0][r] = v.x * 0.25f;
            As[c4 * 4 + 1][r] = v.y * 0.25f;
            As[c4 * 4 + 2][r] = v.z * 0.25f;
            As[c4 * 4 + 3][r] = v.w * 0.25f;
        }
        #pragma unroll
        for (int i = tid; i < 512; i += 256) {
            int c = i >> 5, n4 = i & 31;
            float4 w = *(const float4*)(W1 + (size_t)(k0 + c) * HID + col0 + n4 * 4);
            int c8 = n4 >> 1, half = n4 & 1;
            *(float4*)&Bs[c][8 * c8 + 4 * (c8 >> 2) + 4 * half] = w;
        }
        __syncthreads();
        #pragma unroll
        for (int kk = 0; kk < BK1; ++kk) {
            float4 a0 = *(const float4*)&As[kk][tr * 8];
            float4 a1 = *(const float4*)&As[kk][tr * 8 + 4];
            float4 b0 = *(const float4*)&Bs[kk][sw_tc];
            float4 b1v = *(const float4*)&Bs[kk][sw_tc + 4];
            float a[8] = {a0.x, a0.y, a0.z, a0.w, a1.x, a1.y, a1.z, a1.w};
            float b[8] = {b0.x, b0.y, b0.z, b0.w, b1v.x, b1v.y, b1v.z, b1v.w};
            #pragma unroll
            for (int i = 0; i < 8; ++i)
                #pragma unroll
                for (int j = 0; j < 8; ++j)
                    acc[i][j] += a[i] * b[j];
        }
        __syncthreads();
    }
    float4 bb0 = *(const float4*)(bias1 + col0 + tc * 8);
    float4 bb1 = *(const float4*)(bias1 + col0 + tc * 8 + 4);
    float bb[8] = {bb0.x, bb0.y, bb0.z, bb0.w, bb1.x, bb1.y, bb1.z, bb1.w};
    #pragma unroll
    for (int i = 0; i < 8; ++i) {
        int gr = row0 + tr * 8 + i;
        if (gr >= N_NODES) continue;
        float o[8];
        #pragma unroll
        for (int j = 0; j < 8; ++j) {
            float v = acc[i][j] + bb[j];
            o[j] = v > 0.f ? v : 0.f;
        }
        // pack 8 fp32 -> 8 bf16 (16 B) : H1b row = 32 uint4s
        uint4 pk;
        pk.x = bf16pair(o[0], o[1]);
        pk.y = bf16pair(o[2], o[3]);
        pk.z = bf16pair(o[4], o[5]);
        pk.w = bf16pair(o[6], o[7]);
        H1b4[(size_t)gr * 32 + (col0 >> 3) + tc] = pk;
    }
}

// ---------------- GEMM2: logits = H1(bf16) @ W2 + b2 ----------------
// BM=128, BN=40 (exact), BK=32; 128 threads = 16 rt x 8 ct; micro 8x5.
#define G2_BM 128
#define G2_BK 32
__global__ void gemm2_kernel(const uint4* __restrict__ H1b4,
                             const float* __restrict__ W2,
                             const float* __restrict__ b2,
                             float* __restrict__ logits) {
    __shared__ float As[G2_BK][G2_BM + 4];   // transposed A (fp32, unpacked)
    __shared__ float Bs[G2_BK][44];          // 32 x 40, row pad to 44 (4-aligned)
    int tid = threadIdx.x;                   // 128
    int rt = tid >> 3;                       // 0..15, 8 rows each
    int ct = tid & 7;                        // 0..7, 5 cols each
    int row0 = blockIdx.x * G2_BM;
    float acc[8][5] = {};
    for (int k0 = 0; k0 < HID; k0 += G2_BK) {    // 8 k-tiles
        // stage A: 128 rows x 32 k of bf16 H1 -> transposed fp32.
        // 512 uint4 (8 bf16 each): 4 per thread.
        #pragma unroll
        for (int i = tid; i < 512; i += 128) {
            int r = i >> 2, u = i & 3;           // u: which uint4 within the 32-k span
            int gr = row0 + r;
            uint4 h = make_uint4(0u, 0u, 0u, 0u);
            if (gr < N_NODES)
                h = H1b4[(size_t)gr * 32 + (k0 >> 3) + u];
            int kb = u * 8;
            As[kb + 0][r] = bf_lo(h.x);
            As[kb + 1][r] = bf_hi(h.x);
            As[kb + 2][r] = bf_lo(h.y);
            As[kb + 3][r] = bf_hi(h.y);
            As[kb + 4][r] = bf_lo(h.z);
            As[kb + 5][r] = bf_hi(h.z);
            As[kb + 6][r] = bf_lo(h.w);
            As[kb + 7][r] = bf_hi(h.w);
        }
        // stage B: 32 x 40 fp32 = 320 float4: 2.5 per thread
        for (int i = tid; i < 320; i += 128) {
            int r = i / 10, cg = i % 10;
            float4 w = *(const float4*)(W2 + (size_t)(k0 + r) * NCLASS + cg * 4);
            *(float4*)&Bs[r][cg * 4] = w;
        }
        __syncthreads();
        #pragma unroll
        for (int kk = 0; kk < G2_BK; ++kk) {
            float4 a0 = *(const float4*)&As[kk][rt * 8];
            float4 a1 = *(const float4*)&As[kk][rt * 8 + 4];
            float a[8] = {a0.x, a0.y, a0.z, a0.w, a1.x, a1.y, a1.z, a1.w};
            float b[5];
            #pragma unroll
            for (int j = 0; j < 5; ++j) b[j] = Bs[kk][ct * 5 + j];
            #pragma unroll
            for (int i = 0; i < 8; ++i)
                #pragma unroll
                for (int j = 0; j < 5; ++j)
                    acc[i][j] += a[i] * b[j];
        }
        __syncthreads();
    }
    float bb[5];
    #pragma unroll
    for (int j = 0; j < 5; ++j) bb[j] = b2[ct * 5 + j];
    #pragma unroll
    for (int i = 0; i < 8; ++i) {
        int gr = row0 + rt * 8 + i;
        if (gr >= N_NODES) continue;
        float* dst = logits + (size_t)gr * NCLASS + ct * 5;
        #pragma unroll
        for (int j = 0; j < 5; ++j)
            dst[j] = acc[i][j] + bb[j];
    }
}

// ---------------- double log_softmax over 40 classes, wave per row ----------------
__global__ void lsm_kernel(const float* __restrict__ logits,
                           float* __restrict__ Out) {
    int wave = threadIdx.x >> 6;
    int lane = threadIdx.x & 63;
    int row = blockIdx.x * 4 + wave;
    if (row >= N_NODES) return;

    float acc = (lane < NCLASS) ? logits[(size_t)row * NCLASS + lane] : -INFINITY;

    float m = acc;
    #pragma unroll
    for (int off = 32; off >= 1; off >>= 1)
        m = fmaxf(m, __shfl_xor(m, off));
    float ex = (lane < NCLASS) ? expf(acc - m) : 0.f;
    float s = ex;
    #pragma unroll
    for (int off = 32; off >= 1; off >>= 1)
        s += __shfl_xor(s, off);
    float z1 = acc - (m + logf(s));

    float m2 = z1;
    #pragma unroll
    for (int off = 32; off >= 1; off >>= 1)
        m2 = fmaxf(m2, __shfl_xor(m2, off));
    float ex2 = (lane < NCLASS) ? expf(z1 - m2) : 0.f;
    float s2 = ex2;
    #pragma unroll
    for (int off = 32; off >= 1; off >>= 1)
        s2 += __shfl_xor(s2, off);
    float z2 = z1 - (m2 + logf(s2));

    if (lane < NCLASS)
        Out[(size_t)row * NCLASS + lane] = z2;
}

extern "C" void kernel_launch(void* const* d_in, const int* in_sizes, int n_in,
                              void* d_out, int out_size, void* d_ws, size_t ws_size,
                              hipStream_t stream) {
    const float* feats   = (const float*)d_in[0];
    const int*   e_row   = (const int*)d_in[1];
    const int*   e_col   = (const int*)d_in[2];
    const float* e_vals  = (const float*)d_in[3];
    const float* W1      = (const float*)d_in[4];
    const float* b1      = (const float*)d_in[5];
    const float* W2      = (const float*)d_in[6];
    const float* b2      = (const float*)d_in[7];
    float* out = (float*)d_out;

    // Workspace (19.2M floats proven):
    //   y    : [0, 6.4M)            fp32 MLP input
    //   fb16 : [6.4M, 9.6M)         feats in bf16 (3.2M float-slots)
    //   h1b  : [9.6M, 12.8M)        hop1 out, bf16
    //   h2b  : [12.8M, 16M)         hop2 out, bf16
    //   H1b  : [6.4M, 12.8M)        gemm1 out bf16 (fb16/h1b dead by then)
    //   logits: [0, 2M)             (y dead after gemm1)
    float* ws    = (float*)d_ws;
    float* ybuf  = ws;
    uint2* fb16  = (uint2*)(ws + (size_t)N_NODES * IN_DIM);
    uint2* h1b   = (uint2*)(ws + (size_t)N_NODES * IN_DIM * 3 / 2);
    uint2* h2b   = (uint2*)(ws + (size_t)N_NODES * IN_DIM * 2);
    uint4* H1b4  = (uint4*)(ws + (size_t)N_NODES * IN_DIM);   // 50000*256 bf16 = 6.4M f-slots
    float* logits = ws;

    // CSR scratch in d_out (8 MB; fully overwritten by lsm_kernel at the end).
    int2*  csr_cv    = (int2*)d_out;                     // interleaved (col,val)
    int*   counts    = (int*)d_out + 2 * N_EDGES;        // [1600000, 1650000)
    int*   cursor    = counts + N_NODES;                 // [1650000, 1700000)
    int*   row_start = cursor + N_NODES;                 // [1700000, 1750001)
    int*   blockSums = row_start + N_NODES + 4;
    int*   blockOffs = blockSums + 64;                   // < 2000000

    // zero counts (200 KB)
    hipMemsetAsync(counts, 0, N_NODES * sizeof(int), stream);

    // feats -> bf16 (packed)
    const int ELEMS4 = N_NODES * IN_DIM / 4;  // 1.6M float4s
    to_bf16_kernel<<<ELEMS4 / 256, 256, 0, stream>>>((const float4*)feats, fb16);

    // Build CSR: count -> hierarchical scan -> scatter
    const int EG = N_EDGES / 256;             // 3125 exact
    count_kernel<<<EG, 256, 0, stream>>>(e_row, counts);
    block_sum_kernel<<<SCAN_NBLK, 256, 0, stream>>>(counts, blockSums);
    block_offset_kernel<<<1, 64, 0, stream>>>(blockSums, blockOffs, row_start);
    local_scan_kernel<<<SCAN_NBLK, 256, 0, stream>>>(counts, blockOffs, row_start, cursor);
    scatter_kernel<<<EG, 256, 0, stream>>>(e_row, e_col, e_vals, cursor, csr_cv);

    // 3 propagation hops (bf16 gather, fp32 accumulate; hop3 fuses fp32 combine)
    const int SPMM_BLOCKS = N_NODES / 4;      // 12500 (4 waves/block)
    spmm_csr<1><<<SPMM_BLOCKS, 256, 0, stream>>>(row_start, csr_cv, fb16, h1b,
                                                 nullptr, nullptr, nullptr, nullptr);
    spmm_csr<0><<<SPMM_BLOCKS, 256, 0, stream>>>(row_start, csr_cv, h1b, h2b,
                                                 nullptr, nullptr, nullptr, nullptr);
    spmm_csr<2><<<SPMM_BLOCKS, 256, 0, stream>>>(row_start, csr_cv, h2b, nullptr,
                                                 ybuf, feats, h1b, h2b);

    // GEMM1: H1b = bf16(relu((y*0.25) @ W1 + b1))  (overwrites fb16/h1b region)
    dim3 g1((N_NODES + BM1 - 1) / BM1, HID / BN1);    // (391, 2)
    gemm1_kernel<<<g1, 256, 0, stream>>>(ybuf, W1, b1, H1b4);

    // GEMM2: logits = H1b @ W2 + b2  (into dead y region)
    gemm2_kernel<<<(N_NODES + G2_BM - 1) / G2_BM, 128, 0, stream>>>(H1b4, W2, b2, logits);

    // double log_softmax -> out (overwrites CSR scratch entirely)
    lsm_kernel<<<(N_NODES + 3) / 4, 256, 0, stream>>>(logits, out);
}

// Round 10
// 430.284 us; speedup vs baseline: 1.3236x; 1.3236x over previous
//
#include <hip/hip_runtime.h>
#include <math.h>

#define N_NODES 50000
#define N_EDGES 800000
#define IN_DIM 128
#define HID 256
#define NCLASS 40

#define SCAN_NBLK 49   // ceil(50000 / 1024)

// ---------- bf16 helpers (RNE pack, cheap unpack) ----------
__device__ inline unsigned bf16pair(float a, float b) {
    unsigned ua = __float_as_uint(a), ub = __float_as_uint(b);
    ua = (ua + 0x7fffu + ((ua >> 16) & 1u)) >> 16;
    ub = (ub + 0x7fffu + ((ub >> 16) & 1u)) >> 16;
    return ua | (ub << 16);
}
__device__ inline float bf_lo(unsigned u) { return __uint_as_float(u << 16); }
__device__ inline float bf_hi(unsigned u) { return __uint_as_float(u & 0xffff0000u); }

// ---------------- convert feats -> bf16 (packed) ----------------
__global__ void to_bf16_kernel(const float4* __restrict__ f4,
                               uint2* __restrict__ o) {
    int i = blockIdx.x * blockDim.x + threadIdx.x;   // 1.6M float4s
    float4 v = f4[i];
    o[i] = make_uint2(bf16pair(v.x, v.y), bf16pair(v.z, v.w));
}

// ---------------- CSR build: count ----------------
__global__ void count_kernel(const int* __restrict__ rows,
                             int* __restrict__ counts) {
    int e = blockIdx.x * blockDim.x + threadIdx.x;
    if (e < N_EDGES) atomicAdd(&counts[rows[e]], 1);
}

// ---------------- hierarchical scan, phase 1: per-block sums ----------------
__global__ void block_sum_kernel(const int* __restrict__ counts,
                                 int* __restrict__ blockSums) {
    int t = threadIdx.x;
    int base = blockIdx.x * 1024 + t * 4;
    int s = 0;
    if (base < N_NODES) {
        int4 c = *(const int4*)(counts + base);
        s = c.x + c.y + c.z + c.w;
    }
    #pragma unroll
    for (int off = 32; off >= 1; off >>= 1)
        s += __shfl_xor(s, off);
    __shared__ int wsum[4];
    int lane = t & 63, wid = t >> 6;
    if (lane == 0) wsum[wid] = s;
    __syncthreads();
    if (t == 0)
        blockSums[blockIdx.x] = wsum[0] + wsum[1] + wsum[2] + wsum[3];
}

// ---------------- phase 2: scan the 49 block sums (single wave) ----------------
__global__ void block_offset_kernel(const int* __restrict__ blockSums,
                                    int* __restrict__ blockOffs,
                                    int* __restrict__ row_start) {
    int lane = threadIdx.x;          // 64 threads
    int x = (lane < SCAN_NBLK) ? blockSums[lane] : 0;
    #pragma unroll
    for (int off = 1; off < 64; off <<= 1) {
        int y = __shfl_up(x, off);
        if (lane >= off) x += y;
    }
    int excl = __shfl_up(x, 1);
    if (lane == 0) excl = 0;
    if (lane < SCAN_NBLK) blockOffs[lane] = excl;
    if (lane == SCAN_NBLK - 1) row_start[N_NODES] = x;   // grand total
}

// ---------------- phase 3: local scan + block offset -> row_start, cursor ----------------
__global__ void local_scan_kernel(const int* __restrict__ counts,
                                  const int* __restrict__ blockOffs,
                                  int* __restrict__ row_start,
                                  int* __restrict__ cursor) {
    int t = threadIdx.x;
    int base = blockIdx.x * 1024 + t * 4;
    int4 c = make_int4(0, 0, 0, 0);
    if (base < N_NODES) c = *(const int4*)(counts + base);
    int s0 = c.x, s1 = s0 + c.y, s2 = s1 + c.z, s3 = s2 + c.w;
    int tsum = s3;
    int lane = t & 63, wid = t >> 6;
    int x = tsum;
    #pragma unroll
    for (int off = 1; off < 64; off <<= 1) {
        int y = __shfl_up(x, off);
        if (lane >= off) x += y;
    }
    __shared__ int wsum[4];
    if (lane == 63) wsum[wid] = x;
    __syncthreads();
    int woff = 0;
    for (int i = 0; i < 4; ++i)
        if (i < wid) woff += wsum[i];
    int excl = x - tsum + woff + blockOffs[blockIdx.x];
    if (base < N_NODES) {
        int4 rs = make_int4(excl, excl + s0, excl + s1, excl + s2);
        *(int4*)(row_start + base) = rs;
        *(int4*)(cursor + base) = rs;
    }
}

// ---------------- CSR build: scatter (interleaved col+val, single 8B store) ----------------
__global__ void scatter_kernel(const int* __restrict__ rows,
                               const int* __restrict__ cols,
                               const float* __restrict__ vals,
                               int* __restrict__ cursor,
                               int2* __restrict__ csr_cv) {
    int e = blockIdx.x * blockDim.x + threadIdx.x;
    if (e >= N_EDGES) return;
    int pos = atomicAdd(&cursor[rows[e]], 1);
    csr_cv[pos] = make_int2(cols[e], __float_as_int(vals[e]));
}

// ---------------- SpMM (CSR, bf16 gather, fp32 accumulate) ----------------
// MODE 0: Hout_b[r] = bf16(acc)                         (hop 2)
// MODE 1: Hout_b[r] = bf16(0.5*acc)                     (hop 1, folds input scale)
// MODE 2: Yout[r]   = 0.5*feats[r] + h1[r] + h2[r] + acc (hop 3, fp32 combine)
template <int MODE>
__global__ void spmm_csr(const int* __restrict__ row_start,
                         const int2* __restrict__ csr_cv,
                         const uint2* __restrict__ Hin_b,
                         uint2* __restrict__ Hout_b,
                         float* __restrict__ Yout,
                         const float* __restrict__ feats,
                         const uint2* __restrict__ h1b,
                         const uint2* __restrict__ h2b) {
    int wave = (blockIdx.x * blockDim.x + threadIdx.x) >> 6;
    int lane = threadIdx.x & 63;
    if (wave >= N_NODES) return;
    int p = lane >> 5;          // which edge of the pair
    int q = lane & 31;          // dim group (4 dims)
    int start = row_start[wave];
    int end   = row_start[wave + 1];
    float4 acc = make_float4(0.f, 0.f, 0.f, 0.f);
    for (int base = start; base < end; base += 64) {
        int idx = base + lane;
        int c = 0; float v = 0.f;
        if (idx < end) {
            int2 cv = csr_cv[idx];
            c = cv.x;
            v = __int_as_float(cv.y);
        }
        int cnt = min(64, end - base);
        for (int j = 0; j < cnt; j += 2) {
            int src = j + p;                   // v==0 beyond cnt
            int   cj = __shfl(c, src);
            float vj = __shfl(v, src);
            uint2 h = Hin_b[(size_t)cj * 32 + q];   // 4 bf16 = 8 B
            acc.x += vj * bf_lo(h.x);
            acc.y += vj * bf_hi(h.x);
            acc.z += vj * bf_lo(h.y);
            acc.w += vj * bf_hi(h.y);
        }
    }
    acc.x += __shfl_xor(acc.x, 32);
    acc.y += __shfl_xor(acc.y, 32);
    acc.z += __shfl_xor(acc.z, 32);
    acc.w += __shfl_xor(acc.w, 32);
    if (p == 0) {
        size_t o32 = (size_t)wave * 32 + q;
        if (MODE == 1) {
            acc.x *= 0.5f; acc.y *= 0.5f; acc.z *= 0.5f; acc.w *= 0.5f;
            Hout_b[o32] = make_uint2(bf16pair(acc.x, acc.y), bf16pair(acc.z, acc.w));
        } else if (MODE == 0) {
            Hout_b[o32] = make_uint2(bf16pair(acc.x, acc.y), bf16pair(acc.z, acc.w));
        } else {
            size_t o = (size_t)wave * IN_DIM + q * 4;
            float4 f = *(const float4*)(feats + o);
            uint2 a = h1b[o32];
            uint2 b = h2b[o32];
            acc.x += 0.5f * f.x + bf_lo(a.x) + bf_lo(b.x);
            acc.y += 0.5f * f.y + bf_hi(a.x) + bf_hi(b.x);
            acc.z += 0.5f * f.z + bf_lo(a.y) + bf_lo(b.y);
            acc.w += 0.5f * f.w + bf_hi(a.y) + bf_hi(b.y);
            *(float4*)(Yout + o) = acc;
        }
    }
}

// ---------------- GEMM1: H1 = relu((y*0.25) @ W1 + b1)  [round-7 known-good] ----------------
// 128x128 tile, 8x8 per thread, BK=16, A transposed in LDS (all-b128 reads), fp32 out.
#define BM1 128
#define BN1 128
#define BK1 16
__global__ void gemm1_kernel(const float* __restrict__ Y,
                             const float* __restrict__ W1,
                             const float* __restrict__ bias1,
                             float* __restrict__ H1) {
    __shared__ float As[BK1][BM1 + 4];   // transposed A tile
    __shared__ float Bs[BK1][BN1 + 4];
    int tid = threadIdx.x;               // 256
    int tr = tid >> 4, tc = tid & 15;    // 16x16 thread grid
    int row0 = blockIdx.x * BM1;
    int col0 = blockIdx.y * BN1;
    float acc[8][8] = {};
    for (int k0 = 0; k0 < IN_DIM; k0 += BK1) {   // 8 k-tiles
        #pragma unroll
        for (int i = tid; i < 512; i += 256) {
            int r = i >> 2, c4 = i & 3;
            int gr = row0 + r;
            float4 v = make_float4(0.f, 0.f, 0.f, 0.f);
            if (gr < N_NODES)
                v = *(const float4*)(Y + (size_t)gr * IN_DIM + k0 + c4 * 4);
            As[c4 * 4 + 0][r] = v.x * 0.25f;
            As[c4 * 4 + 1][r] = v.y * 0.25f;
            As[c4 * 4 + 2][r] = v.z * 0.25f;
            As[c4 * 4 + 3][r] = v.w * 0.25f;
        }
        #pragma unroll
        for (int i = tid; i < 512; i += 256) {
            int c = i >> 5, n4 = i & 31;
            float4 w = *(const float4*)(W1 + (size_t)(k0 + c) * HID + col0 + n4 * 4);
            *(float4*)&Bs[c][n4 * 4] = w;
        }
        __syncthreads();
        #pragma unroll
        for (int kk = 0; kk < BK1; ++kk) {
            float4 a0 = *(const float4*)&As[kk][tr * 8];
            float4 a1 = *(const float4*)&As[kk][tr * 8 + 4];
            float4 b0 = *(const float4*)&Bs[kk][tc * 8];
            float4 b1v = *(const float4*)&Bs[kk][tc * 8 + 4];
            float a[8] = {a0.x, a0.y, a0.z, a0.w, a1.x, a1.y, a1.z, a1.w};
            float b[8] = {b0.x, b0.y, b0.z, b0.w, b1v.x, b1v.y, b1v.z, b1v.w};
            #pragma unroll
            for (int i = 0; i < 8; ++i)
                #pragma unroll
                for (int j = 0; j < 8; ++j)
                    acc[i][j] += a[i] * b[j];
        }
        __syncthreads();
    }
    float4 bb0 = *(const float4*)(bias1 + col0 + tc * 8);
    float4 bb1 = *(const float4*)(bias1 + col0 + tc * 8 + 4);
    float bb[8] = {bb0.x, bb0.y, bb0.z, bb0.w, bb1.x, bb1.y, bb1.z, bb1.w};
    #pragma unroll
    for (int i = 0; i < 8; ++i) {
        int gr = row0 + tr * 8 + i;
        if (gr >= N_NODES) continue;
        float o[8];
        #pragma unroll
        for (int j = 0; j < 8; ++j) {
            float v = acc[i][j] + bb[j];
            o[j] = v > 0.f ? v : 0.f;
        }
        float* dst = H1 + (size_t)gr * HID + col0 + tc * 8;
        *(float4*)(dst)     = make_float4(o[0], o[1], o[2], o[3]);
        *(float4*)(dst + 4) = make_float4(o[4], o[5], o[6], o[7]);
    }
}

// ---------------- GEMM2: logits = H1 @ W2 + b2 ----------------
// BM=128, BN=40 (exact), BK=32; 128 threads = 16 rt x 8 ct; micro 8x5; fp32 A.
#define G2_BM 128
#define G2_BK 32
__global__ void gemm2_kernel(const float* __restrict__ H1,
                             const float* __restrict__ W2,
                             const float* __restrict__ b2,
                             float* __restrict__ logits) {
    __shared__ float As[G2_BK][G2_BM + 4];   // transposed A
    __shared__ float Bs[G2_BK][44];          // 32 x 40, row pad to 44 (4-aligned)
    int tid = threadIdx.x;                   // 128
    int rt = tid >> 3;                       // 0..15, 8 rows each
    int ct = tid & 7;                        // 0..7, 5 cols each
    int row0 = blockIdx.x * G2_BM;
    float acc[8][5] = {};
    for (int k0 = 0; k0 < HID; k0 += G2_BK) {    // 8 k-tiles
        // stage A: 128 rows x 32 k fp32 -> transposed. 1024 float4, 8 per thread.
        #pragma unroll
        for (int i = tid; i < 1024; i += 128) {
            int r = i >> 3, u = i & 7;           // u: which float4 within the 32-k span
            int gr = row0 + r;
            float4 v = make_float4(0.f, 0.f, 0.f, 0.f);
            if (gr < N_NODES)
                v = *(const float4*)(H1 + (size_t)gr * HID + k0 + u * 4);
            int kb = u * 4;
            As[kb + 0][r] = v.x;
            As[kb + 1][r] = v.y;
            As[kb + 2][r] = v.z;
            As[kb + 3][r] = v.w;
        }
        // stage B: 32 x 40 fp32 = 320 float4
        for (int i = tid; i < 320; i += 128) {
            int r = i / 10, cg = i % 10;
            float4 w = *(const float4*)(W2 + (size_t)(k0 + r) * NCLASS + cg * 4);
            *(float4*)&Bs[r][cg * 4] = w;
        }
        __syncthreads();
        #pragma unroll
        for (int kk = 0; kk < G2_BK; ++kk) {
            float4 a0 = *(const float4*)&As[kk][rt * 8];
            float4 a1 = *(const float4*)&As[kk][rt * 8 + 4];
            float a[8] = {a0.x, a0.y, a0.z, a0.w, a1.x, a1.y, a1.z, a1.w};
            float b[5];
            #pragma unroll
            for (int j = 0; j < 5; ++j) b[j] = Bs[kk][ct * 5 + j];
            #pragma unroll
            for (int i = 0; i < 8; ++i)
                #pragma unroll
                for (int j = 0; j < 5; ++j)
                    acc[i][j] += a[i] * b[j];
        }
        __syncthreads();
    }
    float bb[5];
    #pragma unroll
    for (int j = 0; j < 5; ++j) bb[j] = b2[ct * 5 + j];
    #pragma unroll
    for (int i = 0; i < 8; ++i) {
        int gr = row0 + rt * 8 + i;
        if (gr >= N_NODES) continue;
        float* dst = logits + (size_t)gr * NCLASS + ct * 5;
        #pragma unroll
        for (int j = 0; j < 5; ++j)
            dst[j] = acc[i][j] + bb[j];
    }
}

// ---------------- double log_softmax over 40 classes, wave per row ----------------
__global__ void lsm_kernel(const float* __restrict__ logits,
                           float* __restrict__ Out) {
    int wave = threadIdx.x >> 6;
    int lane = threadIdx.x & 63;
    int row = blockIdx.x * 4 + wave;
    if (row >= N_NODES) return;

    float acc = (lane < NCLASS) ? logits[(size_t)row * NCLASS + lane] : -INFINITY;

    float m = acc;
    #pragma unroll
    for (int off = 32; off >= 1; off >>= 1)
        m = fmaxf(m, __shfl_xor(m, off));
    float ex = (lane < NCLASS) ? expf(acc - m) : 0.f;
    float s = ex;
    #pragma unroll
    for (int off = 32; off >= 1; off >>= 1)
        s += __shfl_xor(s, off);
    float z1 = acc - (m + logf(s));

    float m2 = z1;
    #pragma unroll
    for (int off = 32; off >= 1; off >>= 1)
        m2 = fmaxf(m2, __shfl_xor(m2, off));
    float ex2 = (lane < NCLASS) ? expf(z1 - m2) : 0.f;
    float s2 = ex2;
    #pragma unroll
    for (int off = 32; off >= 1; off >>= 1)
        s2 += __shfl_xor(s2, off);
    float z2 = z1 - (m2 + logf(s2));

    if (lane < NCLASS)
        Out[(size_t)row * NCLASS + lane] = z2;
}

extern "C" void kernel_launch(void* const* d_in, const int* in_sizes, int n_in,
                              void* d_out, int out_size, void* d_ws, size_t ws_size,
                              hipStream_t stream) {
    const float* feats   = (const float*)d_in[0];
    const int*   e_row   = (const int*)d_in[1];
    const int*   e_col   = (const int*)d_in[2];
    const float* e_vals  = (const float*)d_in[3];
    const float* W1      = (const float*)d_in[4];
    const float* b1      = (const float*)d_in[5];
    const float* W2      = (const float*)d_in[6];
    const float* b2      = (const float*)d_in[7];
    float* out = (float*)d_out;

    // Workspace (19.2M floats proven, round-7 layout):
    //   y    : [0, 6.4M)            fp32 MLP input
    //   fb16 : [6.4M, 9.6M)         feats in bf16
    //   h1b  : [9.6M, 12.8M)        hop1 out, bf16
    //   h2b  : [12.8M, 16M)         hop2 out, bf16
    //   hid  : [6.4M, 19.2M)        gemm1 out fp32 (bf16 bufs dead by then)
    //   logits: [0, 2M)             (y dead after gemm1)
    float* ws    = (float*)d_ws;
    float* ybuf  = ws;
    uint2* fb16  = (uint2*)(ws + (size_t)N_NODES * IN_DIM);
    uint2* h1b   = (uint2*)(ws + (size_t)N_NODES * IN_DIM * 3 / 2);
    uint2* h2b   = (uint2*)(ws + (size_t)N_NODES * IN_DIM * 2);
    float* hid   = ws + (size_t)N_NODES * IN_DIM;
    float* logits = ws;

    // CSR scratch in d_out (8 MB; fully overwritten by lsm_kernel at the end).
    int2*  csr_cv    = (int2*)d_out;                     // interleaved (col,val)
    int*   counts    = (int*)d_out + 2 * N_EDGES;        // [1600000, 1650000)
    int*   cursor    = counts + N_NODES;                 // [1650000, 1700000)
    int*   row_start = cursor + N_NODES;                 // [1700000, 1750001)
    int*   blockSums = row_start + N_NODES + 4;
    int*   blockOffs = blockSums + 64;                   // < 2000000

    // zero counts (200 KB)
    hipMemsetAsync(counts, 0, N_NODES * sizeof(int), stream);

    // feats -> bf16 (packed)
    const int ELEMS4 = N_NODES * IN_DIM / 4;  // 1.6M float4s
    to_bf16_kernel<<<ELEMS4 / 256, 256, 0, stream>>>((const float4*)feats, fb16);

    // Build CSR: count -> hierarchical scan -> scatter
    const int EG = N_EDGES / 256;             // 3125 exact
    count_kernel<<<EG, 256, 0, stream>>>(e_row, counts);
    block_sum_kernel<<<SCAN_NBLK, 256, 0, stream>>>(counts, blockSums);
    block_offset_kernel<<<1, 64, 0, stream>>>(blockSums, blockOffs, row_start);
    local_scan_kernel<<<SCAN_NBLK, 256, 0, stream>>>(counts, blockOffs, row_start, cursor);
    scatter_kernel<<<EG, 256, 0, stream>>>(e_row, e_col, e_vals, cursor, csr_cv);

    // 3 propagation hops (bf16 gather, fp32 accumulate; hop3 fuses fp32 combine)
    const int SPMM_BLOCKS = N_NODES / 4;      // 12500 (4 waves/block)
    spmm_csr<1><<<SPMM_BLOCKS, 256, 0, stream>>>(row_start, csr_cv, fb16, h1b,
                                                 nullptr, nullptr, nullptr, nullptr);
    spmm_csr<0><<<SPMM_BLOCKS, 256, 0, stream>>>(row_start, csr_cv, h1b, h2b,
                                                 nullptr, nullptr, nullptr, nullptr);
    spmm_csr<2><<<SPMM_BLOCKS, 256, 0, stream>>>(row_start, csr_cv, h2b, nullptr,
                                                 ybuf, feats, h1b, h2b);

    // GEMM1: hid = relu((y*0.25) @ W1 + b1)  (fp32 out, round-7 known-good)
    dim3 g1((N_NODES + BM1 - 1) / BM1, HID / BN1);    // (391, 2)
    gemm1_kernel<<<g1, 256, 0, stream>>>(ybuf, W1, b1, hid);

    // GEMM2: logits = hid @ W2 + b2  (into dead y region)
    gemm2_kernel<<<(N_NODES + G2_BM - 1) / G2_BM, 128, 0, stream>>>(hid, W2, b2, logits);

    // double log_softmax -> out (overwrites CSR scratch entirely)
    lsm_kernel<<<(N_NODES + 3) / 4, 256, 0, stream>>>(logits, out);
}

// Round 11
// 391.393 us; speedup vs baseline: 1.4551x; 1.0994x over previous
//
#include <hip/hip_runtime.h>
#include <math.h>

#define N_NODES 50000
#define N_EDGES 800000
#define IN_DIM 128
#define HID 256
#define NCLASS 40

#define SCAN_NBLK 49   // ceil(50000 / 1024)

// ---------- bf16 helpers (RNE pack, cheap unpack) ----------
__device__ inline unsigned bf16pair(float a, float b) {
    unsigned ua = __float_as_uint(a), ub = __float_as_uint(b);
    ua = (ua + 0x7fffu + ((ua >> 16) & 1u)) >> 16;
    ub = (ub + 0x7fffu + ((ub >> 16) & 1u)) >> 16;
    return ua | (ub << 16);
}
__device__ inline float bf_lo(unsigned u) { return __uint_as_float(u << 16); }
__device__ inline float bf_hi(unsigned u) { return __uint_as_float(u & 0xffff0000u); }

// ---------------- convert feats -> bf16 (packed) ----------------
__global__ void to_bf16_kernel(const float4* __restrict__ f4,
                               uint2* __restrict__ o) {
    int i = blockIdx.x * blockDim.x + threadIdx.x;   // 1.6M float4s
    float4 v = f4[i];
    o[i] = make_uint2(bf16pair(v.x, v.y), bf16pair(v.z, v.w));
}

// ---------------- CSR build: count ----------------
__global__ void count_kernel(const int* __restrict__ rows,
                             int* __restrict__ counts) {
    int e = blockIdx.x * blockDim.x + threadIdx.x;
    if (e < N_EDGES) atomicAdd(&counts[rows[e]], 1);
}

// ---------------- hierarchical scan, phase 1: per-block sums ----------------
__global__ void block_sum_kernel(const int* __restrict__ counts,
                                 int* __restrict__ blockSums) {
    int t = threadIdx.x;
    int base = blockIdx.x * 1024 + t * 4;
    int s = 0;
    if (base < N_NODES) {
        int4 c = *(const int4*)(counts + base);
        s = c.x + c.y + c.z + c.w;
    }
    #pragma unroll
    for (int off = 32; off >= 1; off >>= 1)
        s += __shfl_xor(s, off);
    __shared__ int wsum[4];
    int lane = t & 63, wid = t >> 6;
    if (lane == 0) wsum[wid] = s;
    __syncthreads();
    if (t == 0)
        blockSums[blockIdx.x] = wsum[0] + wsum[1] + wsum[2] + wsum[3];
}

// ---------------- phase 2: scan the 49 block sums (single wave) ----------------
__global__ void block_offset_kernel(const int* __restrict__ blockSums,
                                    int* __restrict__ blockOffs,
                                    int* __restrict__ row_start) {
    int lane = threadIdx.x;          // 64 threads
    int x = (lane < SCAN_NBLK) ? blockSums[lane] : 0;
    #pragma unroll
    for (int off = 1; off < 64; off <<= 1) {
        int y = __shfl_up(x, off);
        if (lane >= off) x += y;
    }
    int excl = __shfl_up(x, 1);
    if (lane == 0) excl = 0;
    if (lane < SCAN_NBLK) blockOffs[lane] = excl;
    if (lane == SCAN_NBLK - 1) row_start[N_NODES] = x;   // grand total
}

// ---------------- phase 3: local scan + block offset -> row_start, cursor ----------------
__global__ void local_scan_kernel(const int* __restrict__ counts,
                                  const int* __restrict__ blockOffs,
                                  int* __restrict__ row_start,
                                  int* __restrict__ cursor) {
    int t = threadIdx.x;
    int base = blockIdx.x * 1024 + t * 4;
    int4 c = make_int4(0, 0, 0, 0);
    if (base < N_NODES) c = *(const int4*)(counts + base);
    int s0 = c.x, s1 = s0 + c.y, s2 = s1 + c.z, s3 = s2 + c.w;
    int tsum = s3;
    int lane = t & 63, wid = t >> 6;
    int x = tsum;
    #pragma unroll
    for (int off = 1; off < 64; off <<= 1) {
        int y = __shfl_up(x, off);
        if (lane >= off) x += y;
    }
    __shared__ int wsum[4];
    if (lane == 63) wsum[wid] = x;
    __syncthreads();
    int woff = 0;
    for (int i = 0; i < 4; ++i)
        if (i < wid) woff += wsum[i];
    int excl = x - tsum + woff + blockOffs[blockIdx.x];
    if (base < N_NODES) {
        int4 rs = make_int4(excl, excl + s0, excl + s1, excl + s2);
        *(int4*)(row_start + base) = rs;
        *(int4*)(cursor + base) = rs;
    }
}

// ---------------- CSR build: scatter (interleaved col+val, single 8B store) ----------------
__global__ void scatter_kernel(const int* __restrict__ rows,
                               const int* __restrict__ cols,
                               const float* __restrict__ vals,
                               int* __restrict__ cursor,
                               int2* __restrict__ csr_cv) {
    int e = blockIdx.x * blockDim.x + threadIdx.x;
    if (e >= N_EDGES) return;
    int pos = atomicAdd(&cursor[rows[e]], 1);
    csr_cv[pos] = make_int2(cols[e], __float_as_int(vals[e]));
}

// ---------------- SpMM (CSR, bf16 gather, fp32 accumulate) ----------------
// MODE 0: Hout_b[r] = bf16(acc)                         (hop 2)
// MODE 1: Hout_b[r] = bf16(0.5*acc)                     (hop 1, folds input scale)
// MODE 2: Yout[r]   = 0.5*feats[r] + h1[r] + h2[r] + acc (hop 3, fp32 combine)
template <int MODE>
__global__ void spmm_csr(const int* __restrict__ row_start,
                         const int2* __restrict__ csr_cv,
                         const uint2* __restrict__ Hin_b,
                         uint2* __restrict__ Hout_b,
                         float* __restrict__ Yout,
                         const float* __restrict__ feats,
                         const uint2* __restrict__ h1b,
                         const uint2* __restrict__ h2b) {
    int wave = (blockIdx.x * blockDim.x + threadIdx.x) >> 6;
    int lane = threadIdx.x & 63;
    if (wave >= N_NODES) return;
    int p = lane >> 5;          // which edge of the pair
    int q = lane & 31;          // dim group (4 dims)
    int start = row_start[wave];
    int end   = row_start[wave + 1];
    float4 acc = make_float4(0.f, 0.f, 0.f, 0.f);
    for (int base = start; base < end; base += 64) {
        int idx = base + lane;
        int c = 0; float v = 0.f;
        if (idx < end) {
            int2 cv = csr_cv[idx];
            c = cv.x;
            v = __int_as_float(cv.y);
        }
        int cnt = min(64, end - base);
        for (int j = 0; j < cnt; j += 2) {
            int src = j + p;                   // v==0 beyond cnt
            int   cj = __shfl(c, src);
            float vj = __shfl(v, src);
            uint2 h = Hin_b[(size_t)cj * 32 + q];   // 4 bf16 = 8 B
            acc.x += vj * bf_lo(h.x);
            acc.y += vj * bf_hi(h.x);
            acc.z += vj * bf_lo(h.y);
            acc.w += vj * bf_hi(h.y);
        }
    }
    acc.x += __shfl_xor(acc.x, 32);
    acc.y += __shfl_xor(acc.y, 32);
    acc.z += __shfl_xor(acc.z, 32);
    acc.w += __shfl_xor(acc.w, 32);
    if (p == 0) {
        size_t o32 = (size_t)wave * 32 + q;
        if (MODE == 1) {
            acc.x *= 0.5f; acc.y *= 0.5f; acc.z *= 0.5f; acc.w *= 0.5f;
            Hout_b[o32] = make_uint2(bf16pair(acc.x, acc.y), bf16pair(acc.z, acc.w));
        } else if (MODE == 0) {
            Hout_b[o32] = make_uint2(bf16pair(acc.x, acc.y), bf16pair(acc.z, acc.w));
        } else {
            size_t o = (size_t)wave * IN_DIM + q * 4;
            float4 f = *(const float4*)(feats + o);
            uint2 a = h1b[o32];
            uint2 b = h2b[o32];
            acc.x += 0.5f * f.x + bf_lo(a.x) + bf_lo(b.x);
            acc.y += 0.5f * f.y + bf_hi(a.x) + bf_hi(b.x);
            acc.z += 0.5f * f.z + bf_lo(a.y) + bf_lo(b.y);
            acc.w += 0.5f * f.w + bf_hi(a.y) + bf_hi(b.y);
            *(float4*)(Yout + o) = acc;
        }
    }
}

// ---------------- GEMM1: H1 = relu((y*0.25) @ W1 + b1)  [known-good] ----------------
#define BM1 128
#define BN1 128
#define BK1 16
__global__ void gemm1_kernel(const float* __restrict__ Y,
                             const float* __restrict__ W1,
                             const float* __restrict__ bias1,
                             float* __restrict__ H1) {
    __shared__ float As[BK1][BM1 + 4];   // transposed A tile
    __shared__ float Bs[BK1][BN1 + 4];
    int tid = threadIdx.x;               // 256
    int tr = tid >> 4, tc = tid & 15;    // 16x16 thread grid
    int row0 = blockIdx.x * BM1;
    int col0 = blockIdx.y * BN1;
    float acc[8][8] = {};
    for (int k0 = 0; k0 < IN_DIM; k0 += BK1) {   // 8 k-tiles
        #pragma unroll
        for (int i = tid; i < 512; i += 256) {
            int r = i >> 2, c4 = i & 3;
            int gr = row0 + r;
            float4 v = make_float4(0.f, 0.f, 0.f, 0.f);
            if (gr < N_NODES)
                v = *(const float4*)(Y + (size_t)gr * IN_DIM + k0 + c4 * 4);
            As[c4 * 4 + 0][r] = v.x * 0.25f;
            As[c4 * 4 + 1][r] = v.y * 0.25f;
            As[c4 * 4 + 2][r] = v.z * 0.25f;
            As[c4 * 4 + 3][r] = v.w * 0.25f;
        }
        #pragma unroll
        for (int i = tid; i < 512; i += 256) {
            int c = i >> 5, n4 = i & 31;
            float4 w = *(const float4*)(W1 + (size_t)(k0 + c) * HID + col0 + n4 * 4);
            *(float4*)&Bs[c][n4 * 4] = w;
        }
        __syncthreads();
        #pragma unroll
        for (int kk = 0; kk < BK1; ++kk) {
            float4 a0 = *(const float4*)&As[kk][tr * 8];
            float4 a1 = *(const float4*)&As[kk][tr * 8 + 4];
            float4 b0 = *(const float4*)&Bs[kk][tc * 8];
            float4 b1v = *(const float4*)&Bs[kk][tc * 8 + 4];
            float a[8] = {a0.x, a0.y, a0.z, a0.w, a1.x, a1.y, a1.z, a1.w};
            float b[8] = {b0.x, b0.y, b0.z, b0.w, b1v.x, b1v.y, b1v.z, b1v.w};
            #pragma unroll
            for (int i = 0; i < 8; ++i)
                #pragma unroll
                for (int j = 0; j < 8; ++j)
                    acc[i][j] += a[i] * b[j];
        }
        __syncthreads();
    }
    float4 bb0 = *(const float4*)(bias1 + col0 + tc * 8);
    float4 bb1 = *(const float4*)(bias1 + col0 + tc * 8 + 4);
    float bb[8] = {bb0.x, bb0.y, bb0.z, bb0.w, bb1.x, bb1.y, bb1.z, bb1.w};
    #pragma unroll
    for (int i = 0; i < 8; ++i) {
        int gr = row0 + tr * 8 + i;
        if (gr >= N_NODES) continue;
        float o[8];
        #pragma unroll
        for (int j = 0; j < 8; ++j) {
            float v = acc[i][j] + bb[j];
            o[j] = v > 0.f ? v : 0.f;
        }
        float* dst = H1 + (size_t)gr * HID + col0 + tc * 8;
        *(float4*)(dst)     = make_float4(o[0], o[1], o[2], o[3]);
        *(float4*)(dst + 4) = make_float4(o[4], o[5], o[6], o[7]);
    }
}

// ---------------- GEMM2 (K-split x2): partial = H1[:, khalf] @ W2[khalf, :] ----------------
// BM=128, BN=40 exact, BK=32; 256 threads = 32 rt x 8 ct; micro 4x5.
// blockIdx.y selects K-half (128) and partial buffer. Bias folded into lsm.
#define G2_BM 128
#define G2_BK 32
__global__ void gemm2_kernel(const float* __restrict__ H1,
                             const float* __restrict__ W2,
                             float* __restrict__ part0,
                             float* __restrict__ part1) {
    __shared__ float As[G2_BK][G2_BM + 4];   // transposed A
    __shared__ float Bs[G2_BK][44];          // 32 x 40, row pad to 44
    int tid = threadIdx.x;                   // 256
    int rt = tid >> 3;                       // 0..31, 4 rows each
    int ct = tid & 7;                        // 0..7, 5 cols each
    int row0 = blockIdx.x * G2_BM;
    int kbase = blockIdx.y * (HID / 2);      // 0 or 128
    float* outp = blockIdx.y ? part1 : part0;
    float acc[4][5] = {};
    for (int kt = 0; kt < HID / 2; kt += G2_BK) {    // 4 k-tiles
        int k0 = kbase + kt;
        // stage A: 128 rows x 32 k fp32 -> transposed. 1024 float4, 4 per thread.
        #pragma unroll
        for (int i = tid; i < 1024; i += 256) {
            int r = i >> 3, u = i & 7;           // u: which float4 within the 32-k span
            int gr = row0 + r;
            float4 v = make_float4(0.f, 0.f, 0.f, 0.f);
            if (gr < N_NODES)
                v = *(const float4*)(H1 + (size_t)gr * HID + k0 + u * 4);
            int kb = u * 4;
            As[kb + 0][r] = v.x;
            As[kb + 1][r] = v.y;
            As[kb + 2][r] = v.z;
            As[kb + 3][r] = v.w;
        }
        // stage B: 32 x 40 fp32 = 320 float4
        for (int i = tid; i < 320; i += 256) {
            int r = i / 10, cg = i % 10;
            float4 w = *(const float4*)(W2 + (size_t)(k0 + r) * NCLASS + cg * 4);
            *(float4*)&Bs[r][cg * 4] = w;
        }
        __syncthreads();
        #pragma unroll
        for (int kk = 0; kk < G2_BK; ++kk) {
            float4 a0 = *(const float4*)&As[kk][rt * 4];
            float a[4] = {a0.x, a0.y, a0.z, a0.w};
            float b[5];
            #pragma unroll
            for (int j = 0; j < 5; ++j) b[j] = Bs[kk][ct * 5 + j];
            #pragma unroll
            for (int i = 0; i < 4; ++i)
                #pragma unroll
                for (int j = 0; j < 5; ++j)
                    acc[i][j] += a[i] * b[j];
        }
        __syncthreads();
    }
    #pragma unroll
    for (int i = 0; i < 4; ++i) {
        int gr = row0 + rt * 4 + i;
        if (gr >= N_NODES) continue;
        float* dst = outp + (size_t)gr * NCLASS + ct * 5;
        #pragma unroll
        for (int j = 0; j < 5; ++j)
            dst[j] = acc[i][j];
    }
}

// ---------------- double log_softmax (sums K-split partials + bias) ----------------
__global__ void lsm_kernel(const float* __restrict__ part0,
                           const float* __restrict__ part1,
                           const float* __restrict__ b2,
                           float* __restrict__ Out) {
    int wave = threadIdx.x >> 6;
    int lane = threadIdx.x & 63;
    int row = blockIdx.x * 4 + wave;
    if (row >= N_NODES) return;

    float acc = -INFINITY;
    if (lane < NCLASS) {
        size_t idx = (size_t)row * NCLASS + lane;
        acc = part0[idx] + part1[idx] + b2[lane];
    }

    float m = acc;
    #pragma unroll
    for (int off = 32; off >= 1; off >>= 1)
        m = fmaxf(m, __shfl_xor(m, off));
    float ex = (lane < NCLASS) ? expf(acc - m) : 0.f;
    float s = ex;
    #pragma unroll
    for (int off = 32; off >= 1; off >>= 1)
        s += __shfl_xor(s, off);
    float z1 = acc - (m + logf(s));

    float m2 = z1;
    #pragma unroll
    for (int off = 32; off >= 1; off >>= 1)
        m2 = fmaxf(m2, __shfl_xor(m2, off));
    float ex2 = (lane < NCLASS) ? expf(z1 - m2) : 0.f;
    float s2 = ex2;
    #pragma unroll
    for (int off = 32; off >= 1; off >>= 1)
        s2 += __shfl_xor(s2, off);
    float z2 = z1 - (m2 + logf(s2));

    if (lane < NCLASS)
        Out[(size_t)row * NCLASS + lane] = z2;
}

extern "C" void kernel_launch(void* const* d_in, const int* in_sizes, int n_in,
                              void* d_out, int out_size, void* d_ws, size_t ws_size,
                              hipStream_t stream) {
    const float* feats   = (const float*)d_in[0];
    const int*   e_row   = (const int*)d_in[1];
    const int*   e_col   = (const int*)d_in[2];
    const float* e_vals  = (const float*)d_in[3];
    const float* W1      = (const float*)d_in[4];
    const float* b1      = (const float*)d_in[5];
    const float* W2      = (const float*)d_in[6];
    const float* b2      = (const float*)d_in[7];
    float* out = (float*)d_out;

    // Workspace (19.2M floats proven):
    //   y    : [0, 6.4M)            fp32 MLP input
    //   fb16 : [6.4M, 9.6M)         feats in bf16
    //   h1b  : [9.6M, 12.8M)        hop1 out, bf16
    //   h2b  : [12.8M, 16M)         hop2 out, bf16
    //   hid  : [6.4M, 19.2M)        gemm1 out fp32 (bf16 bufs dead by then)
    //   part0: [0, 2M)  part1: [2M, 4M)   (y dead after gemm1)
    float* ws    = (float*)d_ws;
    float* ybuf  = ws;
    uint2* fb16  = (uint2*)(ws + (size_t)N_NODES * IN_DIM);
    uint2* h1b   = (uint2*)(ws + (size_t)N_NODES * IN_DIM * 3 / 2);
    uint2* h2b   = (uint2*)(ws + (size_t)N_NODES * IN_DIM * 2);
    float* hid   = ws + (size_t)N_NODES * IN_DIM;
    float* part0 = ws;
    float* part1 = ws + (size_t)N_NODES * NCLASS;

    // CSR scratch in d_out (8 MB; fully overwritten by lsm_kernel at the end).
    int2*  csr_cv    = (int2*)d_out;                     // interleaved (col,val)
    int*   counts    = (int*)d_out + 2 * N_EDGES;        // [1600000, 1650000)
    int*   cursor    = counts + N_NODES;                 // [1650000, 1700000)
    int*   row_start = cursor + N_NODES;                 // [1700000, 1750001)
    int*   blockSums = row_start + N_NODES + 4;
    int*   blockOffs = blockSums + 64;                   // < 2000000

    // zero counts (200 KB)
    hipMemsetAsync(counts, 0, N_NODES * sizeof(int), stream);

    // feats -> bf16 (packed)
    const int ELEMS4 = N_NODES * IN_DIM / 4;  // 1.6M float4s
    to_bf16_kernel<<<ELEMS4 / 256, 256, 0, stream>>>((const float4*)feats, fb16);

    // Build CSR: count -> hierarchical scan -> scatter
    const int EG = N_EDGES / 256;             // 3125 exact
    count_kernel<<<EG, 256, 0, stream>>>(e_row, counts);
    block_sum_kernel<<<SCAN_NBLK, 256, 0, stream>>>(counts, blockSums);
    block_offset_kernel<<<1, 64, 0, stream>>>(blockSums, blockOffs, row_start);
    local_scan_kernel<<<SCAN_NBLK, 256, 0, stream>>>(counts, blockOffs, row_start, cursor);
    scatter_kernel<<<EG, 256, 0, stream>>>(e_row, e_col, e_vals, cursor, csr_cv);

    // 3 propagation hops (bf16 gather, fp32 accumulate; hop3 fuses fp32 combine)
    const int SPMM_BLOCKS = N_NODES / 4;      // 12500 (4 waves/block)
    spmm_csr<1><<<SPMM_BLOCKS, 256, 0, stream>>>(row_start, csr_cv, fb16, h1b,
                                                 nullptr, nullptr, nullptr, nullptr);
    spmm_csr<0><<<SPMM_BLOCKS, 256, 0, stream>>>(row_start, csr_cv, h1b, h2b,
                                                 nullptr, nullptr, nullptr, nullptr);
    spmm_csr<2><<<SPMM_BLOCKS, 256, 0, stream>>>(row_start, csr_cv, h2b, nullptr,
                                                 ybuf, feats, h1b, h2b);

    // GEMM1: hid = relu((y*0.25) @ W1 + b1)
    dim3 g1((N_NODES + BM1 - 1) / BM1, HID / BN1);    // (391, 2)
    gemm1_kernel<<<g1, 256, 0, stream>>>(ybuf, W1, b1, hid);

    // GEMM2 (K-split x2): partials into dead y region
    dim3 g2((N_NODES + G2_BM - 1) / G2_BM, 2);        // (391, 2)
    gemm2_kernel<<<g2, 256, 0, stream>>>(hid, W2, part0, part1);

    // double log_softmax (sums partials + bias) -> out
    lsm_kernel<<<(N_NODES + 3) / 4, 256, 0, stream>>>(part0, part1, b2, out);
}

// Round 12
// 387.616 us; speedup vs baseline: 1.4693x; 1.0097x over previous
//
#include <hip/hip_runtime.h>
#include <math.h>

#define N_NODES 50000
#define N_EDGES 800000
#define IN_DIM 128
#define HID 256
#define NCLASS 40

#define SCAN_NBLK 49   // ceil(50000 / 1024)

// ---------- bf16 helpers (RNE pack, cheap unpack) ----------
__device__ inline unsigned bf16pair(float a, float b) {
    unsigned ua = __float_as_uint(a), ub = __float_as_uint(b);
    ua = (ua + 0x7fffu + ((ua >> 16) & 1u)) >> 16;
    ub = (ub + 0x7fffu + ((ub >> 16) & 1u)) >> 16;
    return ua | (ub << 16);
}
__device__ inline float bf_lo(unsigned u) { return __uint_as_float(u << 16); }
__device__ inline float bf_hi(unsigned u) { return __uint_as_float(u & 0xffff0000u); }

// ---------------- convert feats -> bf16 (packed) ----------------
__global__ void to_bf16_kernel(const float4* __restrict__ f4,
                               uint2* __restrict__ o) {
    int i = blockIdx.x * blockDim.x + threadIdx.x;   // 1.6M float4s
    float4 v = f4[i];
    o[i] = make_uint2(bf16pair(v.x, v.y), bf16pair(v.z, v.w));
}

// ---------------- CSR build: count ----------------
__global__ void count_kernel(const int* __restrict__ rows,
                             int* __restrict__ counts) {
    int e = blockIdx.x * blockDim.x + threadIdx.x;
    if (e < N_EDGES) atomicAdd(&counts[rows[e]], 1);
}

// ---------------- hierarchical scan, phase 1: per-block sums ----------------
__global__ void block_sum_kernel(const int* __restrict__ counts,
                                 int* __restrict__ blockSums) {
    int t = threadIdx.x;
    int base = blockIdx.x * 1024 + t * 4;
    int s = 0;
    if (base < N_NODES) {
        int4 c = *(const int4*)(counts + base);
        s = c.x + c.y + c.z + c.w;
    }
    #pragma unroll
    for (int off = 32; off >= 1; off >>= 1)
        s += __shfl_xor(s, off);
    __shared__ int wsum[4];
    int lane = t & 63, wid = t >> 6;
    if (lane == 0) wsum[wid] = s;
    __syncthreads();
    if (t == 0)
        blockSums[blockIdx.x] = wsum[0] + wsum[1] + wsum[2] + wsum[3];
}

// ---------------- phase 2: scan the 49 block sums (single wave) ----------------
__global__ void block_offset_kernel(const int* __restrict__ blockSums,
                                    int* __restrict__ blockOffs,
                                    int* __restrict__ row_start) {
    int lane = threadIdx.x;          // 64 threads
    int x = (lane < SCAN_NBLK) ? blockSums[lane] : 0;
    #pragma unroll
    for (int off = 1; off < 64; off <<= 1) {
        int y = __shfl_up(x, off);
        if (lane >= off) x += y;
    }
    int excl = __shfl_up(x, 1);
    if (lane == 0) excl = 0;
    if (lane < SCAN_NBLK) blockOffs[lane] = excl;
    if (lane == SCAN_NBLK - 1) row_start[N_NODES] = x;   // grand total
}

// ---------------- phase 3: local scan + block offset -> row_start, cursor ----------------
__global__ void local_scan_kernel(const int* __restrict__ counts,
                                  const int* __restrict__ blockOffs,
                                  int* __restrict__ row_start,
                                  int* __restrict__ cursor) {
    int t = threadIdx.x;
    int base = blockIdx.x * 1024 + t * 4;
    int4 c = make_int4(0, 0, 0, 0);
    if (base < N_NODES) c = *(const int4*)(counts + base);
    int s0 = c.x, s1 = s0 + c.y, s2 = s1 + c.z, s3 = s2 + c.w;
    int tsum = s3;
    int lane = t & 63, wid = t >> 6;
    int x = tsum;
    #pragma unroll
    for (int off = 1; off < 64; off <<= 1) {
        int y = __shfl_up(x, off);
        if (lane >= off) x += y;
    }
    __shared__ int wsum[4];
    if (lane == 63) wsum[wid] = x;
    __syncthreads();
    int woff = 0;
    for (int i = 0; i < 4; ++i)
        if (i < wid) woff += wsum[i];
    int excl = x - tsum + woff + blockOffs[blockIdx.x];
    if (base < N_NODES) {
        int4 rs = make_int4(excl, excl + s0, excl + s1, excl + s2);
        *(int4*)(row_start + base) = rs;
        *(int4*)(cursor + base) = rs;
    }
}

// ---------------- CSR build: scatter (interleaved col+val, single 8B store) ----------------
__global__ void scatter_kernel(const int* __restrict__ rows,
                               const int* __restrict__ cols,
                               const float* __restrict__ vals,
                               int* __restrict__ cursor,
                               int2* __restrict__ csr_cv) {
    int e = blockIdx.x * blockDim.x + threadIdx.x;
    if (e >= N_EDGES) return;
    int pos = atomicAdd(&cursor[rows[e]], 1);
    csr_cv[pos] = make_int2(cols[e], __float_as_int(vals[e]));
}

// ---------------- SpMM (CSR, bf16 gather, fp32 accumulate) ----------------
// MODE 0: Hout_b[r] = bf16(acc)                         (hop 2)
// MODE 1: Hout_b[r] = bf16(0.5*acc)                     (hop 1, folds input scale)
// MODE 2: Yout[r]   = 0.5*feats[r] + h1[r] + h2[r] + acc (hop 3, fp32 combine)
template <int MODE>
__global__ void spmm_csr(const int* __restrict__ row_start,
                         const int2* __restrict__ csr_cv,
                         const uint2* __restrict__ Hin_b,
                         uint2* __restrict__ Hout_b,
                         float* __restrict__ Yout,
                         const float* __restrict__ feats,
                         const uint2* __restrict__ h1b,
                         const uint2* __restrict__ h2b) {
    int wave = (blockIdx.x * blockDim.x + threadIdx.x) >> 6;
    int lane = threadIdx.x & 63;
    if (wave >= N_NODES) return;
    int p = lane >> 5;          // which edge of the pair
    int q = lane & 31;          // dim group (4 dims)
    int start = row_start[wave];
    int end   = row_start[wave + 1];
    float4 acc = make_float4(0.f, 0.f, 0.f, 0.f);
    for (int base = start; base < end; base += 64) {
        int idx = base + lane;
        int c = 0; float v = 0.f;
        if (idx < end) {
            int2 cv = csr_cv[idx];
            c = cv.x;
            v = __int_as_float(cv.y);
        }
        int cnt = min(64, end - base);
        for (int j = 0; j < cnt; j += 2) {
            int src = j + p;                   // v==0 beyond cnt
            int   cj = __shfl(c, src);
            float vj = __shfl(v, src);
            uint2 h = Hin_b[(size_t)cj * 32 + q];   // 4 bf16 = 8 B
            acc.x += vj * bf_lo(h.x);
            acc.y += vj * bf_hi(h.x);
            acc.z += vj * bf_lo(h.y);
            acc.w += vj * bf_hi(h.y);
        }
    }
    acc.x += __shfl_xor(acc.x, 32);
    acc.y += __shfl_xor(acc.y, 32);
    acc.z += __shfl_xor(acc.z, 32);
    acc.w += __shfl_xor(acc.w, 32);
    if (p == 0) {
        size_t o32 = (size_t)wave * 32 + q;
        if (MODE == 1) {
            acc.x *= 0.5f; acc.y *= 0.5f; acc.z *= 0.5f; acc.w *= 0.5f;
            Hout_b[o32] = make_uint2(bf16pair(acc.x, acc.y), bf16pair(acc.z, acc.w));
        } else if (MODE == 0) {
            Hout_b[o32] = make_uint2(bf16pair(acc.x, acc.y), bf16pair(acc.z, acc.w));
        } else {
            size_t o = (size_t)wave * IN_DIM + q * 4;
            float4 f = *(const float4*)(feats + o);
            uint2 a = h1b[o32];
            uint2 b = h2b[o32];
            acc.x += 0.5f * f.x + bf_lo(a.x) + bf_lo(b.x);
            acc.y += 0.5f * f.y + bf_hi(a.x) + bf_hi(b.x);
            acc.z += 0.5f * f.z + bf_lo(a.y) + bf_lo(b.y);
            acc.w += 0.5f * f.w + bf_hi(a.y) + bf_hi(b.y);
            *(float4*)(Yout + o) = acc;
        }
    }
}

// ---------------- GEMM1: H1 = relu((y*0.25) @ W1 + b1) ----------------
// 128x128 tile, BK=16. Micro-tile 8 rows x (4+4 split cols):
// thread tc owns cols {tc*4..+3} and {64+tc*4..+3} ->
//   - stores: 16 lanes x 16 B contiguous per instruction (256 B/row segments)
//   - Bs b128 reads at 4*tc stride -> 2-way bank aliasing (free)
#define BM1 128
#define BN1 128
#define BK1 16
__global__ void gemm1_kernel(const float* __restrict__ Y,
                             const float* __restrict__ W1,
                             const float* __restrict__ bias1,
                             float* __restrict__ H1) {
    __shared__ float As[BK1][BM1 + 4];   // transposed A tile
    __shared__ float Bs[BK1][BN1 + 4];
    int tid = threadIdx.x;               // 256
    int tr = tid >> 4, tc = tid & 15;    // 16x16 thread grid
    int row0 = blockIdx.x * BM1;
    int col0 = blockIdx.y * BN1;
    float acc[8][8] = {};                // [row][col: 0..3 lo group, 4..7 hi group]
    for (int k0 = 0; k0 < IN_DIM; k0 += BK1) {   // 8 k-tiles
        #pragma unroll
        for (int i = tid; i < 512; i += 256) {
            int r = i >> 2, c4 = i & 3;
            int gr = row0 + r;
            float4 v = make_float4(0.f, 0.f, 0.f, 0.f);
            if (gr < N_NODES)
                v = *(const float4*)(Y + (size_t)gr * IN_DIM + k0 + c4 * 4);
            As[c4 * 4 + 0][r] = v.x * 0.25f;
            As[c4 * 4 + 1][r] = v.y * 0.25f;
            As[c4 * 4 + 2][r] = v.z * 0.25f;
            As[c4 * 4 + 3][r] = v.w * 0.25f;
        }
        #pragma unroll
        for (int i = tid; i < 512; i += 256) {
            int c = i >> 5, n4 = i & 31;
            float4 w = *(const float4*)(W1 + (size_t)(k0 + c) * HID + col0 + n4 * 4);
            *(float4*)&Bs[c][n4 * 4] = w;
        }
        __syncthreads();
        #pragma unroll
        for (int kk = 0; kk < BK1; ++kk) {
            float4 a0 = *(const float4*)&As[kk][tr * 8];
            float4 a1 = *(const float4*)&As[kk][tr * 8 + 4];
            float4 b0 = *(const float4*)&Bs[kk][tc * 4];        // lo col group
            float4 b1v = *(const float4*)&Bs[kk][64 + tc * 4];  // hi col group
            float a[8] = {a0.x, a0.y, a0.z, a0.w, a1.x, a1.y, a1.z, a1.w};
            float b[8] = {b0.x, b0.y, b0.z, b0.w, b1v.x, b1v.y, b1v.z, b1v.w};
            #pragma unroll
            for (int i = 0; i < 8; ++i)
                #pragma unroll
                for (int j = 0; j < 8; ++j)
                    acc[i][j] += a[i] * b[j];
        }
        __syncthreads();
    }
    float4 bb0 = *(const float4*)(bias1 + col0 + tc * 4);
    float4 bb1 = *(const float4*)(bias1 + col0 + 64 + tc * 4);
    float bb[8] = {bb0.x, bb0.y, bb0.z, bb0.w, bb1.x, bb1.y, bb1.z, bb1.w};
    #pragma unroll
    for (int i = 0; i < 8; ++i) {
        int gr = row0 + tr * 8 + i;
        if (gr >= N_NODES) continue;
        float o[8];
        #pragma unroll
        for (int j = 0; j < 8; ++j) {
            float v = acc[i][j] + bb[j];
            o[j] = v > 0.f ? v : 0.f;
        }
        float* dst = H1 + (size_t)gr * HID + col0;
        *(float4*)(dst + tc * 4)      = make_float4(o[0], o[1], o[2], o[3]);
        *(float4*)(dst + 64 + tc * 4) = make_float4(o[4], o[5], o[6], o[7]);
    }
}

// ---------------- GEMM2 (K-split x2): partial = H1[:, khalf] @ W2[khalf, :] ----------------
// BM=128, BN=40 exact, BK=32; 256 threads = 32 rt x 8 ct; micro 4x5.
#define G2_BM 128
#define G2_BK 32
__global__ void gemm2_kernel(const float* __restrict__ H1,
                             const float* __restrict__ W2,
                             float* __restrict__ part0,
                             float* __restrict__ part1) {
    __shared__ float As[G2_BK][G2_BM + 4];   // transposed A
    __shared__ float Bs[G2_BK][44];          // 32 x 40, row pad to 44
    int tid = threadIdx.x;                   // 256
    int rt = tid >> 3;                       // 0..31, 4 rows each
    int ct = tid & 7;                        // 0..7, 5 cols each
    int row0 = blockIdx.x * G2_BM;
    int kbase = blockIdx.y * (HID / 2);      // 0 or 128
    float* outp = blockIdx.y ? part1 : part0;
    float acc[4][5] = {};
    for (int kt = 0; kt < HID / 2; kt += G2_BK) {    // 4 k-tiles
        int k0 = kbase + kt;
        #pragma unroll
        for (int i = tid; i < 1024; i += 256) {
            int r = i >> 3, u = i & 7;
            int gr = row0 + r;
            float4 v = make_float4(0.f, 0.f, 0.f, 0.f);
            if (gr < N_NODES)
                v = *(const float4*)(H1 + (size_t)gr * HID + k0 + u * 4);
            int kb = u * 4;
            As[kb + 0][r] = v.x;
            As[kb + 1][r] = v.y;
            As[kb + 2][r] = v.z;
            As[kb + 3][r] = v.w;
        }
        for (int i = tid; i < 320; i += 256) {
            int r = i / 10, cg = i % 10;
            float4 w = *(const float4*)(W2 + (size_t)(k0 + r) * NCLASS + cg * 4);
            *(float4*)&Bs[r][cg * 4] = w;
        }
        __syncthreads();
        #pragma unroll
        for (int kk = 0; kk < G2_BK; ++kk) {
            float4 a0 = *(const float4*)&As[kk][rt * 4];
            float a[4] = {a0.x, a0.y, a0.z, a0.w};
            float b[5];
            #pragma unroll
            for (int j = 0; j < 5; ++j) b[j] = Bs[kk][ct * 5 + j];
            #pragma unroll
            for (int i = 0; i < 4; ++i)
                #pragma unroll
                for (int j = 0; j < 5; ++j)
                    acc[i][j] += a[i] * b[j];
        }
        __syncthreads();
    }
    #pragma unroll
    for (int i = 0; i < 4; ++i) {
        int gr = row0 + rt * 4 + i;
        if (gr >= N_NODES) continue;
        float* dst = outp + (size_t)gr * NCLASS + ct * 5;
        #pragma unroll
        for (int j = 0; j < 5; ++j)
            dst[j] = acc[i][j];
    }
}

// ---------------- double log_softmax (sums K-split partials + bias) ----------------
__global__ void lsm_kernel(const float* __restrict__ part0,
                           const float* __restrict__ part1,
                           const float* __restrict__ b2,
                           float* __restrict__ Out) {
    int wave = threadIdx.x >> 6;
    int lane = threadIdx.x & 63;
    int row = blockIdx.x * 4 + wave;
    if (row >= N_NODES) return;

    float acc = -INFINITY;
    if (lane < NCLASS) {
        size_t idx = (size_t)row * NCLASS + lane;
        acc = part0[idx] + part1[idx] + b2[lane];
    }

    float m = acc;
    #pragma unroll
    for (int off = 32; off >= 1; off >>= 1)
        m = fmaxf(m, __shfl_xor(m, off));
    float ex = (lane < NCLASS) ? expf(acc - m) : 0.f;
    float s = ex;
    #pragma unroll
    for (int off = 32; off >= 1; off >>= 1)
        s += __shfl_xor(s, off);
    float z1 = acc - (m + logf(s));

    float m2 = z1;
    #pragma unroll
    for (int off = 32; off >= 1; off >>= 1)
        m2 = fmaxf(m2, __shfl_xor(m2, off));
    float ex2 = (lane < NCLASS) ? expf(z1 - m2) : 0.f;
    float s2 = ex2;
    #pragma unroll
    for (int off = 32; off >= 1; off >>= 1)
        s2 += __shfl_xor(s2, off);
    float z2 = z1 - (m2 + logf(s2));

    if (lane < NCLASS)
        Out[(size_t)row * NCLASS + lane] = z2;
}

extern "C" void kernel_launch(void* const* d_in, const int* in_sizes, int n_in,
                              void* d_out, int out_size, void* d_ws, size_t ws_size,
                              hipStream_t stream) {
    const float* feats   = (const float*)d_in[0];
    const int*   e_row   = (const int*)d_in[1];
    const int*   e_col   = (const int*)d_in[2];
    const float* e_vals  = (const float*)d_in[3];
    const float* W1      = (const float*)d_in[4];
    const float* b1      = (const float*)d_in[5];
    const float* W2      = (const float*)d_in[6];
    const float* b2      = (const float*)d_in[7];
    float* out = (float*)d_out;

    // Workspace (19.2M floats proven):
    //   y    : [0, 6.4M)            fp32 MLP input
    //   fb16 : [6.4M, 9.6M)         feats in bf16
    //   h1b  : [9.6M, 12.8M)        hop1 out, bf16
    //   h2b  : [12.8M, 16M)         hop2 out, bf16
    //   hid  : [6.4M, 19.2M)        gemm1 out fp32 (bf16 bufs dead by then)
    //   part0: [0, 2M)  part1: [2M, 4M)   (y dead after gemm1)
    float* ws    = (float*)d_ws;
    float* ybuf  = ws;
    uint2* fb16  = (uint2*)(ws + (size_t)N_NODES * IN_DIM);
    uint2* h1b   = (uint2*)(ws + (size_t)N_NODES * IN_DIM * 3 / 2);
    uint2* h2b   = (uint2*)(ws + (size_t)N_NODES * IN_DIM * 2);
    float* hid   = ws + (size_t)N_NODES * IN_DIM;
    float* part0 = ws;
    float* part1 = ws + (size_t)N_NODES * NCLASS;

    // CSR scratch in d_out (8 MB; fully overwritten by lsm_kernel at the end).
    int2*  csr_cv    = (int2*)d_out;                     // interleaved (col,val)
    int*   counts    = (int*)d_out + 2 * N_EDGES;        // [1600000, 1650000)
    int*   cursor    = counts + N_NODES;                 // [1650000, 1700000)
    int*   row_start = cursor + N_NODES;                 // [1700000, 1750001)
    int*   blockSums = row_start + N_NODES + 4;
    int*   blockOffs = blockSums + 64;                   // < 2000000

    // zero counts (200 KB)
    hipMemsetAsync(counts, 0, N_NODES * sizeof(int), stream);

    // feats -> bf16 (packed)
    const int ELEMS4 = N_NODES * IN_DIM / 4;  // 1.6M float4s
    to_bf16_kernel<<<ELEMS4 / 256, 256, 0, stream>>>((const float4*)feats, fb16);

    // Build CSR: count -> hierarchical scan -> scatter
    const int EG = N_EDGES / 256;             // 3125 exact
    count_kernel<<<EG, 256, 0, stream>>>(e_row, counts);
    block_sum_kernel<<<SCAN_NBLK, 256, 0, stream>>>(counts, blockSums);
    block_offset_kernel<<<1, 64, 0, stream>>>(blockSums, blockOffs, row_start);
    local_scan_kernel<<<SCAN_NBLK, 256, 0, stream>>>(counts, blockOffs, row_start, cursor);
    scatter_kernel<<<EG, 256, 0, stream>>>(e_row, e_col, e_vals, cursor, csr_cv);

    // 3 propagation hops (bf16 gather, fp32 accumulate; hop3 fuses fp32 combine)
    const int SPMM_BLOCKS = N_NODES / 4;      // 12500 (4 waves/block)
    spmm_csr<1><<<SPMM_BLOCKS, 256, 0, stream>>>(row_start, csr_cv, fb16, h1b,
                                                 nullptr, nullptr, nullptr, nullptr);
    spmm_csr<0><<<SPMM_BLOCKS, 256, 0, stream>>>(row_start, csr_cv, h1b, h2b,
                                                 nullptr, nullptr, nullptr, nullptr);
    spmm_csr<2><<<SPMM_BLOCKS, 256, 0, stream>>>(row_start, csr_cv, h2b, nullptr,
                                                 ybuf, feats, h1b, h2b);

    // GEMM1: hid = relu((y*0.25) @ W1 + b1)
    dim3 g1((N_NODES + BM1 - 1) / BM1, HID / BN1);    // (391, 2)
    gemm1_kernel<<<g1, 256, 0, stream>>>(ybuf, W1, b1, hid);

    // GEMM2 (K-split x2): partials into dead y region
    dim3 g2((N_NODES + G2_BM - 1) / G2_BM, 2);        // (391, 2)
    gemm2_kernel<<<g2, 256, 0, stream>>>(hid, W2, part0, part1);

    // double log_softmax (sums partials + bias) -> out
    lsm_kernel<<<(N_NODES + 3) / 4, 256, 0, stream>>>(part0, part1, b2, out);
}

// Round 13
// 386.505 us; speedup vs baseline: 1.4735x; 1.0029x over previous
//
#include <hip/hip_runtime.h>
#include <math.h>

#define N_NODES 50000
#define N_EDGES 800000
#define IN_DIM 128
#define HID 256
#define NCLASS 40

#define SCAN_NBLK 49   // ceil(50000 / 1024)

// ---------- bf16 helpers (RNE pack, cheap unpack) ----------
__device__ inline unsigned bf16pair(float a, float b) {
    unsigned ua = __float_as_uint(a), ub = __float_as_uint(b);
    ua = (ua + 0x7fffu + ((ua >> 16) & 1u)) >> 16;
    ub = (ub + 0x7fffu + ((ub >> 16) & 1u)) >> 16;
    return ua | (ub << 16);
}
__device__ inline float bf_lo(unsigned u) { return __uint_as_float(u << 16); }
__device__ inline float bf_hi(unsigned u) { return __uint_as_float(u & 0xffff0000u); }

// ---------------- convert feats -> bf16 (packed) ----------------
__global__ void to_bf16_kernel(const float4* __restrict__ f4,
                               uint2* __restrict__ o) {
    int i = blockIdx.x * blockDim.x + threadIdx.x;   // 1.6M float4s
    float4 v = f4[i];
    o[i] = make_uint2(bf16pair(v.x, v.y), bf16pair(v.z, v.w));
}

// ---------------- CSR build: count ----------------
__global__ void count_kernel(const int* __restrict__ rows,
                             int* __restrict__ counts) {
    int e = blockIdx.x * blockDim.x + threadIdx.x;
    if (e < N_EDGES) atomicAdd(&counts[rows[e]], 1);
}

// ---------------- hierarchical scan, phase 1: per-block sums ----------------
__global__ void block_sum_kernel(const int* __restrict__ counts,
                                 int* __restrict__ blockSums) {
    int t = threadIdx.x;
    int base = blockIdx.x * 1024 + t * 4;
    int s = 0;
    if (base < N_NODES) {
        int4 c = *(const int4*)(counts + base);
        s = c.x + c.y + c.z + c.w;
    }
    #pragma unroll
    for (int off = 32; off >= 1; off >>= 1)
        s += __shfl_xor(s, off);
    __shared__ int wsum[4];
    int lane = t & 63, wid = t >> 6;
    if (lane == 0) wsum[wid] = s;
    __syncthreads();
    if (t == 0)
        blockSums[blockIdx.x] = wsum[0] + wsum[1] + wsum[2] + wsum[3];
}

// ---------------- phase 2: scan the 49 block sums (single wave) ----------------
__global__ void block_offset_kernel(const int* __restrict__ blockSums,
                                    int* __restrict__ blockOffs,
                                    int* __restrict__ row_start) {
    int lane = threadIdx.x;          // 64 threads
    int x = (lane < SCAN_NBLK) ? blockSums[lane] : 0;
    #pragma unroll
    for (int off = 1; off < 64; off <<= 1) {
        int y = __shfl_up(x, off);
        if (lane >= off) x += y;
    }
    int excl = __shfl_up(x, 1);
    if (lane == 0) excl = 0;
    if (lane < SCAN_NBLK) blockOffs[lane] = excl;
    if (lane == SCAN_NBLK - 1) row_start[N_NODES] = x;   // grand total
}

// ---------------- phase 3: local scan + block offset -> row_start, cursor ----------------
__global__ void local_scan_kernel(const int* __restrict__ counts,
                                  const int* __restrict__ blockOffs,
                                  int* __restrict__ row_start,
                                  int* __restrict__ cursor) {
    int t = threadIdx.x;
    int base = blockIdx.x * 1024 + t * 4;
    int4 c = make_int4(0, 0, 0, 0);
    if (base < N_NODES) c = *(const int4*)(counts + base);
    int s0 = c.x, s1 = s0 + c.y, s2 = s1 + c.z, s3 = s2 + c.w;
    int tsum = s3;
    int lane = t & 63, wid = t >> 6;
    int x = tsum;
    #pragma unroll
    for (int off = 1; off < 64; off <<= 1) {
        int y = __shfl_up(x, off);
        if (lane >= off) x += y;
    }
    __shared__ int wsum[4];
    if (lane == 63) wsum[wid] = x;
    __syncthreads();
    int woff = 0;
    for (int i = 0; i < 4; ++i)
        if (i < wid) woff += wsum[i];
    int excl = x - tsum + woff + blockOffs[blockIdx.x];
    if (base < N_NODES) {
        int4 rs = make_int4(excl, excl + s0, excl + s1, excl + s2);
        *(int4*)(row_start + base) = rs;
        *(int4*)(cursor + base) = rs;
    }
}

// ---------------- CSR build: scatter (interleaved col+val, single 8B store) ----------------
__global__ void scatter_kernel(const int* __restrict__ rows,
                               const int* __restrict__ cols,
                               const float* __restrict__ vals,
                               int* __restrict__ cursor,
                               int2* __restrict__ csr_cv) {
    int e = blockIdx.x * blockDim.x + threadIdx.x;
    if (e >= N_EDGES) return;
    int pos = atomicAdd(&cursor[rows[e]], 1);
    csr_cv[pos] = make_int2(cols[e], __float_as_int(vals[e]));
}

// ---------------- SpMM (CSR, bf16 gather, fp32 accumulate) ----------------
// MODE 0: Hout_b[r] = bf16(acc)                         (hop 2)
// MODE 1: Hout_b[r] = bf16(0.5*acc)                     (hop 1, folds input scale)
// MODE 2: Yout[r]   = 0.5*feats[r] + h1[r] + h2[r] + acc (hop 3, fp32 combine)
template <int MODE>
__global__ void spmm_csr(const int* __restrict__ row_start,
                         const int2* __restrict__ csr_cv,
                         const uint2* __restrict__ Hin_b,
                         uint2* __restrict__ Hout_b,
                         float* __restrict__ Yout,
                         const float* __restrict__ feats,
                         const uint2* __restrict__ h1b,
                         const uint2* __restrict__ h2b) {
    int wave = (blockIdx.x * blockDim.x + threadIdx.x) >> 6;
    int lane = threadIdx.x & 63;
    if (wave >= N_NODES) return;
    int p = lane >> 5;          // which edge of the pair
    int q = lane & 31;          // dim group (4 dims)
    int start = row_start[wave];
    int end   = row_start[wave + 1];
    float4 acc = make_float4(0.f, 0.f, 0.f, 0.f);
    for (int base = start; base < end; base += 64) {
        int idx = base + lane;
        int c = 0; float v = 0.f;
        if (idx < end) {
            int2 cv = csr_cv[idx];
            c = cv.x;
            v = __int_as_float(cv.y);
        }
        int cnt = min(64, end - base);
        for (int j = 0; j < cnt; j += 2) {
            int src = j + p;                   // v==0 beyond cnt
            int   cj = __shfl(c, src);
            float vj = __shfl(v, src);
            uint2 h = Hin_b[(size_t)cj * 32 + q];   // 4 bf16 = 8 B
            acc.x += vj * bf_lo(h.x);
            acc.y += vj * bf_hi(h.x);
            acc.z += vj * bf_lo(h.y);
            acc.w += vj * bf_hi(h.y);
        }
    }
    acc.x += __shfl_xor(acc.x, 32);
    acc.y += __shfl_xor(acc.y, 32);
    acc.z += __shfl_xor(acc.z, 32);
    acc.w += __shfl_xor(acc.w, 32);
    if (p == 0) {
        size_t o32 = (size_t)wave * 32 + q;
        if (MODE == 1) {
            acc.x *= 0.5f; acc.y *= 0.5f; acc.z *= 0.5f; acc.w *= 0.5f;
            Hout_b[o32] = make_uint2(bf16pair(acc.x, acc.y), bf16pair(acc.z, acc.w));
        } else if (MODE == 0) {
            Hout_b[o32] = make_uint2(bf16pair(acc.x, acc.y), bf16pair(acc.z, acc.w));
        } else {
            size_t o = (size_t)wave * IN_DIM + q * 4;
            float4 f = *(const float4*)(feats + o);
            uint2 a = h1b[o32];
            uint2 b = h2b[o32];
            acc.x += 0.5f * f.x + bf_lo(a.x) + bf_lo(b.x);
            acc.y += 0.5f * f.y + bf_hi(a.x) + bf_hi(b.x);
            acc.z += 0.5f * f.z + bf_lo(a.y) + bf_lo(b.y);
            acc.w += 0.5f * f.w + bf_hi(a.y) + bf_hi(b.y);
            *(float4*)(Yout + o) = acc;
        }
    }
}

// ---------------- GEMM1: H1 = relu((y*0.25) @ W1 + b1) ----------------
// 128x64 tile, BK=16, micro 8x4, 256 threads. Grid (391,4) = 1564 blocks ->
// ~6 blocks/CU (~24 waves/CU) to hide staging latency (was 22% occupancy at BN=128).
#define BM1 128
#define BN1 64
#define BK1 16
__global__ void gemm1_kernel(const float* __restrict__ Y,
                             const float* __restrict__ W1,
                             const float* __restrict__ bias1,
                             float* __restrict__ H1) {
    __shared__ float As[BK1][BM1 + 4];   // transposed A tile
    __shared__ float Bs[BK1][BN1 + 4];
    int tid = threadIdx.x;               // 256
    int tr = tid >> 4, tc = tid & 15;    // 16x16 thread grid
    int row0 = blockIdx.x * BM1;
    int col0 = blockIdx.y * BN1;
    float acc[8][4] = {};
    for (int k0 = 0; k0 < IN_DIM; k0 += BK1) {   // 8 k-tiles
        // stage A (128x16) transposed: 512 float4, 2 per thread
        #pragma unroll
        for (int i = tid; i < 512; i += 256) {
            int r = i >> 2, c4 = i & 3;
            int gr = row0 + r;
            float4 v = make_float4(0.f, 0.f, 0.f, 0.f);
            if (gr < N_NODES)
                v = *(const float4*)(Y + (size_t)gr * IN_DIM + k0 + c4 * 4);
            As[c4 * 4 + 0][r] = v.x * 0.25f;
            As[c4 * 4 + 1][r] = v.y * 0.25f;
            As[c4 * 4 + 2][r] = v.z * 0.25f;
            As[c4 * 4 + 3][r] = v.w * 0.25f;
        }
        // stage B (16x64): 256 float4, 1 per thread
        {
            int c = tid >> 4, n4 = tid & 15;
            float4 w = *(const float4*)(W1 + (size_t)(k0 + c) * HID + col0 + n4 * 4);
            *(float4*)&Bs[c][n4 * 4] = w;
        }
        __syncthreads();
        #pragma unroll
        for (int kk = 0; kk < BK1; ++kk) {
            float4 a0 = *(const float4*)&As[kk][tr * 8];
            float4 a1 = *(const float4*)&As[kk][tr * 8 + 4];
            float4 b0 = *(const float4*)&Bs[kk][tc * 4];
            float a[8] = {a0.x, a0.y, a0.z, a0.w, a1.x, a1.y, a1.z, a1.w};
            float b[4] = {b0.x, b0.y, b0.z, b0.w};
            #pragma unroll
            for (int i = 0; i < 8; ++i)
                #pragma unroll
                for (int j = 0; j < 4; ++j)
                    acc[i][j] += a[i] * b[j];
        }
        __syncthreads();
    }
    float4 bb0 = *(const float4*)(bias1 + col0 + tc * 4);
    float bb[4] = {bb0.x, bb0.y, bb0.z, bb0.w};
    #pragma unroll
    for (int i = 0; i < 8; ++i) {
        int gr = row0 + tr * 8 + i;
        if (gr >= N_NODES) continue;
        float o[4];
        #pragma unroll
        for (int j = 0; j < 4; ++j) {
            float v = acc[i][j] + bb[j];
            o[j] = v > 0.f ? v : 0.f;
        }
        *(float4*)(H1 + (size_t)gr * HID + col0 + tc * 4) =
            make_float4(o[0], o[1], o[2], o[3]);
    }
}

// ---------------- GEMM2 (K-split x2): partial = H1[:, khalf] @ W2[khalf, :] ----------------
// BM=128, BN=40 exact, BK=32; 256 threads = 32 rt x 8 ct; micro 4x5.
#define G2_BM 128
#define G2_BK 32
__global__ void gemm2_kernel(const float* __restrict__ H1,
                             const float* __restrict__ W2,
                             float* __restrict__ part0,
                             float* __restrict__ part1) {
    __shared__ float As[G2_BK][G2_BM + 4];   // transposed A
    __shared__ float Bs[G2_BK][44];          // 32 x 40, row pad to 44
    int tid = threadIdx.x;                   // 256
    int rt = tid >> 3;                       // 0..31, 4 rows each
    int ct = tid & 7;                        // 0..7, 5 cols each
    int row0 = blockIdx.x * G2_BM;
    int kbase = blockIdx.y * (HID / 2);      // 0 or 128
    float* outp = blockIdx.y ? part1 : part0;
    float acc[4][5] = {};
    for (int kt = 0; kt < HID / 2; kt += G2_BK) {    // 4 k-tiles
        int k0 = kbase + kt;
        #pragma unroll
        for (int i = tid; i < 1024; i += 256) {
            int r = i >> 3, u = i & 7;
            int gr = row0 + r;
            float4 v = make_float4(0.f, 0.f, 0.f, 0.f);
            if (gr < N_NODES)
                v = *(const float4*)(H1 + (size_t)gr * HID + k0 + u * 4);
            int kb = u * 4;
            As[kb + 0][r] = v.x;
            As[kb + 1][r] = v.y;
            As[kb + 2][r] = v.z;
            As[kb + 3][r] = v.w;
        }
        for (int i = tid; i < 320; i += 256) {
            int r = i / 10, cg = i % 10;
            float4 w = *(const float4*)(W2 + (size_t)(k0 + r) * NCLASS + cg * 4);
            *(float4*)&Bs[r][cg * 4] = w;
        }
        __syncthreads();
        #pragma unroll
        for (int kk = 0; kk < G2_BK; ++kk) {
            float4 a0 = *(const float4*)&As[kk][rt * 4];
            float a[4] = {a0.x, a0.y, a0.z, a0.w};
            float b[5];
            #pragma unroll
            for (int j = 0; j < 5; ++j) b[j] = Bs[kk][ct * 5 + j];
            #pragma unroll
            for (int i = 0; i < 4; ++i)
                #pragma unroll
                for (int j = 0; j < 5; ++j)
                    acc[i][j] += a[i] * b[j];
        }
        __syncthreads();
    }
    #pragma unroll
    for (int i = 0; i < 4; ++i) {
        int gr = row0 + rt * 4 + i;
        if (gr >= N_NODES) continue;
        float* dst = outp + (size_t)gr * NCLASS + ct * 5;
        #pragma unroll
        for (int j = 0; j < 5; ++j)
            dst[j] = acc[i][j];
    }
}

// ---------------- double log_softmax (sums K-split partials + bias) ----------------
__global__ void lsm_kernel(const float* __restrict__ part0,
                           const float* __restrict__ part1,
                           const float* __restrict__ b2,
                           float* __restrict__ Out) {
    int wave = threadIdx.x >> 6;
    int lane = threadIdx.x & 63;
    int row = blockIdx.x * 4 + wave;
    if (row >= N_NODES) return;

    float acc = -INFINITY;
    if (lane < NCLASS) {
        size_t idx = (size_t)row * NCLASS + lane;
        acc = part0[idx] + part1[idx] + b2[lane];
    }

    float m = acc;
    #pragma unroll
    for (int off = 32; off >= 1; off >>= 1)
        m = fmaxf(m, __shfl_xor(m, off));
    float ex = (lane < NCLASS) ? expf(acc - m) : 0.f;
    float s = ex;
    #pragma unroll
    for (int off = 32; off >= 1; off >>= 1)
        s += __shfl_xor(s, off);
    float z1 = acc - (m + logf(s));

    float m2 = z1;
    #pragma unroll
    for (int off = 32; off >= 1; off >>= 1)
        m2 = fmaxf(m2, __shfl_xor(m2, off));
    float ex2 = (lane < NCLASS) ? expf(z1 - m2) : 0.f;
    float s2 = ex2;
    #pragma unroll
    for (int off = 32; off >= 1; off >>= 1)
        s2 += __shfl_xor(s2, off);
    float z2 = z1 - (m2 + logf(s2));

    if (lane < NCLASS)
        Out[(size_t)row * NCLASS + lane] = z2;
}

extern "C" void kernel_launch(void* const* d_in, const int* in_sizes, int n_in,
                              void* d_out, int out_size, void* d_ws, size_t ws_size,
                              hipStream_t stream) {
    const float* feats   = (const float*)d_in[0];
    const int*   e_row   = (const int*)d_in[1];
    const int*   e_col   = (const int*)d_in[2];
    const float* e_vals  = (const float*)d_in[3];
    const float* W1      = (const float*)d_in[4];
    const float* b1      = (const float*)d_in[5];
    const float* W2      = (const float*)d_in[6];
    const float* b2      = (const float*)d_in[7];
    float* out = (float*)d_out;

    // Workspace (19.2M floats proven):
    //   y    : [0, 6.4M)            fp32 MLP input
    //   fb16 : [6.4M, 9.6M)         feats in bf16
    //   h1b  : [9.6M, 12.8M)        hop1 out, bf16
    //   h2b  : [12.8M, 16M)         hop2 out, bf16
    //   hid  : [6.4M, 19.2M)        gemm1 out fp32 (bf16 bufs dead by then)
    //   part0: [0, 2M)  part1: [2M, 4M)   (y dead after gemm1)
    float* ws    = (float*)d_ws;
    float* ybuf  = ws;
    uint2* fb16  = (uint2*)(ws + (size_t)N_NODES * IN_DIM);
    uint2* h1b   = (uint2*)(ws + (size_t)N_NODES * IN_DIM * 3 / 2);
    uint2* h2b   = (uint2*)(ws + (size_t)N_NODES * IN_DIM * 2);
    float* hid   = ws + (size_t)N_NODES * IN_DIM;
    float* part0 = ws;
    float* part1 = ws + (size_t)N_NODES * NCLASS;

    // CSR scratch in d_out (8 MB; fully overwritten by lsm_kernel at the end).
    int2*  csr_cv    = (int2*)d_out;                     // interleaved (col,val)
    int*   counts    = (int*)d_out + 2 * N_EDGES;        // [1600000, 1650000)
    int*   cursor    = counts + N_NODES;                 // [1650000, 1700000)
    int*   row_start = cursor + N_NODES;                 // [1700000, 1750001)
    int*   blockSums = row_start + N_NODES + 4;
    int*   blockOffs = blockSums + 64;                   // < 2000000

    // zero counts (200 KB)
    hipMemsetAsync(counts, 0, N_NODES * sizeof(int), stream);

    // feats -> bf16 (packed)
    const int ELEMS4 = N_NODES * IN_DIM / 4;  // 1.6M float4s
    to_bf16_kernel<<<ELEMS4 / 256, 256, 0, stream>>>((const float4*)feats, fb16);

    // Build CSR: count -> hierarchical scan -> scatter
    const int EG = N_EDGES / 256;             // 3125 exact
    count_kernel<<<EG, 256, 0, stream>>>(e_row, counts);
    block_sum_kernel<<<SCAN_NBLK, 256, 0, stream>>>(counts, blockSums);
    block_offset_kernel<<<1, 64, 0, stream>>>(blockSums, blockOffs, row_start);
    local_scan_kernel<<<SCAN_NBLK, 256, 0, stream>>>(counts, blockOffs, row_start, cursor);
    scatter_kernel<<<EG, 256, 0, stream>>>(e_row, e_col, e_vals, cursor, csr_cv);

    // 3 propagation hops (bf16 gather, fp32 accumulate; hop3 fuses fp32 combine)
    const int SPMM_BLOCKS = N_NODES / 4;      // 12500 (4 waves/block)
    spmm_csr<1><<<SPMM_BLOCKS, 256, 0, stream>>>(row_start, csr_cv, fb16, h1b,
                                                 nullptr, nullptr, nullptr, nullptr);
    spmm_csr<0><<<SPMM_BLOCKS, 256, 0, stream>>>(row_start, csr_cv, h1b, h2b,
                                                 nullptr, nullptr, nullptr, nullptr);
    spmm_csr<2><<<SPMM_BLOCKS, 256, 0, stream>>>(row_start, csr_cv, h2b, nullptr,
                                                 ybuf, feats, h1b, h2b);

    // GEMM1: hid = relu((y*0.25) @ W1 + b1)
    dim3 g1((N_NODES + BM1 - 1) / BM1, HID / BN1);    // (391, 4)
    gemm1_kernel<<<g1, 256, 0, stream>>>(ybuf, W1, b1, hid);

    // GEMM2 (K-split x2): partials into dead y region
    dim3 g2((N_NODES + G2_BM - 1) / G2_BM, 2);        // (391, 2)
    gemm2_kernel<<<g2, 256, 0, stream>>>(hid, W2, part0, part1);

    // double log_softmax (sums partials + bias) -> out
    lsm_kernel<<<(N_NODES + 3) / 4, 256, 0, stream>>>(part0, part1, b2, out);
}

// Round 14
// 354.769 us; speedup vs baseline: 1.6054x; 1.0895x over previous
//
#include <hip/hip_runtime.h>
#include <math.h>

#define N_NODES 50000
#define N_EDGES 800000
#define IN_DIM 128
#define HID 256
#define NCLASS 40

#define SCAN_NBLK 49   // ceil(50000 / 1024)

typedef __attribute__((ext_vector_type(8))) short short8;
typedef __attribute__((ext_vector_type(4))) float floatx4;

// ---------- bf16 helpers (RNE pack, cheap unpack) ----------
__device__ inline unsigned bf16pair(float a, float b) {
    unsigned ua = __float_as_uint(a), ub = __float_as_uint(b);
    ua = (ua + 0x7fffu + ((ua >> 16) & 1u)) >> 16;
    ub = (ub + 0x7fffu + ((ub >> 16) & 1u)) >> 16;
    return ua | (ub << 16);
}
__device__ inline float bf_lo(unsigned u) { return __uint_as_float(u << 16); }
__device__ inline float bf_hi(unsigned u) { return __uint_as_float(u & 0xffff0000u); }

// ---------------- convert feats -> bf16 (packed) ----------------
__global__ void to_bf16_kernel(const float4* __restrict__ f4,
                               uint2* __restrict__ o) {
    int i = blockIdx.x * blockDim.x + threadIdx.x;   // 1.6M float4s
    float4 v = f4[i];
    o[i] = make_uint2(bf16pair(v.x, v.y), bf16pair(v.z, v.w));
}

// ---------------- W1 -> bf16 MFMA B-fragment layout ----------------
// W1frag[((h*8 + t)*4 + s)*64 + lane] = uint4 of 8 bf16:
//   j-th = W1[k = s*32 + (lane>>4)*8 + j][n = h*128 + t*16 + (lane&15)]
__global__ void w1_frag_kernel(const float* __restrict__ W1,
                               uint4* __restrict__ W1frag) {
    int f = blockIdx.x * blockDim.x + threadIdx.x;   // 0..4095
    int h = f >> 11, rem = f & 2047;
    int t = rem >> 8, s = (rem >> 6) & 3, l = rem & 63;
    int q = l >> 4, n16 = l & 15;
    int n = h * 128 + t * 16 + n16;
    int kb = s * 32 + q * 8;
    unsigned p[4];
    #pragma unroll
    for (int jj = 0; jj < 4; ++jj) {
        float a = W1[(size_t)(kb + 2 * jj) * HID + n];
        float b = W1[(size_t)(kb + 2 * jj + 1) * HID + n];
        p[jj] = bf16pair(a, b);
    }
    W1frag[f] = make_uint4(p[0], p[1], p[2], p[3]);
}

// ---------------- CSR build: count ----------------
__global__ void count_kernel(const int* __restrict__ rows,
                             int* __restrict__ counts) {
    int e = blockIdx.x * blockDim.x + threadIdx.x;
    if (e < N_EDGES) atomicAdd(&counts[rows[e]], 1);
}

// ---------------- hierarchical scan, phase 1: per-block sums ----------------
__global__ void block_sum_kernel(const int* __restrict__ counts,
                                 int* __restrict__ blockSums) {
    int t = threadIdx.x;
    int base = blockIdx.x * 1024 + t * 4;
    int s = 0;
    if (base < N_NODES) {
        int4 c = *(const int4*)(counts + base);
        s = c.x + c.y + c.z + c.w;
    }
    #pragma unroll
    for (int off = 32; off >= 1; off >>= 1)
        s += __shfl_xor(s, off);
    __shared__ int wsum[4];
    int lane = t & 63, wid = t >> 6;
    if (lane == 0) wsum[wid] = s;
    __syncthreads();
    if (t == 0)
        blockSums[blockIdx.x] = wsum[0] + wsum[1] + wsum[2] + wsum[3];
}

// ---------------- phase 2: scan the 49 block sums (single wave) ----------------
__global__ void block_offset_kernel(const int* __restrict__ blockSums,
                                    int* __restrict__ blockOffs,
                                    int* __restrict__ row_start) {
    int lane = threadIdx.x;          // 64 threads
    int x = (lane < SCAN_NBLK) ? blockSums[lane] : 0;
    #pragma unroll
    for (int off = 1; off < 64; off <<= 1) {
        int y = __shfl_up(x, off);
        if (lane >= off) x += y;
    }
    int excl = __shfl_up(x, 1);
    if (lane == 0) excl = 0;
    if (lane < SCAN_NBLK) blockOffs[lane] = excl;
    if (lane == SCAN_NBLK - 1) row_start[N_NODES] = x;   // grand total
}

// ---------------- phase 3: local scan + block offset -> row_start, cursor ----------------
__global__ void local_scan_kernel(const int* __restrict__ counts,
                                  const int* __restrict__ blockOffs,
                                  int* __restrict__ row_start,
                                  int* __restrict__ cursor) {
    int t = threadIdx.x;
    int base = blockIdx.x * 1024 + t * 4;
    int4 c = make_int4(0, 0, 0, 0);
    if (base < N_NODES) c = *(const int4*)(counts + base);
    int s0 = c.x, s1 = s0 + c.y, s2 = s1 + c.z, s3 = s2 + c.w;
    int tsum = s3;
    int lane = t & 63, wid = t >> 6;
    int x = tsum;
    #pragma unroll
    for (int off = 1; off < 64; off <<= 1) {
        int y = __shfl_up(x, off);
        if (lane >= off) x += y;
    }
    __shared__ int wsum[4];
    if (lane == 63) wsum[wid] = x;
    __syncthreads();
    int woff = 0;
    for (int i = 0; i < 4; ++i)
        if (i < wid) woff += wsum[i];
    int excl = x - tsum + woff + blockOffs[blockIdx.x];
    if (base < N_NODES) {
        int4 rs = make_int4(excl, excl + s0, excl + s1, excl + s2);
        *(int4*)(row_start + base) = rs;
        *(int4*)(cursor + base) = rs;
    }
}

// ---------------- CSR build: scatter (interleaved col+val, single 8B store) ----------------
__global__ void scatter_kernel(const int* __restrict__ rows,
                               const int* __restrict__ cols,
                               const float* __restrict__ vals,
                               int* __restrict__ cursor,
                               int2* __restrict__ csr_cv) {
    int e = blockIdx.x * blockDim.x + threadIdx.x;
    if (e >= N_EDGES) return;
    int pos = atomicAdd(&cursor[rows[e]], 1);
    csr_cv[pos] = make_int2(cols[e], __float_as_int(vals[e]));
}

// ---------------- SpMM (CSR, bf16 gather, fp32 accumulate) ----------------
// MODE 0: Hout_b[r] = bf16(acc)                              (hop 2)
// MODE 1: Hout_b[r] = bf16(0.5*acc)                          (hop 1, folds input scale)
// MODE 2: Hout_b[r] = bf16(0.5*feats[r] + h1[r] + h2[r] + acc)  (hop 3, y in bf16)
template <int MODE>
__global__ void spmm_csr(const int* __restrict__ row_start,
                         const int2* __restrict__ csr_cv,
                         const uint2* __restrict__ Hin_b,
                         uint2* __restrict__ Hout_b,
                         const float* __restrict__ feats,
                         const uint2* __restrict__ h1b,
                         const uint2* __restrict__ h2b) {
    int wave = (blockIdx.x * blockDim.x + threadIdx.x) >> 6;
    int lane = threadIdx.x & 63;
    if (wave >= N_NODES) return;
    int p = lane >> 5;          // which edge of the pair
    int q = lane & 31;          // dim group (4 dims)
    int start = row_start[wave];
    int end   = row_start[wave + 1];
    float4 acc = make_float4(0.f, 0.f, 0.f, 0.f);
    for (int base = start; base < end; base += 64) {
        int idx = base + lane;
        int c = 0; float v = 0.f;
        if (idx < end) {
            int2 cv = csr_cv[idx];
            c = cv.x;
            v = __int_as_float(cv.y);
        }
        int cnt = min(64, end - base);
        for (int j = 0; j < cnt; j += 2) {
            int src = j + p;                   // v==0 beyond cnt
            int   cj = __shfl(c, src);
            float vj = __shfl(v, src);
            uint2 h = Hin_b[(size_t)cj * 32 + q];   // 4 bf16 = 8 B
            acc.x += vj * bf_lo(h.x);
            acc.y += vj * bf_hi(h.x);
            acc.z += vj * bf_lo(h.y);
            acc.w += vj * bf_hi(h.y);
        }
    }
    acc.x += __shfl_xor(acc.x, 32);
    acc.y += __shfl_xor(acc.y, 32);
    acc.z += __shfl_xor(acc.z, 32);
    acc.w += __shfl_xor(acc.w, 32);
    if (p == 0) {
        size_t o32 = (size_t)wave * 32 + q;
        if (MODE == 1) {
            acc.x *= 0.5f; acc.y *= 0.5f; acc.z *= 0.5f; acc.w *= 0.5f;
        } else if (MODE == 2) {
            size_t o = (size_t)wave * IN_DIM + q * 4;
            float4 f = *(const float4*)(feats + o);
            uint2 a = h1b[o32];
            uint2 b = h2b[o32];
            acc.x += 0.5f * f.x + bf_lo(a.x) + bf_lo(b.x);
            acc.y += 0.5f * f.y + bf_hi(a.x) + bf_hi(b.x);
            acc.z += 0.5f * f.z + bf_lo(a.y) + bf_lo(b.y);
            acc.w += 0.5f * f.w + bf_hi(a.y) + bf_hi(b.y);
        }
        Hout_b[o32] = make_uint2(bf16pair(acc.x, acc.y), bf16pair(acc.z, acc.w));
    }
}

// ---------------- GEMM1 (MFMA): H1 = relu(0.25*(ybf16 @ W1) + b1) ----------------
// grid (ceil(N/64), 2), 256 threads = 4 waves. Wave w: rows [row0+16w, +16),
// cols [h*128, +128) as 8 16x16 C-tiles, K=128 via 4 MFMA steps.
// A-fragment: direct 16B loads from bf16 y row (A[m=lane&15][k=quad*8+j]).
// B-fragment: W1frag staged in LDS (B[k=quad*8+j][n=lane&15]).
// C/D: col=lane&15, row=quad*4+reg  [HW-verified gfx950 layout].
__global__ void gemm1_mfma(const uint4* __restrict__ yb4,
                           const uint4* __restrict__ W1frag,
                           const float* __restrict__ bias1,
                           float* __restrict__ H1) {
    __shared__ uint4 wlds[2048];   // 32 KB: this block's N-half of W1 fragments
    int tid = threadIdx.x;
    int h = blockIdx.y;
    for (int i = tid; i < 2048; i += 256)
        wlds[i] = W1frag[h * 2048 + i];
    __syncthreads();

    int wave = tid >> 6, lane = tid & 63;
    int q = lane >> 4, c16 = lane & 15;
    int row0 = blockIdx.x * 64 + wave * 16;
    int arow = row0 + c16;

    union { uint4 u; short8 v; } au[4], bu;
    if (arow < N_NODES) {
        #pragma unroll
        for (int s = 0; s < 4; ++s)
            au[s].u = yb4[(size_t)arow * 16 + 4 * s + q];
    } else {
        #pragma unroll
        for (int s = 0; s < 4; ++s)
            au[s].u = make_uint4(0u, 0u, 0u, 0u);
    }

    #pragma unroll
    for (int t = 0; t < 8; ++t) {
        floatx4 acc = {0.f, 0.f, 0.f, 0.f};
        #pragma unroll
        for (int s = 0; s < 4; ++s) {
            bu.u = wlds[(t * 4 + s) * 64 + lane];
            acc = __builtin_amdgcn_mfma_f32_16x16x32_bf16(au[s].v, bu.v, acc, 0, 0, 0);
        }
        int col = h * 128 + t * 16 + c16;
        float bs = bias1[col];
        #pragma unroll
        for (int r = 0; r < 4; ++r) {
            int crow = row0 + q * 4 + r;
            if (crow < N_NODES) {
                float v = 0.25f * acc[r] + bs;
                H1[(size_t)crow * HID + col] = v > 0.f ? v : 0.f;
            }
        }
    }
}

// ---------------- GEMM2 (K-split x2): partial = H1[:, khalf] @ W2[khalf, :] ----------------
#define G2_BM 128
#define G2_BK 32
__global__ void gemm2_kernel(const float* __restrict__ H1,
                             const float* __restrict__ W2,
                             float* __restrict__ part0,
                             float* __restrict__ part1) {
    __shared__ float As[G2_BK][G2_BM + 4];   // transposed A
    __shared__ float Bs[G2_BK][44];          // 32 x 40, row pad to 44
    int tid = threadIdx.x;                   // 256
    int rt = tid >> 3;                       // 0..31, 4 rows each
    int ct = tid & 7;                        // 0..7, 5 cols each
    int row0 = blockIdx.x * G2_BM;
    int kbase = blockIdx.y * (HID / 2);      // 0 or 128
    float* outp = blockIdx.y ? part1 : part0;
    float acc[4][5] = {};
    for (int kt = 0; kt < HID / 2; kt += G2_BK) {    // 4 k-tiles
        int k0 = kbase + kt;
        #pragma unroll
        for (int i = tid; i < 1024; i += 256) {
            int r = i >> 3, u = i & 7;
            int gr = row0 + r;
            float4 v = make_float4(0.f, 0.f, 0.f, 0.f);
            if (gr < N_NODES)
                v = *(const float4*)(H1 + (size_t)gr * HID + k0 + u * 4);
            int kb = u * 4;
            As[kb + 0][r] = v.x;
            As[kb + 1][r] = v.y;
            As[kb + 2][r] = v.z;
            As[kb + 3][r] = v.w;
        }
        for (int i = tid; i < 320; i += 256) {
            int r = i / 10, cg = i % 10;
            float4 w = *(const float4*)(W2 + (size_t)(k0 + r) * NCLASS + cg * 4);
            *(float4*)&Bs[r][cg * 4] = w;
        }
        __syncthreads();
        #pragma unroll
        for (int kk = 0; kk < G2_BK; ++kk) {
            float4 a0 = *(const float4*)&As[kk][rt * 4];
            float a[4] = {a0.x, a0.y, a0.z, a0.w};
            float b[5];
            #pragma unroll
            for (int j = 0; j < 5; ++j) b[j] = Bs[kk][ct * 5 + j];
            #pragma unroll
            for (int i = 0; i < 4; ++i)
                #pragma unroll
                for (int j = 0; j < 5; ++j)
                    acc[i][j] += a[i] * b[j];
        }
        __syncthreads();
    }
    #pragma unroll
    for (int i = 0; i < 4; ++i) {
        int gr = row0 + rt * 4 + i;
        if (gr >= N_NODES) continue;
        float* dst = outp + (size_t)gr * NCLASS + ct * 5;
        #pragma unroll
        for (int j = 0; j < 5; ++j)
            dst[j] = acc[i][j];
    }
}

// ---------------- double log_softmax (sums K-split partials + bias) ----------------
__global__ void lsm_kernel(const float* __restrict__ part0,
                           const float* __restrict__ part1,
                           const float* __restrict__ b2,
                           float* __restrict__ Out) {
    int wave = threadIdx.x >> 6;
    int lane = threadIdx.x & 63;
    int row = blockIdx.x * 4 + wave;
    if (row >= N_NODES) return;

    float acc = -INFINITY;
    if (lane < NCLASS) {
        size_t idx = (size_t)row * NCLASS + lane;
        acc = part0[idx] + part1[idx] + b2[lane];
    }

    float m = acc;
    #pragma unroll
    for (int off = 32; off >= 1; off >>= 1)
        m = fmaxf(m, __shfl_xor(m, off));
    float ex = (lane < NCLASS) ? expf(acc - m) : 0.f;
    float s = ex;
    #pragma unroll
    for (int off = 32; off >= 1; off >>= 1)
        s += __shfl_xor(s, off);
    float z1 = acc - (m + logf(s));

    float m2 = z1;
    #pragma unroll
    for (int off = 32; off >= 1; off >>= 1)
        m2 = fmaxf(m2, __shfl_xor(m2, off));
    float ex2 = (lane < NCLASS) ? expf(z1 - m2) : 0.f;
    float s2 = ex2;
    #pragma unroll
    for (int off = 32; off >= 1; off >>= 1)
        s2 += __shfl_xor(s2, off);
    float z2 = z1 - (m2 + logf(s2));

    if (lane < NCLASS)
        Out[(size_t)row * NCLASS + lane] = z2;
}

extern "C" void kernel_launch(void* const* d_in, const int* in_sizes, int n_in,
                              void* d_out, int out_size, void* d_ws, size_t ws_size,
                              hipStream_t stream) {
    const float* feats   = (const float*)d_in[0];
    const int*   e_row   = (const int*)d_in[1];
    const int*   e_col   = (const int*)d_in[2];
    const float* e_vals  = (const float*)d_in[3];
    const float* W1      = (const float*)d_in[4];
    const float* b1      = (const float*)d_in[5];
    const float* W2      = (const float*)d_in[6];
    const float* b2      = (const float*)d_in[7];
    float* out = (float*)d_out;

    // Workspace (19.2M floats proven):
    //   ybf   : [0, 3.2M)           y in bf16 (MLP input, written by hop3)
    //   W1frag: [3.2M, 3.216M)      W1 bf16 MFMA fragments (64 KB)
    //   fb16  : [6.4M, 9.6M)        feats in bf16
    //   h1b   : [9.6M, 12.8M)       hop1 out, bf16
    //   h2b   : [12.8M, 16M)        hop2 out, bf16
    //   hid   : [6.4M, 19.2M)       gemm1 out fp32 (bf16 hop bufs dead by then)
    //   part0 : [0, 2M)  part1: [2M, 4M)   (ybf/W1frag dead after gemm1)
    float* ws    = (float*)d_ws;
    uint2* ybf   = (uint2*)ws;
    uint4* W1frag = (uint4*)(ws + (size_t)N_NODES * IN_DIM / 2);
    uint2* fb16  = (uint2*)(ws + (size_t)N_NODES * IN_DIM);
    uint2* h1b   = (uint2*)(ws + (size_t)N_NODES * IN_DIM * 3 / 2);
    uint2* h2b   = (uint2*)(ws + (size_t)N_NODES * IN_DIM * 2);
    float* hid   = ws + (size_t)N_NODES * IN_DIM;
    float* part0 = ws;
    float* part1 = ws + (size_t)N_NODES * NCLASS;

    // CSR scratch in d_out (8 MB; fully overwritten by lsm_kernel at the end).
    int2*  csr_cv    = (int2*)d_out;                     // interleaved (col,val)
    int*   counts    = (int*)d_out + 2 * N_EDGES;        // [1600000, 1650000)
    int*   cursor    = counts + N_NODES;                 // [1650000, 1700000)
    int*   row_start = cursor + N_NODES;                 // [1700000, 1750001)
    int*   blockSums = row_start + N_NODES + 4;
    int*   blockOffs = blockSums + 64;                   // < 2000000

    // zero counts (200 KB)
    hipMemsetAsync(counts, 0, N_NODES * sizeof(int), stream);

    // feats -> bf16 (packed); W1 -> MFMA fragment layout
    const int ELEMS4 = N_NODES * IN_DIM / 4;  // 1.6M float4s
    to_bf16_kernel<<<ELEMS4 / 256, 256, 0, stream>>>((const float4*)feats, fb16);
    w1_frag_kernel<<<16, 256, 0, stream>>>(W1, W1frag);

    // Build CSR: count -> hierarchical scan -> scatter
    const int EG = N_EDGES / 256;             // 3125 exact
    count_kernel<<<EG, 256, 0, stream>>>(e_row, counts);
    block_sum_kernel<<<SCAN_NBLK, 256, 0, stream>>>(counts, blockSums);
    block_offset_kernel<<<1, 64, 0, stream>>>(blockSums, blockOffs, row_start);
    local_scan_kernel<<<SCAN_NBLK, 256, 0, stream>>>(counts, blockOffs, row_start, cursor);
    scatter_kernel<<<EG, 256, 0, stream>>>(e_row, e_col, e_vals, cursor, csr_cv);

    // 3 propagation hops (bf16 gather, fp32 accumulate; hop3 emits bf16 y)
    const int SPMM_BLOCKS = N_NODES / 4;      // 12500 (4 waves/block)
    spmm_csr<1><<<SPMM_BLOCKS, 256, 0, stream>>>(row_start, csr_cv, fb16, h1b,
                                                 nullptr, nullptr, nullptr);
    spmm_csr<0><<<SPMM_BLOCKS, 256, 0, stream>>>(row_start, csr_cv, h1b, h2b,
                                                 nullptr, nullptr, nullptr);
    spmm_csr<2><<<SPMM_BLOCKS, 256, 0, stream>>>(row_start, csr_cv, h2b, ybf,
                                                 feats, h1b, h2b);

    // GEMM1 (MFMA): hid = relu(0.25*(ybf @ W1) + b1)
    dim3 g1((N_NODES + 63) / 64, 2);          // (782, 2)
    gemm1_mfma<<<g1, 256, 0, stream>>>((const uint4*)ybf, W1frag, b1, hid);

    // GEMM2 (K-split x2): partials into dead y region
    dim3 g2((N_NODES + G2_BM - 1) / G2_BM, 2);        // (391, 2)
    gemm2_kernel<<<g2, 256, 0, stream>>>(hid, W2, part0, part1);

    // double log_softmax (sums partials + bias) -> out
    lsm_kernel<<<(N_NODES + 3) / 4, 256, 0, stream>>>(part0, part1, b2, out);
}

// Round 15
// 351.349 us; speedup vs baseline: 1.6210x; 1.0097x over previous
//
#include <hip/hip_runtime.h>
#include <math.h>

#define N_NODES 50000
#define N_EDGES 800000
#define IN_DIM 128
#define HID 256
#define NCLASS 40

#define SCAN_NBLK 49   // ceil(50000 / 1024)

typedef __attribute__((ext_vector_type(8))) short short8;
typedef __attribute__((ext_vector_type(4))) float floatx4;

// ---------- bf16 helpers (RNE pack, cheap unpack) ----------
__device__ inline unsigned bf16pair(float a, float b) {
    unsigned ua = __float_as_uint(a), ub = __float_as_uint(b);
    ua = (ua + 0x7fffu + ((ua >> 16) & 1u)) >> 16;
    ub = (ub + 0x7fffu + ((ub >> 16) & 1u)) >> 16;
    return ua | (ub << 16);
}
__device__ inline unsigned bf16bits(float a) {     // 16-bit RNE bf16 of a
    unsigned ua = __float_as_uint(a);
    return (ua + 0x7fffu + ((ua >> 16) & 1u)) >> 16;
}
__device__ inline float bf_lo(unsigned u) { return __uint_as_float(u << 16); }
__device__ inline float bf_hi(unsigned u) { return __uint_as_float(u & 0xffff0000u); }

// ---------------- convert feats -> bf16 (packed) ----------------
__global__ void to_bf16_kernel(const float4* __restrict__ f4,
                               uint2* __restrict__ o) {
    int i = blockIdx.x * blockDim.x + threadIdx.x;   // 1.6M float4s
    float4 v = f4[i];
    o[i] = make_uint2(bf16pair(v.x, v.y), bf16pair(v.z, v.w));
}

// ---------------- W1 -> bf16 MFMA B-fragment layout ----------------
// W1frag[((h*8 + t)*4 + s)*64 + lane] = uint4 of 8 bf16:
//   j-th = W1[k = s*32 + (lane>>4)*8 + j][n = h*128 + t*16 + (lane&15)]
__global__ void w1_frag_kernel(const float* __restrict__ W1,
                               uint4* __restrict__ W1frag) {
    int f = blockIdx.x * blockDim.x + threadIdx.x;   // 0..4095
    int h = f >> 11, rem = f & 2047;
    int t = rem >> 8, s = (rem >> 6) & 3, l = rem & 63;
    int q = l >> 4, n16 = l & 15;
    int n = h * 128 + t * 16 + n16;
    int kb = s * 32 + q * 8;
    unsigned p[4];
    #pragma unroll
    for (int jj = 0; jj < 4; ++jj) {
        float a = W1[(size_t)(kb + 2 * jj) * HID + n];
        float b = W1[(size_t)(kb + 2 * jj + 1) * HID + n];
        p[jj] = bf16pair(a, b);
    }
    W1frag[f] = make_uint4(p[0], p[1], p[2], p[3]);
}

// ---------------- CSR build: count ----------------
__global__ void count_kernel(const int* __restrict__ rows,
                             int* __restrict__ counts) {
    int e = blockIdx.x * blockDim.x + threadIdx.x;
    if (e < N_EDGES) atomicAdd(&counts[rows[e]], 1);
}

// ---------------- hierarchical scan, phase 1: per-block sums ----------------
__global__ void block_sum_kernel(const int* __restrict__ counts,
                                 int* __restrict__ blockSums) {
    int t = threadIdx.x;
    int base = blockIdx.x * 1024 + t * 4;
    int s = 0;
    if (base < N_NODES) {
        int4 c = *(const int4*)(counts + base);
        s = c.x + c.y + c.z + c.w;
    }
    #pragma unroll
    for (int off = 32; off >= 1; off >>= 1)
        s += __shfl_xor(s, off);
    __shared__ int wsum[4];
    int lane = t & 63, wid = t >> 6;
    if (lane == 0) wsum[wid] = s;
    __syncthreads();
    if (t == 0)
        blockSums[blockIdx.x] = wsum[0] + wsum[1] + wsum[2] + wsum[3];
}

// ---------------- phase 2: scan the 49 block sums (single wave) ----------------
__global__ void block_offset_kernel(const int* __restrict__ blockSums,
                                    int* __restrict__ blockOffs,
                                    int* __restrict__ row_start) {
    int lane = threadIdx.x;          // 64 threads
    int x = (lane < SCAN_NBLK) ? blockSums[lane] : 0;
    #pragma unroll
    for (int off = 1; off < 64; off <<= 1) {
        int y = __shfl_up(x, off);
        if (lane >= off) x += y;
    }
    int excl = __shfl_up(x, 1);
    if (lane == 0) excl = 0;
    if (lane < SCAN_NBLK) blockOffs[lane] = excl;
    if (lane == SCAN_NBLK - 1) row_start[N_NODES] = x;   // grand total
}

// ---------------- phase 3: local scan + block offset -> row_start, cursor ----------------
__global__ void local_scan_kernel(const int* __restrict__ counts,
                                  const int* __restrict__ blockOffs,
                                  int* __restrict__ row_start,
                                  int* __restrict__ cursor) {
    int t = threadIdx.x;
    int base = blockIdx.x * 1024 + t * 4;
    int4 c = make_int4(0, 0, 0, 0);
    if (base < N_NODES) c = *(const int4*)(counts + base);
    int s0 = c.x, s1 = s0 + c.y, s2 = s1 + c.z, s3 = s2 + c.w;
    int tsum = s3;
    int lane = t & 63, wid = t >> 6;
    int x = tsum;
    #pragma unroll
    for (int off = 1; off < 64; off <<= 1) {
        int y = __shfl_up(x, off);
        if (lane >= off) x += y;
    }
    __shared__ int wsum[4];
    if (lane == 63) wsum[wid] = x;
    __syncthreads();
    int woff = 0;
    for (int i = 0; i < 4; ++i)
        if (i < wid) woff += wsum[i];
    int excl = x - tsum + woff + blockOffs[blockIdx.x];
    if (base < N_NODES) {
        int4 rs = make_int4(excl, excl + s0, excl + s1, excl + s2);
        *(int4*)(row_start + base) = rs;
        *(int4*)(cursor + base) = rs;
    }
}

// ---------------- CSR build: scatter (packed u16 col | bf16 val, 4B store) ----------------
__global__ void scatter_kernel(const int* __restrict__ rows,
                               const int* __restrict__ cols,
                               const float* __restrict__ vals,
                               int* __restrict__ cursor,
                               unsigned* __restrict__ csr_cv) {
    int e = blockIdx.x * blockDim.x + threadIdx.x;
    if (e >= N_EDGES) return;
    int pos = atomicAdd(&cursor[rows[e]], 1);
    csr_cv[pos] = ((unsigned)cols[e] << 16) | bf16bits(vals[e]);
}

// ---------------- SpMM (CSR, bf16 gather + bf16 vals, fp32 accumulate) ----------------
// MODE 0: Hout_b[r] = bf16(acc)                              (hop 2)
// MODE 1: Hout_b[r] = bf16(0.5*acc)                          (hop 1, folds input scale)
// MODE 2: Hout_b[r] = bf16(0.5*feats[r] + h1[r] + h2[r] + acc)  (hop 3, y in bf16)
template <int MODE>
__global__ void spmm_csr(const int* __restrict__ row_start,
                         const unsigned* __restrict__ csr_cv,
                         const uint2* __restrict__ Hin_b,
                         uint2* __restrict__ Hout_b,
                         const float* __restrict__ feats,
                         const uint2* __restrict__ h1b,
                         const uint2* __restrict__ h2b) {
    int wave = (blockIdx.x * blockDim.x + threadIdx.x) >> 6;
    int lane = threadIdx.x & 63;
    if (wave >= N_NODES) return;
    int p = lane >> 5;          // which edge of the pair
    int q = lane & 31;          // dim group (4 dims)
    int start = row_start[wave];
    int end   = row_start[wave + 1];
    float4 acc = make_float4(0.f, 0.f, 0.f, 0.f);
    for (int base = start; base < end; base += 64) {
        int idx = base + lane;
        unsigned u = 0;                         // col=0, val=+0.0
        if (idx < end) u = csr_cv[idx];
        int cnt = min(64, end - base);
        for (int j = 0; j < cnt; j += 2) {
            unsigned uj = __shfl(u, j + p);     // single shuffle broadcasts col+val
            int   cj = uj >> 16;
            float vj = __uint_as_float(uj << 16);
            uint2 h = Hin_b[(size_t)cj * 32 + q];   // 4 bf16 = 8 B
            acc.x += vj * bf_lo(h.x);
            acc.y += vj * bf_hi(h.x);
            acc.z += vj * bf_lo(h.y);
            acc.w += vj * bf_hi(h.y);
        }
    }
    acc.x += __shfl_xor(acc.x, 32);
    acc.y += __shfl_xor(acc.y, 32);
    acc.z += __shfl_xor(acc.z, 32);
    acc.w += __shfl_xor(acc.w, 32);
    if (p == 0) {
        size_t o32 = (size_t)wave * 32 + q;
        if (MODE == 1) {
            acc.x *= 0.5f; acc.y *= 0.5f; acc.z *= 0.5f; acc.w *= 0.5f;
        } else if (MODE == 2) {
            size_t o = (size_t)wave * IN_DIM + q * 4;
            float4 f = *(const float4*)(feats + o);
            uint2 a = h1b[o32];
            uint2 b = h2b[o32];
            acc.x += 0.5f * f.x + bf_lo(a.x) + bf_lo(b.x);
            acc.y += 0.5f * f.y + bf_hi(a.x) + bf_hi(b.x);
            acc.z += 0.5f * f.z + bf_lo(a.y) + bf_lo(b.y);
            acc.w += 0.5f * f.w + bf_hi(a.y) + bf_hi(b.y);
        }
        Hout_b[o32] = make_uint2(bf16pair(acc.x, acc.y), bf16pair(acc.z, acc.w));
    }
}

// ---------------- GEMM1 (MFMA): H1 = relu(0.25*(ybf16 @ W1) + b1) ----------------
__global__ void gemm1_mfma(const uint4* __restrict__ yb4,
                           const uint4* __restrict__ W1frag,
                           const float* __restrict__ bias1,
                           float* __restrict__ H1) {
    __shared__ uint4 wlds[2048];   // 32 KB: this block's N-half of W1 fragments
    int tid = threadIdx.x;
    int h = blockIdx.y;
    for (int i = tid; i < 2048; i += 256)
        wlds[i] = W1frag[h * 2048 + i];
    __syncthreads();

    int wave = tid >> 6, lane = tid & 63;
    int q = lane >> 4, c16 = lane & 15;
    int row0 = blockIdx.x * 64 + wave * 16;
    int arow = row0 + c16;

    union { uint4 u; short8 v; } au[4], bu;
    if (arow < N_NODES) {
        #pragma unroll
        for (int s = 0; s < 4; ++s)
            au[s].u = yb4[(size_t)arow * 16 + 4 * s + q];
    } else {
        #pragma unroll
        for (int s = 0; s < 4; ++s)
            au[s].u = make_uint4(0u, 0u, 0u, 0u);
    }

    #pragma unroll
    for (int t = 0; t < 8; ++t) {
        floatx4 acc = {0.f, 0.f, 0.f, 0.f};
        #pragma unroll
        for (int s = 0; s < 4; ++s) {
            bu.u = wlds[(t * 4 + s) * 64 + lane];
            acc = __builtin_amdgcn_mfma_f32_16x16x32_bf16(au[s].v, bu.v, acc, 0, 0, 0);
        }
        int col = h * 128 + t * 16 + c16;
        float bs = bias1[col];
        #pragma unroll
        for (int r = 0; r < 4; ++r) {
            int crow = row0 + q * 4 + r;
            if (crow < N_NODES) {
                float v = 0.25f * acc[r] + bs;
                H1[(size_t)crow * HID + col] = v > 0.f ? v : 0.f;
            }
        }
    }
}

// ---------------- GEMM2 (K-split x2): partial = H1[:, khalf] @ W2[khalf, :] ----------------
#define G2_BM 128
#define G2_BK 32
__global__ void gemm2_kernel(const float* __restrict__ H1,
                             const float* __restrict__ W2,
                             float* __restrict__ part0,
                             float* __restrict__ part1) {
    __shared__ float As[G2_BK][G2_BM + 4];   // transposed A
    __shared__ float Bs[G2_BK][44];          // 32 x 40, row pad to 44
    int tid = threadIdx.x;                   // 256
    int rt = tid >> 3;                       // 0..31, 4 rows each
    int ct = tid & 7;                        // 0..7, 5 cols each
    int row0 = blockIdx.x * G2_BM;
    int kbase = blockIdx.y * (HID / 2);      // 0 or 128
    float* outp = blockIdx.y ? part1 : part0;
    float acc[4][5] = {};
    for (int kt = 0; kt < HID / 2; kt += G2_BK) {    // 4 k-tiles
        int k0 = kbase + kt;
        #pragma unroll
        for (int i = tid; i < 1024; i += 256) {
            int r = i >> 3, u = i & 7;
            int gr = row0 + r;
            float4 v = make_float4(0.f, 0.f, 0.f, 0.f);
            if (gr < N_NODES)
                v = *(const float4*)(H1 + (size_t)gr * HID + k0 + u * 4);
            int kb = u * 4;
            As[kb + 0][r] = v.x;
            As[kb + 1][r] = v.y;
            As[kb + 2][r] = v.z;
            As[kb + 3][r] = v.w;
        }
        for (int i = tid; i < 320; i += 256) {
            int r = i / 10, cg = i % 10;
            float4 w = *(const float4*)(W2 + (size_t)(k0 + r) * NCLASS + cg * 4);
            *(float4*)&Bs[r][cg * 4] = w;
        }
        __syncthreads();
        #pragma unroll
        for (int kk = 0; kk < G2_BK; ++kk) {
            float4 a0 = *(const float4*)&As[kk][rt * 4];
            float a[4] = {a0.x, a0.y, a0.z, a0.w};
            float b[5];
            #pragma unroll
            for (int j = 0; j < 5; ++j) b[j] = Bs[kk][ct * 5 + j];
            #pragma unroll
            for (int i = 0; i < 4; ++i)
                #pragma unroll
                for (int j = 0; j < 5; ++j)
                    acc[i][j] += a[i] * b[j];
        }
        __syncthreads();
    }
    #pragma unroll
    for (int i = 0; i < 4; ++i) {
        int gr = row0 + rt * 4 + i;
        if (gr >= N_NODES) continue;
        float* dst = outp + (size_t)gr * NCLASS + ct * 5;
        #pragma unroll
        for (int j = 0; j < 5; ++j)
            dst[j] = acc[i][j];
    }
}

// ---------------- double log_softmax (sums K-split partials + bias) ----------------
__global__ void lsm_kernel(const float* __restrict__ part0,
                           const float* __restrict__ part1,
                           const float* __restrict__ b2,
                           float* __restrict__ Out) {
    int wave = threadIdx.x >> 6;
    int lane = threadIdx.x & 63;
    int row = blockIdx.x * 4 + wave;
    if (row >= N_NODES) return;

    float acc = -INFINITY;
    if (lane < NCLASS) {
        size_t idx = (size_t)row * NCLASS + lane;
        acc = part0[idx] + part1[idx] + b2[lane];
    }

    float m = acc;
    #pragma unroll
    for (int off = 32; off >= 1; off >>= 1)
        m = fmaxf(m, __shfl_xor(m, off));
    float ex = (lane < NCLASS) ? expf(acc - m) : 0.f;
    float s = ex;
    #pragma unroll
    for (int off = 32; off >= 1; off >>= 1)
        s += __shfl_xor(s, off);
    float z1 = acc - (m + logf(s));

    float m2 = z1;
    #pragma unroll
    for (int off = 32; off >= 1; off >>= 1)
        m2 = fmaxf(m2, __shfl_xor(m2, off));
    float ex2 = (lane < NCLASS) ? expf(z1 - m2) : 0.f;
    float s2 = ex2;
    #pragma unroll
    for (int off = 32; off >= 1; off >>= 1)
        s2 += __shfl_xor(s2, off);
    float z2 = z1 - (m2 + logf(s2));

    if (lane < NCLASS)
        Out[(size_t)row * NCLASS + lane] = z2;
}

extern "C" void kernel_launch(void* const* d_in, const int* in_sizes, int n_in,
                              void* d_out, int out_size, void* d_ws, size_t ws_size,
                              hipStream_t stream) {
    const float* feats   = (const float*)d_in[0];
    const int*   e_row   = (const int*)d_in[1];
    const int*   e_col   = (const int*)d_in[2];
    const float* e_vals  = (const float*)d_in[3];
    const float* W1      = (const float*)d_in[4];
    const float* b1      = (const float*)d_in[5];
    const float* W2      = (const float*)d_in[6];
    const float* b2      = (const float*)d_in[7];
    float* out = (float*)d_out;

    // Workspace (19.2M floats proven):
    //   ybf   : [0, 3.2M)           y in bf16 (MLP input, written by hop3)
    //   W1frag: [3.2M, 3.216M)      W1 bf16 MFMA fragments (64 KB)
    //   fb16  : [6.4M, 9.6M)        feats in bf16
    //   h1b   : [9.6M, 12.8M)       hop1 out, bf16
    //   h2b   : [12.8M, 16M)        hop2 out, bf16
    //   hid   : [6.4M, 19.2M)       gemm1 out fp32 (bf16 hop bufs dead by then)
    //   part0 : [0, 2M)  part1: [2M, 4M)   (ybf/W1frag dead after gemm1)
    float* ws    = (float*)d_ws;
    uint2* ybf   = (uint2*)ws;
    uint4* W1frag = (uint4*)(ws + (size_t)N_NODES * IN_DIM / 2);
    uint2* fb16  = (uint2*)(ws + (size_t)N_NODES * IN_DIM);
    uint2* h1b   = (uint2*)(ws + (size_t)N_NODES * IN_DIM * 3 / 2);
    uint2* h2b   = (uint2*)(ws + (size_t)N_NODES * IN_DIM * 2);
    float* hid   = ws + (size_t)N_NODES * IN_DIM;
    float* part0 = ws;
    float* part1 = ws + (size_t)N_NODES * NCLASS;

    // CSR scratch in d_out (8 MB; fully overwritten by lsm_kernel at the end).
    unsigned* csr_cv = (unsigned*)d_out;                 // packed (col<<16)|bf16(val), 800000
    int*   counts    = (int*)d_out + 2 * N_EDGES;        // [1600000, 1650000)
    int*   cursor    = counts + N_NODES;                 // [1650000, 1700000)
    int*   row_start = cursor + N_NODES;                 // [1700000, 1750001)
    int*   blockSums = row_start + N_NODES + 4;
    int*   blockOffs = blockSums + 64;                   // < 2000000

    // zero counts (200 KB)
    hipMemsetAsync(counts, 0, N_NODES * sizeof(int), stream);

    // feats -> bf16 (packed); W1 -> MFMA fragment layout
    const int ELEMS4 = N_NODES * IN_DIM / 4;  // 1.6M float4s
    to_bf16_kernel<<<ELEMS4 / 256, 256, 0, stream>>>((const float4*)feats, fb16);
    w1_frag_kernel<<<16, 256, 0, stream>>>(W1, W1frag);

    // Build CSR: count -> hierarchical scan -> scatter
    const int EG = N_EDGES / 256;             // 3125 exact
    count_kernel<<<EG, 256, 0, stream>>>(e_row, counts);
    block_sum_kernel<<<SCAN_NBLK, 256, 0, stream>>>(counts, blockSums);
    block_offset_kernel<<<1, 64, 0, stream>>>(blockSums, blockOffs, row_start);
    local_scan_kernel<<<SCAN_NBLK, 256, 0, stream>>>(counts, blockOffs, row_start, cursor);
    scatter_kernel<<<EG, 256, 0, stream>>>(e_row, e_col, e_vals, cursor, csr_cv);

    // 3 propagation hops (bf16 gather + bf16 vals, fp32 accumulate; hop3 emits bf16 y)
    const int SPMM_BLOCKS = N_NODES / 4;      // 12500 (4 waves/block)
    spmm_csr<1><<<SPMM_BLOCKS, 256, 0, stream>>>(row_start, csr_cv, fb16, h1b,
                                                 nullptr, nullptr, nullptr);
    spmm_csr<0><<<SPMM_BLOCKS, 256, 0, stream>>>(row_start, csr_cv, h1b, h2b,
                                                 nullptr, nullptr, nullptr);
    spmm_csr<2><<<SPMM_BLOCKS, 256, 0, stream>>>(row_start, csr_cv, h2b, ybf,
                                                 feats, h1b, h2b);

    // GEMM1 (MFMA): hid = relu(0.25*(ybf @ W1) + b1)
    dim3 g1((N_NODES + 63) / 64, 2);          // (782, 2)
    gemm1_mfma<<<g1, 256, 0, stream>>>((const uint4*)ybf, W1frag, b1, hid);

    // GEMM2 (K-split x2): partials into dead y region
    dim3 g2((N_NODES + G2_BM - 1) / G2_BM, 2);        // (391, 2)
    gemm2_kernel<<<g2, 256, 0, stream>>>(hid, W2, part0, part1);

    // double log_softmax (sums partials + bias) -> out
    lsm_kernel<<<(N_NODES + 3) / 4, 256, 0, stream>>>(part0, part1, b2, out);
}

// Round 16
// 349.996 us; speedup vs baseline: 1.6272x; 1.0039x over previous
//
#include <hip/hip_runtime.h>
#include <math.h>

#define N_NODES 50000
#define N_EDGES 800000
#define IN_DIM 128
#define HID 256
#define NCLASS 40

#define SCAN_NBLK 49   // ceil(50000 / 1024)
#define CPAD 16        // cursor/counts padded to one int per 64B line

typedef __attribute__((ext_vector_type(8))) short short8;
typedef __attribute__((ext_vector_type(4))) float floatx4;

// ---------- bf16 helpers (RNE pack, cheap unpack) ----------
__device__ inline unsigned bf16pair(float a, float b) {
    unsigned ua = __float_as_uint(a), ub = __float_as_uint(b);
    ua = (ua + 0x7fffu + ((ua >> 16) & 1u)) >> 16;
    ub = (ub + 0x7fffu + ((ub >> 16) & 1u)) >> 16;
    return ua | (ub << 16);
}
__device__ inline unsigned bf16bits(float a) {     // 16-bit RNE bf16 of a
    unsigned ua = __float_as_uint(a);
    return (ua + 0x7fffu + ((ua >> 16) & 1u)) >> 16;
}
__device__ inline float bf_lo(unsigned u) { return __uint_as_float(u << 16); }
__device__ inline float bf_hi(unsigned u) { return __uint_as_float(u & 0xffff0000u); }

// ---------------- convert feats -> bf16 (packed) ----------------
__global__ void to_bf16_kernel(const float4* __restrict__ f4,
                               uint2* __restrict__ o) {
    int i = blockIdx.x * blockDim.x + threadIdx.x;   // 1.6M float4s
    float4 v = f4[i];
    o[i] = make_uint2(bf16pair(v.x, v.y), bf16pair(v.z, v.w));
}

// ---------------- W1 -> bf16 MFMA B-fragment layout ----------------
__global__ void w1_frag_kernel(const float* __restrict__ W1,
                               uint4* __restrict__ W1frag) {
    int f = blockIdx.x * blockDim.x + threadIdx.x;   // 0..4095
    int h = f >> 11, rem = f & 2047;
    int t = rem >> 8, s = (rem >> 6) & 3, l = rem & 63;
    int q = l >> 4, n16 = l & 15;
    int n = h * 128 + t * 16 + n16;
    int kb = s * 32 + q * 8;
    unsigned p[4];
    #pragma unroll
    for (int jj = 0; jj < 4; ++jj) {
        float a = W1[(size_t)(kb + 2 * jj) * HID + n];
        float b = W1[(size_t)(kb + 2 * jj + 1) * HID + n];
        p[jj] = bf16pair(a, b);
    }
    W1frag[f] = make_uint4(p[0], p[1], p[2], p[3]);
}

// ---------------- CSR build: count (line-padded counters) ----------------
__global__ void count_kernel(const int* __restrict__ rows,
                             int* __restrict__ counts) {
    int e = blockIdx.x * blockDim.x + threadIdx.x;
    if (e < N_EDGES) atomicAdd(&counts[(size_t)rows[e] * CPAD], 1);
}

// ---------------- hierarchical scan, phase 1: per-block sums (strided reads) ----------------
__global__ void block_sum_kernel(const int* __restrict__ counts,
                                 int* __restrict__ blockSums) {
    int t = threadIdx.x;
    int base = blockIdx.x * 1024 + t * 4;
    int s = 0;
    if (base < N_NODES) {
        #pragma unroll
        for (int i = 0; i < 4; ++i)
            s += counts[(size_t)(base + i) * CPAD];
    }
    #pragma unroll
    for (int off = 32; off >= 1; off >>= 1)
        s += __shfl_xor(s, off);
    __shared__ int wsum[4];
    int lane = t & 63, wid = t >> 6;
    if (lane == 0) wsum[wid] = s;
    __syncthreads();
    if (t == 0)
        blockSums[blockIdx.x] = wsum[0] + wsum[1] + wsum[2] + wsum[3];
}

// ---------------- phase 2: scan the 49 block sums (single wave) ----------------
__global__ void block_offset_kernel(const int* __restrict__ blockSums,
                                    int* __restrict__ blockOffs,
                                    int* __restrict__ row_start) {
    int lane = threadIdx.x;          // 64 threads
    int x = (lane < SCAN_NBLK) ? blockSums[lane] : 0;
    #pragma unroll
    for (int off = 1; off < 64; off <<= 1) {
        int y = __shfl_up(x, off);
        if (lane >= off) x += y;
    }
    int excl = __shfl_up(x, 1);
    if (lane == 0) excl = 0;
    if (lane < SCAN_NBLK) blockOffs[lane] = excl;
    if (lane == SCAN_NBLK - 1) row_start[N_NODES] = x;   // grand total
}

// ---------------- phase 3: local scan -> row_start (compact), cursor (padded) ----------------
__global__ void local_scan_kernel(const int* __restrict__ counts,
                                  const int* __restrict__ blockOffs,
                                  int* __restrict__ row_start,
                                  int* __restrict__ cursor) {
    int t = threadIdx.x;
    int base = blockIdx.x * 1024 + t * 4;
    int c0 = 0, c1 = 0, c2 = 0, c3 = 0;
    if (base < N_NODES) {
        c0 = counts[(size_t)(base + 0) * CPAD];
        c1 = counts[(size_t)(base + 1) * CPAD];
        c2 = counts[(size_t)(base + 2) * CPAD];
        c3 = counts[(size_t)(base + 3) * CPAD];
    }
    int s0 = c0, s1 = s0 + c1, s2 = s1 + c2, s3 = s2 + c3;
    int tsum = s3;
    int lane = t & 63, wid = t >> 6;
    int x = tsum;
    #pragma unroll
    for (int off = 1; off < 64; off <<= 1) {
        int y = __shfl_up(x, off);
        if (lane >= off) x += y;
    }
    __shared__ int wsum[4];
    if (lane == 63) wsum[wid] = x;
    __syncthreads();
    int woff = 0;
    for (int i = 0; i < 4; ++i)
        if (i < wid) woff += wsum[i];
    int excl = x - tsum + woff + blockOffs[blockIdx.x];
    if (base < N_NODES) {
        int4 rs = make_int4(excl, excl + s0, excl + s1, excl + s2);
        *(int4*)(row_start + base) = rs;
        cursor[(size_t)(base + 0) * CPAD] = rs.x;
        cursor[(size_t)(base + 1) * CPAD] = rs.y;
        cursor[(size_t)(base + 2) * CPAD] = rs.z;
        cursor[(size_t)(base + 3) * CPAD] = rs.w;
    }
}

// ---------------- CSR build: scatter (packed u16 col | bf16 val, padded cursor) ----------------
__global__ void scatter_kernel(const int* __restrict__ rows,
                               const int* __restrict__ cols,
                               const float* __restrict__ vals,
                               int* __restrict__ cursor,
                               unsigned* __restrict__ csr_cv) {
    int e = blockIdx.x * blockDim.x + threadIdx.x;
    if (e >= N_EDGES) return;
    int pos = atomicAdd(&cursor[(size_t)rows[e] * CPAD], 1);
    csr_cv[pos] = ((unsigned)cols[e] << 16) | bf16bits(vals[e]);
}

// ---------------- SpMM (CSR, bf16 gather + bf16 vals, fp32 accumulate) ----------------
// MODE 0: Hout_b[r] = bf16(acc)                              (hop 2)
// MODE 1: Hout_b[r] = bf16(0.5*acc)                          (hop 1, folds input scale)
// MODE 2: Hout_b[r] = bf16(0.5*feats[r] + h1[r] + h2[r] + acc)  (hop 3, y in bf16)
template <int MODE>
__global__ void spmm_csr(const int* __restrict__ row_start,
                         const unsigned* __restrict__ csr_cv,
                         const uint2* __restrict__ Hin_b,
                         uint2* __restrict__ Hout_b,
                         const float* __restrict__ feats,
                         const uint2* __restrict__ h1b,
                         const uint2* __restrict__ h2b) {
    int wave = (blockIdx.x * blockDim.x + threadIdx.x) >> 6;
    int lane = threadIdx.x & 63;
    if (wave >= N_NODES) return;
    int p = lane >> 5;          // which edge of the pair
    int q = lane & 31;          // dim group (4 dims)
    int start = row_start[wave];
    int end   = row_start[wave + 1];
    float4 acc = make_float4(0.f, 0.f, 0.f, 0.f);
    for (int base = start; base < end; base += 64) {
        int idx = base + lane;
        unsigned u = 0;                         // col=0, val=+0.0
        if (idx < end) u = csr_cv[idx];
        int cnt = min(64, end - base);
        for (int j = 0; j < cnt; j += 2) {
            unsigned uj = __shfl(u, j + p);     // single shuffle broadcasts col+val
            int   cj = uj >> 16;
            float vj = __uint_as_float(uj << 16);
            uint2 h = Hin_b[(size_t)cj * 32 + q];   // 4 bf16 = 8 B
            acc.x += vj * bf_lo(h.x);
            acc.y += vj * bf_hi(h.x);
            acc.z += vj * bf_lo(h.y);
            acc.w += vj * bf_hi(h.y);
        }
    }
    acc.x += __shfl_xor(acc.x, 32);
    acc.y += __shfl_xor(acc.y, 32);
    acc.z += __shfl_xor(acc.z, 32);
    acc.w += __shfl_xor(acc.w, 32);
    if (p == 0) {
        size_t o32 = (size_t)wave * 32 + q;
        if (MODE == 1) {
            acc.x *= 0.5f; acc.y *= 0.5f; acc.z *= 0.5f; acc.w *= 0.5f;
        } else if (MODE == 2) {
            size_t o = (size_t)wave * IN_DIM + q * 4;
            float4 f = *(const float4*)(feats + o);
            uint2 a = h1b[o32];
            uint2 b = h2b[o32];
            acc.x += 0.5f * f.x + bf_lo(a.x) + bf_lo(b.x);
            acc.y += 0.5f * f.y + bf_hi(a.x) + bf_hi(b.x);
            acc.z += 0.5f * f.z + bf_lo(a.y) + bf_lo(b.y);
            acc.w += 0.5f * f.w + bf_hi(a.y) + bf_hi(b.y);
        }
        Hout_b[o32] = make_uint2(bf16pair(acc.x, acc.y), bf16pair(acc.z, acc.w));
    }
}

// ---------------- GEMM1 (MFMA): H1 = relu(0.25*(ybf16 @ W1) + b1) ----------------
__global__ void gemm1_mfma(const uint4* __restrict__ yb4,
                           const uint4* __restrict__ W1frag,
                           const float* __restrict__ bias1,
                           float* __restrict__ H1) {
    __shared__ uint4 wlds[2048];   // 32 KB: this block's N-half of W1 fragments
    int tid = threadIdx.x;
    int h = blockIdx.y;
    for (int i = tid; i < 2048; i += 256)
        wlds[i] = W1frag[h * 2048 + i];
    __syncthreads();

    int wave = tid >> 6, lane = tid & 63;
    int q = lane >> 4, c16 = lane & 15;
    int row0 = blockIdx.x * 64 + wave * 16;
    int arow = row0 + c16;

    union { uint4 u; short8 v; } au[4], bu;
    if (arow < N_NODES) {
        #pragma unroll
        for (int s = 0; s < 4; ++s)
            au[s].u = yb4[(size_t)arow * 16 + 4 * s + q];
    } else {
        #pragma unroll
        for (int s = 0; s < 4; ++s)
            au[s].u = make_uint4(0u, 0u, 0u, 0u);
    }

    #pragma unroll
    for (int t = 0; t < 8; ++t) {
        floatx4 acc = {0.f, 0.f, 0.f, 0.f};
        #pragma unroll
        for (int s = 0; s < 4; ++s) {
            bu.u = wlds[(t * 4 + s) * 64 + lane];
            acc = __builtin_amdgcn_mfma_f32_16x16x32_bf16(au[s].v, bu.v, acc, 0, 0, 0);
        }
        int col = h * 128 + t * 16 + c16;
        float bs = bias1[col];
        #pragma unroll
        for (int r = 0; r < 4; ++r) {
            int crow = row0 + q * 4 + r;
            if (crow < N_NODES) {
                float v = 0.25f * acc[r] + bs;
                H1[(size_t)crow * HID + col] = v > 0.f ? v : 0.f;
            }
        }
    }
}

// ---------------- GEMM2 (K-split x2): partial = H1[:, khalf] @ W2[khalf, :] ----------------
#define G2_BM 128
#define G2_BK 32
__global__ void gemm2_kernel(const float* __restrict__ H1,
                             const float* __restrict__ W2,
                             float* __restrict__ part0,
                             float* __restrict__ part1) {
    __shared__ float As[G2_BK][G2_BM + 4];   // transposed A
    __shared__ float Bs[G2_BK][44];          // 32 x 40, row pad to 44
    int tid = threadIdx.x;                   // 256
    int rt = tid >> 3;                       // 0..31, 4 rows each
    int ct = tid & 7;                        // 0..7, 5 cols each
    int row0 = blockIdx.x * G2_BM;
    int kbase = blockIdx.y * (HID / 2);      // 0 or 128
    float* outp = blockIdx.y ? part1 : part0;
    float acc[4][5] = {};
    for (int kt = 0; kt < HID / 2; kt += G2_BK) {    // 4 k-tiles
        int k0 = kbase + kt;
        #pragma unroll
        for (int i = tid; i < 1024; i += 256) {
            int r = i >> 3, u = i & 7;
            int gr = row0 + r;
            float4 v = make_float4(0.f, 0.f, 0.f, 0.f);
            if (gr < N_NODES)
                v = *(const float4*)(H1 + (size_t)gr * HID + k0 + u * 4);
            int kb = u * 4;
            As[kb + 0][r] = v.x;
            As[kb + 1][r] = v.y;
            As[kb + 2][r] = v.z;
            As[kb + 3][r] = v.w;
        }
        for (int i = tid; i < 320; i += 256) {
            int r = i / 10, cg = i % 10;
            float4 w = *(const float4*)(W2 + (size_t)(k0 + r) * NCLASS + cg * 4);
            *(float4*)&Bs[r][cg * 4] = w;
        }
        __syncthreads();
        #pragma unroll
        for (int kk = 0; kk < G2_BK; ++kk) {
            float4 a0 = *(const float4*)&As[kk][rt * 4];
            float a[4] = {a0.x, a0.y, a0.z, a0.w};
            float b[5];
            #pragma unroll
            for (int j = 0; j < 5; ++j) b[j] = Bs[kk][ct * 5 + j];
            #pragma unroll
            for (int i = 0; i < 4; ++i)
                #pragma unroll
                for (int j = 0; j < 5; ++j)
                    acc[i][j] += a[i] * b[j];
        }
        __syncthreads();
    }
    #pragma unroll
    for (int i = 0; i < 4; ++i) {
        int gr = row0 + rt * 4 + i;
        if (gr >= N_NODES) continue;
        float* dst = outp + (size_t)gr * NCLASS + ct * 5;
        #pragma unroll
        for (int j = 0; j < 5; ++j)
            dst[j] = acc[i][j];
    }
}

// ---------------- double log_softmax (sums K-split partials + bias) ----------------
__global__ void lsm_kernel(const float* __restrict__ part0,
                           const float* __restrict__ part1,
                           const float* __restrict__ b2,
                           float* __restrict__ Out) {
    int wave = threadIdx.x >> 6;
    int lane = threadIdx.x & 63;
    int row = blockIdx.x * 4 + wave;
    if (row >= N_NODES) return;

    float acc = -INFINITY;
    if (lane < NCLASS) {
        size_t idx = (size_t)row * NCLASS + lane;
        acc = part0[idx] + part1[idx] + b2[lane];
    }

    float m = acc;
    #pragma unroll
    for (int off = 32; off >= 1; off >>= 1)
        m = fmaxf(m, __shfl_xor(m, off));
    float ex = (lane < NCLASS) ? expf(acc - m) : 0.f;
    float s = ex;
    #pragma unroll
    for (int off = 32; off >= 1; off >>= 1)
        s += __shfl_xor(s, off);
    float z1 = acc - (m + logf(s));

    float m2 = z1;
    #pragma unroll
    for (int off = 32; off >= 1; off >>= 1)
        m2 = fmaxf(m2, __shfl_xor(m2, off));
    float ex2 = (lane < NCLASS) ? expf(z1 - m2) : 0.f;
    float s2 = ex2;
    #pragma unroll
    for (int off = 32; off >= 1; off >>= 1)
        s2 += __shfl_xor(s2, off);
    float z2 = z1 - (m2 + logf(s2));

    if (lane < NCLASS)
        Out[(size_t)row * NCLASS + lane] = z2;
}

extern "C" void kernel_launch(void* const* d_in, const int* in_sizes, int n_in,
                              void* d_out, int out_size, void* d_ws, size_t ws_size,
                              hipStream_t stream) {
    const float* feats   = (const float*)d_in[0];
    const int*   e_row   = (const int*)d_in[1];
    const int*   e_col   = (const int*)d_in[2];
    const float* e_vals  = (const float*)d_in[3];
    const float* W1      = (const float*)d_in[4];
    const float* b1      = (const float*)d_in[5];
    const float* W2      = (const float*)d_in[6];
    const float* b2      = (const float*)d_in[7];
    float* out = (float*)d_out;

    // Workspace (19.2M floats proven):
    //   ybf   : [0, 3.2M)           y in bf16 (MLP input, written by hop3)
    //   W1frag: [3.2M, 3.216M)      W1 bf16 MFMA fragments (64 KB)
    //   fb16  : [6.4M, 9.6M)        feats in bf16
    //   h1b   : [9.6M, 12.8M)       hop1 out, bf16
    //   h2b   : [12.8M, 16M)        hop2 out, bf16
    //   counts: [16M, 16.8M)        line-padded counters (dead after scan)
    //   cursor: [16.8M, 17.6M)      line-padded cursors  (dead after scatter)
    //   hid   : [6.4M, 19.2M)       gemm1 out fp32 (all above dead by then)
    //   part0 : [0, 2M)  part1: [2M, 4M)
    float* ws    = (float*)d_ws;
    uint2* ybf   = (uint2*)ws;
    uint4* W1frag = (uint4*)(ws + (size_t)N_NODES * IN_DIM / 2);
    uint2* fb16  = (uint2*)(ws + (size_t)N_NODES * IN_DIM);
    uint2* h1b   = (uint2*)(ws + (size_t)N_NODES * IN_DIM * 3 / 2);
    uint2* h2b   = (uint2*)(ws + (size_t)N_NODES * IN_DIM * 2);
    int*   counts = (int*)(ws + (size_t)N_NODES * IN_DIM * 5 / 2);   // 16M
    int*   cursor = counts + (size_t)N_NODES * CPAD;                 // +800k ints
    float* hid   = ws + (size_t)N_NODES * IN_DIM;
    float* part0 = ws;
    float* part1 = ws + (size_t)N_NODES * NCLASS;

    // CSR scratch in d_out (8 MB; fully overwritten by lsm_kernel at the end).
    unsigned* csr_cv = (unsigned*)d_out;                 // packed (col<<16)|bf16(val), 800000
    int*   row_start = (int*)d_out + 2 * N_EDGES;        // [1600000, 1650001)
    int*   blockSums = row_start + N_NODES + 4;
    int*   blockOffs = blockSums + 64;                   // < 2000000

    // zero line-padded counts (3.2 MB)
    hipMemsetAsync(counts, 0, (size_t)N_NODES * CPAD * sizeof(int), stream);

    // feats -> bf16 (packed); W1 -> MFMA fragment layout
    const int ELEMS4 = N_NODES * IN_DIM / 4;  // 1.6M float4s
    to_bf16_kernel<<<ELEMS4 / 256, 256, 0, stream>>>((const float4*)feats, fb16);
    w1_frag_kernel<<<16, 256, 0, stream>>>(W1, W1frag);

    // Build CSR: count -> hierarchical scan -> scatter
    const int EG = N_EDGES / 256;             // 3125 exact
    count_kernel<<<EG, 256, 0, stream>>>(e_row, counts);
    block_sum_kernel<<<SCAN_NBLK, 256, 0, stream>>>(counts, blockSums);
    block_offset_kernel<<<1, 64, 0, stream>>>(blockSums, blockOffs, row_start);
    local_scan_kernel<<<SCAN_NBLK, 256, 0, stream>>>(counts, blockOffs, row_start, cursor);
    scatter_kernel<<<EG, 256, 0, stream>>>(e_row, e_col, e_vals, cursor, csr_cv);

    // 3 propagation hops (bf16 gather + bf16 vals, fp32 accumulate; hop3 emits bf16 y)
    const int SPMM_BLOCKS = N_NODES / 4;      // 12500 (4 waves/block)
    spmm_csr<1><<<SPMM_BLOCKS, 256, 0, stream>>>(row_start, csr_cv, fb16, h1b,
                                                 nullptr, nullptr, nullptr);
    spmm_csr<0><<<SPMM_BLOCKS, 256, 0, stream>>>(row_start, csr_cv, h1b, h2b,
                                                 nullptr, nullptr, nullptr);
    spmm_csr<2><<<SPMM_BLOCKS, 256, 0, stream>>>(row_start, csr_cv, h2b, ybf,
                                                 feats, h1b, h2b);

    // GEMM1 (MFMA): hid = relu(0.25*(ybf @ W1) + b1)
    dim3 g1((N_NODES + 63) / 64, 2);          // (782, 2)
    gemm1_mfma<<<g1, 256, 0, stream>>>((const uint4*)ybf, W1frag, b1, hid);

    // GEMM2 (K-split x2): partials into dead y region
    dim3 g2((N_NODES + G2_BM - 1) / G2_BM, 2);        // (391, 2)
    gemm2_kernel<<<g2, 256, 0, stream>>>(hid, W2, part0, part1);

    // double log_softmax (sums partials + bias) -> out
    lsm_kernel<<<(N_NODES + 3) / 4, 256, 0, stream>>>(part0, part1, b2, out);
}

// Round 17
// 323.609 us; speedup vs baseline: 1.7599x; 1.0815x over previous
//
#include <hip/hip_runtime.h>
#include <math.h>

#define N_NODES 50000
#define N_EDGES 800000
#define IN_DIM 128
#define HID 256
#define NCLASS 40

#define SCAN_NBLK 49   // ceil(50000 / 1024)
#define CPAD 16        // cursor padded to one int per 64B line

typedef __attribute__((ext_vector_type(8))) short short8;
typedef __attribute__((ext_vector_type(4))) float floatx4;

// ---------- bf16 helpers (RNE pack, cheap unpack) ----------
__device__ inline unsigned bf16pair(float a, float b) {
    unsigned ua = __float_as_uint(a), ub = __float_as_uint(b);
    ua = (ua + 0x7fffu + ((ua >> 16) & 1u)) >> 16;
    ub = (ub + 0x7fffu + ((ub >> 16) & 1u)) >> 16;
    return ua | (ub << 16);
}
__device__ inline unsigned bf16bits(float a) {
    unsigned ua = __float_as_uint(a);
    return (ua + 0x7fffu + ((ua >> 16) & 1u)) >> 16;
}
__device__ inline float bf_lo(unsigned u) { return __uint_as_float(u << 16); }
__device__ inline float bf_hi(unsigned u) { return __uint_as_float(u & 0xffff0000u); }

// ---------------- prep: feats->bf16, edge count, W1 fragment pack (fused) ----------------
__global__ void prep_kernel(const float4* __restrict__ f4,
                            uint2* __restrict__ fb16,
                            const int* __restrict__ rows,
                            int* __restrict__ counts,
                            const float* __restrict__ W1,
                            uint4* __restrict__ W1frag) {
    int i = blockIdx.x * blockDim.x + threadIdx.x;   // < 1.6M
    float4 v = f4[i];
    fb16[i] = make_uint2(bf16pair(v.x, v.y), bf16pair(v.z, v.w));
    if (i < N_EDGES) atomicAdd(&counts[rows[i]], 1);
    if (i < 4096) {
        int f = i;
        int h = f >> 11, rem = f & 2047;
        int t = rem >> 8, s = (rem >> 6) & 3, l = rem & 63;
        int q = l >> 4, n16 = l & 15;
        int n = h * 128 + t * 16 + n16;
        int kb = s * 32 + q * 8;
        unsigned p[4];
        #pragma unroll
        for (int jj = 0; jj < 4; ++jj) {
            float a = W1[(size_t)(kb + 2 * jj) * HID + n];
            float b = W1[(size_t)(kb + 2 * jj + 1) * HID + n];
            p[jj] = bf16pair(a, b);
        }
        W1frag[f] = make_uint4(p[0], p[1], p[2], p[3]);
    }
}

// ---------------- hierarchical scan, phase 1: per-block sums (compact counts) ----------------
__global__ void block_sum_kernel(const int* __restrict__ counts,
                                 int* __restrict__ blockSums) {
    int t = threadIdx.x;
    int base = blockIdx.x * 1024 + t * 4;
    int s = 0;
    if (base < N_NODES) {
        int4 c = *(const int4*)(counts + base);
        s = c.x + c.y + c.z + c.w;
    }
    #pragma unroll
    for (int off = 32; off >= 1; off >>= 1)
        s += __shfl_xor(s, off);
    __shared__ int wsum[4];
    int lane = t & 63, wid = t >> 6;
    if (lane == 0) wsum[wid] = s;
    __syncthreads();
    if (t == 0)
        blockSums[blockIdx.x] = wsum[0] + wsum[1] + wsum[2] + wsum[3];
}

// ---------------- phase 2: scan the 49 block sums (single wave) ----------------
__global__ void block_offset_kernel(const int* __restrict__ blockSums,
                                    int* __restrict__ blockOffs,
                                    int* __restrict__ row_start) {
    int lane = threadIdx.x;          // 64 threads
    int x = (lane < SCAN_NBLK) ? blockSums[lane] : 0;
    #pragma unroll
    for (int off = 1; off < 64; off <<= 1) {
        int y = __shfl_up(x, off);
        if (lane >= off) x += y;
    }
    int excl = __shfl_up(x, 1);
    if (lane == 0) excl = 0;
    if (lane < SCAN_NBLK) blockOffs[lane] = excl;
    if (lane == SCAN_NBLK - 1) row_start[N_NODES] = x;   // grand total
}

// ---------------- phase 3: local scan -> row_start (compact), cursor (padded) ----------------
__global__ void local_scan_kernel(const int* __restrict__ counts,
                                  const int* __restrict__ blockOffs,
                                  int* __restrict__ row_start,
                                  int* __restrict__ cursor) {
    int t = threadIdx.x;
    int base = blockIdx.x * 1024 + t * 4;
    int4 c = make_int4(0, 0, 0, 0);
    if (base < N_NODES) c = *(const int4*)(counts + base);
    int s0 = c.x, s1 = s0 + c.y, s2 = s1 + c.z, s3 = s2 + c.w;
    int tsum = s3;
    int lane = t & 63, wid = t >> 6;
    int x = tsum;
    #pragma unroll
    for (int off = 1; off < 64; off <<= 1) {
        int y = __shfl_up(x, off);
        if (lane >= off) x += y;
    }
    __shared__ int wsum[4];
    if (lane == 63) wsum[wid] = x;
    __syncthreads();
    int woff = 0;
    for (int i = 0; i < 4; ++i)
        if (i < wid) woff += wsum[i];
    int excl = x - tsum + woff + blockOffs[blockIdx.x];
    if (base < N_NODES) {
        int4 rs = make_int4(excl, excl + s0, excl + s1, excl + s2);
        *(int4*)(row_start + base) = rs;
        cursor[(size_t)(base + 0) * CPAD] = rs.x;
        cursor[(size_t)(base + 1) * CPAD] = rs.y;
        cursor[(size_t)(base + 2) * CPAD] = rs.z;
        cursor[(size_t)(base + 3) * CPAD] = rs.w;
    }
}

// ---------------- scatter: 4 edges/thread (independent atomic->store chains) ----------------
__global__ void scatter_kernel(const int* __restrict__ rows,
                               const int* __restrict__ cols,
                               const float* __restrict__ vals,
                               int* __restrict__ cursor,
                               unsigned* __restrict__ csr_cv) {
    int base = blockIdx.x * 1024 + threadIdx.x;
    int e[4], r[4]; unsigned pk[4];
    #pragma unroll
    for (int k = 0; k < 4; ++k) {
        e[k] = base + k * 256;
        if (e[k] < N_EDGES) {
            r[k] = rows[e[k]];
            pk[k] = ((unsigned)cols[e[k]] << 16) | bf16bits(vals[e[k]]);
        }
    }
    int pos[4];
    #pragma unroll
    for (int k = 0; k < 4; ++k)
        if (e[k] < N_EDGES)
            pos[k] = atomicAdd(&cursor[(size_t)r[k] * CPAD], 1);
    #pragma unroll
    for (int k = 0; k < 4; ++k)
        if (e[k] < N_EDGES)
            csr_cv[pos[k]] = pk[k];
}

// ---------------- SpMM (CSR, quarter-wave per edge: 4-edge ILP, 16B gathers) ----------------
// lane = 16p+q: p = edge-of-quad, q = dim group of 8 (one uint4 of Hin row).
// MODE 0: Hout_b[r] = bf16(acc)                              (hop 2)
// MODE 1: Hout_b[r] = bf16(0.5*acc)                          (hop 1, folds input scale)
// MODE 2: Hout_b[r] = bf16(0.5*feats[r] + h1[r] + h2[r] + acc)  (hop 3, y in bf16)
template <int MODE>
__global__ void spmm_csr(const int* __restrict__ row_start,
                         const unsigned* __restrict__ csr_cv,
                         const uint4* __restrict__ Hin4,
                         uint4* __restrict__ Hout4,
                         const float* __restrict__ feats,
                         const uint4* __restrict__ h1b4,
                         const uint4* __restrict__ h2b4) {
    int wave = (blockIdx.x * blockDim.x + threadIdx.x) >> 6;
    int lane = threadIdx.x & 63;
    if (wave >= N_NODES) return;
    int p = lane >> 4;          // 0..3: which edge of the quad
    int q = lane & 15;          // dim group (8 dims = one uint4)
    int start = row_start[wave];
    int end   = row_start[wave + 1];
    float acc[8] = {};
    for (int base = start; base < end; base += 64) {
        int idx = base + lane;
        unsigned u = 0;                         // col=0, val=+0.0
        if (idx < end) u = csr_cv[idx];
        int cnt = min(64, end - base);
        for (int j = 0; j < cnt; j += 4) {
            unsigned uj = __shfl(u, j + p);     // j+p <= 63 always; val=0 beyond cnt
            int   cj = uj >> 16;
            float vj = __uint_as_float(uj << 16);
            uint4 h = Hin4[(size_t)cj * 16 + q];   // 8 bf16 = 16 B
            acc[0] += vj * bf_lo(h.x);
            acc[1] += vj * bf_hi(h.x);
            acc[2] += vj * bf_lo(h.y);
            acc[3] += vj * bf_hi(h.y);
            acc[4] += vj * bf_lo(h.z);
            acc[5] += vj * bf_hi(h.z);
            acc[6] += vj * bf_lo(h.w);
            acc[7] += vj * bf_hi(h.w);
        }
    }
    // reduce the 4 edge-subsets (lanes differing in bits 4..5)
    #pragma unroll
    for (int i = 0; i < 8; ++i) {
        acc[i] += __shfl_xor(acc[i], 16);
        acc[i] += __shfl_xor(acc[i], 32);
    }
    if (p == 0) {
        size_t o16 = (size_t)wave * 16 + q;
        if (MODE == 1) {
            #pragma unroll
            for (int i = 0; i < 8; ++i) acc[i] *= 0.5f;
        } else if (MODE == 2) {
            size_t of = (size_t)wave * IN_DIM + q * 8;
            float4 f0 = *(const float4*)(feats + of);
            float4 f1 = *(const float4*)(feats + of + 4);
            uint4 a = h1b4[o16];
            uint4 b = h2b4[o16];
            acc[0] += 0.5f * f0.x + bf_lo(a.x) + bf_lo(b.x);
            acc[1] += 0.5f * f0.y + bf_hi(a.x) + bf_hi(b.x);
            acc[2] += 0.5f * f0.z + bf_lo(a.y) + bf_lo(b.y);
            acc[3] += 0.5f * f0.w + bf_hi(a.y) + bf_hi(b.y);
            acc[4] += 0.5f * f1.x + bf_lo(a.z) + bf_lo(b.z);
            acc[5] += 0.5f * f1.y + bf_hi(a.z) + bf_hi(b.z);
            acc[6] += 0.5f * f1.z + bf_lo(a.w) + bf_lo(b.w);
            acc[7] += 0.5f * f1.w + bf_hi(a.w) + bf_hi(b.w);
        }
        Hout4[o16] = make_uint4(bf16pair(acc[0], acc[1]), bf16pair(acc[2], acc[3]),
                                bf16pair(acc[4], acc[5]), bf16pair(acc[6], acc[7]));
    }
}

// ---------------- GEMM1 (MFMA): H1 = relu(0.25*(ybf16 @ W1) + b1) ----------------
__global__ void gemm1_mfma(const uint4* __restrict__ yb4,
                           const uint4* __restrict__ W1frag,
                           const float* __restrict__ bias1,
                           float* __restrict__ H1) {
    __shared__ uint4 wlds[2048];   // 32 KB: this block's N-half of W1 fragments
    int tid = threadIdx.x;
    int h = blockIdx.y;
    for (int i = tid; i < 2048; i += 256)
        wlds[i] = W1frag[h * 2048 + i];
    __syncthreads();

    int wave = tid >> 6, lane = tid & 63;
    int q = lane >> 4, c16 = lane & 15;
    int row0 = blockIdx.x * 64 + wave * 16;
    int arow = row0 + c16;

    union { uint4 u; short8 v; } au[4], bu;
    if (arow < N_NODES) {
        #pragma unroll
        for (int s = 0; s < 4; ++s)
            au[s].u = yb4[(size_t)arow * 16 + 4 * s + q];
    } else {
        #pragma unroll
        for (int s = 0; s < 4; ++s)
            au[s].u = make_uint4(0u, 0u, 0u, 0u);
    }

    #pragma unroll
    for (int t = 0; t < 8; ++t) {
        floatx4 acc = {0.f, 0.f, 0.f, 0.f};
        #pragma unroll
        for (int s = 0; s < 4; ++s) {
            bu.u = wlds[(t * 4 + s) * 64 + lane];
            acc = __builtin_amdgcn_mfma_f32_16x16x32_bf16(au[s].v, bu.v, acc, 0, 0, 0);
        }
        int col = h * 128 + t * 16 + c16;
        float bs = bias1[col];
        #pragma unroll
        for (int r = 0; r < 4; ++r) {
            int crow = row0 + q * 4 + r;
            if (crow < N_NODES) {
                float v = 0.25f * acc[r] + bs;
                H1[(size_t)crow * HID + col] = v > 0.f ? v : 0.f;
            }
        }
    }
}

// ---------------- GEMM2 (K-split x2): partial = H1[:, khalf] @ W2[khalf, :] ----------------
#define G2_BM 128
#define G2_BK 32
__global__ void gemm2_kernel(const float* __restrict__ H1,
                             const float* __restrict__ W2,
                             float* __restrict__ part0,
                             float* __restrict__ part1) {
    __shared__ float As[G2_BK][G2_BM + 4];   // transposed A
    __shared__ float Bs[G2_BK][44];          // 32 x 40, row pad to 44
    int tid = threadIdx.x;                   // 256
    int rt = tid >> 3;                       // 0..31, 4 rows each
    int ct = tid & 7;                        // 0..7, 5 cols each
    int row0 = blockIdx.x * G2_BM;
    int kbase = blockIdx.y * (HID / 2);      // 0 or 128
    float* outp = blockIdx.y ? part1 : part0;
    float acc[4][5] = {};
    for (int kt = 0; kt < HID / 2; kt += G2_BK) {    // 4 k-tiles
        int k0 = kbase + kt;
        #pragma unroll
        for (int i = tid; i < 1024; i += 256) {
            int r = i >> 3, u = i & 7;
            int gr = row0 + r;
            float4 v = make_float4(0.f, 0.f, 0.f, 0.f);
            if (gr < N_NODES)
                v = *(const float4*)(H1 + (size_t)gr * HID + k0 + u * 4);
            int kb = u * 4;
            As[kb + 0][r] = v.x;
            As[kb + 1][r] = v.y;
            As[kb + 2][r] = v.z;
            As[kb + 3][r] = v.w;
        }
        for (int i = tid; i < 320; i += 256) {
            int r = i / 10, cg = i % 10;
            float4 w = *(const float4*)(W2 + (size_t)(k0 + r) * NCLASS + cg * 4);
            *(float4*)&Bs[r][cg * 4] = w;
        }
        __syncthreads();
        #pragma unroll
        for (int kk = 0; kk < G2_BK; ++kk) {
            float4 a0 = *(const float4*)&As[kk][rt * 4];
            float a[4] = {a0.x, a0.y, a0.z, a0.w};
            float b[5];
            #pragma unroll
            for (int j = 0; j < 5; ++j) b[j] = Bs[kk][ct * 5 + j];
            #pragma unroll
            for (int i = 0; i < 4; ++i)
                #pragma unroll
                for (int j = 0; j < 5; ++j)
                    acc[i][j] += a[i] * b[j];
        }
        __syncthreads();
    }
    #pragma unroll
    for (int i = 0; i < 4; ++i) {
        int gr = row0 + rt * 4 + i;
        if (gr >= N_NODES) continue;
        float* dst = outp + (size_t)gr * NCLASS + ct * 5;
        #pragma unroll
        for (int j = 0; j < 5; ++j)
            dst[j] = acc[i][j];
    }
}

// ---------------- double log_softmax (sums K-split partials + bias) ----------------
__global__ void lsm_kernel(const float* __restrict__ part0,
                           const float* __restrict__ part1,
                           const float* __restrict__ b2,
                           float* __restrict__ Out) {
    int wave = threadIdx.x >> 6;
    int lane = threadIdx.x & 63;
    int row = blockIdx.x * 4 + wave;
    if (row >= N_NODES) return;

    float acc = -INFINITY;
    if (lane < NCLASS) {
        size_t idx = (size_t)row * NCLASS + lane;
        acc = part0[idx] + part1[idx] + b2[lane];
    }

    float m = acc;
    #pragma unroll
    for (int off = 32; off >= 1; off >>= 1)
        m = fmaxf(m, __shfl_xor(m, off));
    float ex = (lane < NCLASS) ? expf(acc - m) : 0.f;
    float s = ex;
    #pragma unroll
    for (int off = 32; off >= 1; off >>= 1)
        s += __shfl_xor(s, off);
    float z1 = acc - (m + logf(s));

    float m2 = z1;
    #pragma unroll
    for (int off = 32; off >= 1; off >>= 1)
        m2 = fmaxf(m2, __shfl_xor(m2, off));
    float ex2 = (lane < NCLASS) ? expf(z1 - m2) : 0.f;
    float s2 = ex2;
    #pragma unroll
    for (int off = 32; off >= 1; off >>= 1)
        s2 += __shfl_xor(s2, off);
    float z2 = z1 - (m2 + logf(s2));

    if (lane < NCLASS)
        Out[(size_t)row * NCLASS + lane] = z2;
}

extern "C" void kernel_launch(void* const* d_in, const int* in_sizes, int n_in,
                              void* d_out, int out_size, void* d_ws, size_t ws_size,
                              hipStream_t stream) {
    const float* feats   = (const float*)d_in[0];
    const int*   e_row   = (const int*)d_in[1];
    const int*   e_col   = (const int*)d_in[2];
    const float* e_vals  = (const float*)d_in[3];
    const float* W1      = (const float*)d_in[4];
    const float* b1      = (const float*)d_in[5];
    const float* W2      = (const float*)d_in[6];
    const float* b2      = (const float*)d_in[7];
    float* out = (float*)d_out;

    // Workspace (19.2M floats proven):
    //   ybf   : [0, 3.2M)           y in bf16 (MLP input, written by hop3)
    //   W1frag: [3.2M, 3.216M)      W1 bf16 MFMA fragments (64 KB)
    //   fb16  : [6.4M, 9.6M)        feats in bf16
    //   h1b   : [9.6M, 12.8M)       hop1 out, bf16
    //   h2b   : [12.8M, 16M)        hop2 out, bf16
    //   counts: [16M, 16.05M)       compact counters (dead after scan)
    //   cursor: [16.8M, 17.6M)      line-padded cursors (dead after scatter)
    //   hid   : [6.4M, 19.2M)       gemm1 out fp32 (all above dead by then)
    //   part0 : [0, 2M)  part1: [2M, 4M)
    float* ws    = (float*)d_ws;
    uint4* ybf4  = (uint4*)ws;
    uint4* W1frag = (uint4*)(ws + (size_t)N_NODES * IN_DIM / 2);
    uint4* fb16_4 = (uint4*)(ws + (size_t)N_NODES * IN_DIM);
    uint4* h1b4  = (uint4*)(ws + (size_t)N_NODES * IN_DIM * 3 / 2);
    uint4* h2b4  = (uint4*)(ws + (size_t)N_NODES * IN_DIM * 2);
    int*   counts = (int*)(ws + (size_t)N_NODES * IN_DIM * 5 / 2);   // 16M
    int*   cursor = counts + 800000;                                 // 16.8M
    float* hid   = ws + (size_t)N_NODES * IN_DIM;
    float* part0 = ws;
    float* part1 = ws + (size_t)N_NODES * NCLASS;

    // CSR scratch in d_out (8 MB; fully overwritten by lsm_kernel at the end).
    unsigned* csr_cv = (unsigned*)d_out;                 // packed (col<<16)|bf16(val), 800000
    int*   row_start = (int*)d_out + 2 * N_EDGES;        // [1600000, 1650001)
    int*   blockSums = row_start + N_NODES + 4;
    int*   blockOffs = blockSums + 64;                   // < 2000000

    // zero compact counts (200 KB)
    hipMemsetAsync(counts, 0, N_NODES * sizeof(int), stream);

    // prep: feats->bf16 + edge count + W1 fragment pack
    const int ELEMS4 = N_NODES * IN_DIM / 4;  // 1.6M float4s
    prep_kernel<<<ELEMS4 / 256, 256, 0, stream>>>((const float4*)feats, (uint2*)fb16_4,
                                                  e_row, counts, W1, W1frag);

    // Hierarchical scan -> row_start (compact) + cursor (padded)
    block_sum_kernel<<<SCAN_NBLK, 256, 0, stream>>>(counts, blockSums);
    block_offset_kernel<<<1, 64, 0, stream>>>(blockSums, blockOffs, row_start);
    local_scan_kernel<<<SCAN_NBLK, 256, 0, stream>>>(counts, blockOffs, row_start, cursor);

    // scatter: 4 edges per thread
    scatter_kernel<<<(N_EDGES + 1023) / 1024, 256, 0, stream>>>(e_row, e_col, e_vals,
                                                                cursor, csr_cv);

    // 3 propagation hops (quarter-wave per edge, 16B gathers; hop3 emits bf16 y)
    const int SPMM_BLOCKS = N_NODES / 4;      // 12500 (4 waves/block)
    spmm_csr<1><<<SPMM_BLOCKS, 256, 0, stream>>>(row_start, csr_cv, fb16_4, h1b4,
                                                 nullptr, nullptr, nullptr);
    spmm_csr<0><<<SPMM_BLOCKS, 256, 0, stream>>>(row_start, csr_cv, h1b4, h2b4,
                                                 nullptr, nullptr, nullptr);
    spmm_csr<2><<<SPMM_BLOCKS, 256, 0, stream>>>(row_start, csr_cv, h2b4, ybf4,
                                                 feats, h1b4, h2b4);

    // GEMM1 (MFMA): hid = relu(0.25*(ybf @ W1) + b1)
    dim3 g1((N_NODES + 63) / 64, 2);          // (782, 2)
    gemm1_mfma<<<g1, 256, 0, stream>>>(ybf4, W1frag, b1, hid);

    // GEMM2 (K-split x2): partials into dead y region
    dim3 g2((N_NODES + G2_BM - 1) / G2_BM, 2);        // (391, 2)
    gemm2_kernel<<<g2, 256, 0, stream>>>(hid, W2, part0, part1);

    // double log_softmax (sums partials + bias) -> out
    lsm_kernel<<<(N_NODES + 3) / 4, 256, 0, stream>>>(part0, part1, b2, out);
}

// Round 18
// 316.484 us; speedup vs baseline: 1.7996x; 1.0225x over previous
//
#include <hip/hip_runtime.h>
#include <math.h>

#define N_NODES 50000
#define N_EDGES 800000
#define IN_DIM 128
#define HID 256
#define NCLASS 40

#define SCAN_NBLK 49   // ceil(50000 / 1024)
#define CPAD 16        // cursor padded to one int per 64B line

typedef __attribute__((ext_vector_type(8))) short short8;
typedef __attribute__((ext_vector_type(4))) float floatx4;

// ---------- bf16 helpers (RNE pack, cheap unpack) ----------
__device__ inline unsigned bf16pair(float a, float b) {
    unsigned ua = __float_as_uint(a), ub = __float_as_uint(b);
    ua = (ua + 0x7fffu + ((ua >> 16) & 1u)) >> 16;
    ub = (ub + 0x7fffu + ((ub >> 16) & 1u)) >> 16;
    return ua | (ub << 16);
}
__device__ inline unsigned bf16bits(float a) {
    unsigned ua = __float_as_uint(a);
    return (ua + 0x7fffu + ((ua >> 16) & 1u)) >> 16;
}
__device__ inline float bf_lo(unsigned u) { return __uint_as_float(u << 16); }
__device__ inline float bf_hi(unsigned u) { return __uint_as_float(u & 0xffff0000u); }

// ---------------- prep: feats->bf16, edge count, W1 fragment pack (fused) ----------------
__global__ void prep_kernel(const float4* __restrict__ f4,
                            uint2* __restrict__ fb16,
                            const int* __restrict__ rows,
                            int* __restrict__ counts,
                            const float* __restrict__ W1,
                            uint4* __restrict__ W1frag) {
    int i = blockIdx.x * blockDim.x + threadIdx.x;   // < 1.6M
    float4 v = f4[i];
    fb16[i] = make_uint2(bf16pair(v.x, v.y), bf16pair(v.z, v.w));
    if (i < N_EDGES) atomicAdd(&counts[rows[i]], 1);
    if (i < 4096) {
        int f = i;
        int h = f >> 11, rem = f & 2047;
        int t = rem >> 8, s = (rem >> 6) & 3, l = rem & 63;
        int q = l >> 4, n16 = l & 15;
        int n = h * 128 + t * 16 + n16;
        int kb = s * 32 + q * 8;
        unsigned p[4];
        #pragma unroll
        for (int jj = 0; jj < 4; ++jj) {
            float a = W1[(size_t)(kb + 2 * jj) * HID + n];
            float b = W1[(size_t)(kb + 2 * jj + 1) * HID + n];
            p[jj] = bf16pair(a, b);
        }
        W1frag[f] = make_uint4(p[0], p[1], p[2], p[3]);
    }
}

// ---------------- hierarchical scan, phase 1: per-block sums ----------------
__global__ void block_sum_kernel(const int* __restrict__ counts,
                                 int* __restrict__ blockSums) {
    int t = threadIdx.x;
    int base = blockIdx.x * 1024 + t * 4;
    int s = 0;
    if (base < N_NODES) {
        int4 c = *(const int4*)(counts + base);
        s = c.x + c.y + c.z + c.w;
    }
    #pragma unroll
    for (int off = 32; off >= 1; off >>= 1)
        s += __shfl_xor(s, off);
    __shared__ int wsum[4];
    int lane = t & 63, wid = t >> 6;
    if (lane == 0) wsum[wid] = s;
    __syncthreads();
    if (t == 0)
        blockSums[blockIdx.x] = wsum[0] + wsum[1] + wsum[2] + wsum[3];
}

// ---------------- phase 2: scan the 49 block sums (single wave) ----------------
__global__ void block_offset_kernel(const int* __restrict__ blockSums,
                                    int* __restrict__ blockOffs,
                                    int* __restrict__ row_start) {
    int lane = threadIdx.x;          // 64 threads
    int x = (lane < SCAN_NBLK) ? blockSums[lane] : 0;
    #pragma unroll
    for (int off = 1; off < 64; off <<= 1) {
        int y = __shfl_up(x, off);
        if (lane >= off) x += y;
    }
    int excl = __shfl_up(x, 1);
    if (lane == 0) excl = 0;
    if (lane < SCAN_NBLK) blockOffs[lane] = excl;
    if (lane == SCAN_NBLK - 1) row_start[N_NODES] = x;   // grand total
}

// ---------------- phase 3: local scan -> row_start (compact), cursor (padded) ----------------
__global__ void local_scan_kernel(const int* __restrict__ counts,
                                  const int* __restrict__ blockOffs,
                                  int* __restrict__ row_start,
                                  int* __restrict__ cursor) {
    int t = threadIdx.x;
    int base = blockIdx.x * 1024 + t * 4;
    int4 c = make_int4(0, 0, 0, 0);
    if (base < N_NODES) c = *(const int4*)(counts + base);
    int s0 = c.x, s1 = s0 + c.y, s2 = s1 + c.z, s3 = s2 + c.w;
    int tsum = s3;
    int lane = t & 63, wid = t >> 6;
    int x = tsum;
    #pragma unroll
    for (int off = 1; off < 64; off <<= 1) {
        int y = __shfl_up(x, off);
        if (lane >= off) x += y;
    }
    __shared__ int wsum[4];
    if (lane == 63) wsum[wid] = x;
    __syncthreads();
    int woff = 0;
    for (int i = 0; i < 4; ++i)
        if (i < wid) woff += wsum[i];
    int excl = x - tsum + woff + blockOffs[blockIdx.x];
    if (base < N_NODES) {
        int4 rs = make_int4(excl, excl + s0, excl + s1, excl + s2);
        *(int4*)(row_start + base) = rs;
        cursor[(size_t)(base + 0) * CPAD] = rs.x;
        cursor[(size_t)(base + 1) * CPAD] = rs.y;
        cursor[(size_t)(base + 2) * CPAD] = rs.z;
        cursor[(size_t)(base + 3) * CPAD] = rs.w;
    }
}

// ---------------- scatter: 8 edges/thread (independent atomic->store chains) ----------------
__global__ void scatter_kernel(const int* __restrict__ rows,
                               const int* __restrict__ cols,
                               const float* __restrict__ vals,
                               int* __restrict__ cursor,
                               unsigned* __restrict__ csr_cv) {
    int base = blockIdx.x * 2048 + threadIdx.x;
    int e[8], r[8]; unsigned pk[8];
    #pragma unroll
    for (int k = 0; k < 8; ++k) {
        e[k] = base + k * 256;
        if (e[k] < N_EDGES) {
            r[k] = rows[e[k]];
            pk[k] = ((unsigned)cols[e[k]] << 16) | bf16bits(vals[e[k]]);
        }
    }
    int pos[8];
    #pragma unroll
    for (int k = 0; k < 8; ++k)
        if (e[k] < N_EDGES)
            pos[k] = atomicAdd(&cursor[(size_t)r[k] * CPAD], 1);
    #pragma unroll
    for (int k = 0; k < 8; ++k)
        if (e[k] < N_EDGES)
            csr_cv[pos[k]] = pk[k];
}

// ---------------- SpMM (CSR, quarter-wave per edge, 8-edge unrolled gathers) ----------------
// lane = 16p+q: p = edge-of-quad, q = dim group of 8 (one uint4 of Hin row).
// Inner loop handles 8 edges (2 quads) per iteration: two independent
// shuffle->gather chains in flight. val=0 padding beyond cnt makes over-run safe.
// MODE 0: Hout_b[r] = bf16(acc)                              (hop 2)
// MODE 1: Hout_b[r] = bf16(0.5*acc)                          (hop 1, folds input scale)
// MODE 2: Hout_b[r] = bf16(0.5*feats[r] + h1[r] + h2[r] + acc)  (hop 3, y in bf16)
template <int MODE>
__global__ void spmm_csr(const int* __restrict__ row_start,
                         const unsigned* __restrict__ csr_cv,
                         const uint4* __restrict__ Hin4,
                         uint4* __restrict__ Hout4,
                         const float* __restrict__ feats,
                         const uint4* __restrict__ h1b4,
                         const uint4* __restrict__ h2b4) {
    int wave = (blockIdx.x * blockDim.x + threadIdx.x) >> 6;
    int lane = threadIdx.x & 63;
    if (wave >= N_NODES) return;
    int p = lane >> 4;          // 0..3: which edge of the quad
    int q = lane & 15;          // dim group (8 dims = one uint4)
    int start = row_start[wave];
    int end   = row_start[wave + 1];
    float acc[8] = {};
    for (int base = start; base < end; base += 64) {
        int idx = base + lane;
        unsigned u = 0;                         // col=0, val=+0.0
        if (idx < end) u = csr_cv[idx];
        int cnt = min(64, end - base);
        for (int j = 0; j < cnt; j += 8) {
            unsigned uj0 = __shfl(u, j + p);        // <= 59+3? j<=56: ok
            unsigned uj1 = __shfl(u, j + 4 + p);    // <= 63: ok; val=0 beyond cnt
            int   c0 = uj0 >> 16;
            int   c1 = uj1 >> 16;
            float v0 = __uint_as_float(uj0 << 16);
            float v1 = __uint_as_float(uj1 << 16);
            uint4 h0 = Hin4[(size_t)c0 * 16 + q];   // independent gathers
            uint4 h1 = Hin4[(size_t)c1 * 16 + q];
            acc[0] += v0 * bf_lo(h0.x);
            acc[1] += v0 * bf_hi(h0.x);
            acc[2] += v0 * bf_lo(h0.y);
            acc[3] += v0 * bf_hi(h0.y);
            acc[4] += v0 * bf_lo(h0.z);
            acc[5] += v0 * bf_hi(h0.z);
            acc[6] += v0 * bf_lo(h0.w);
            acc[7] += v0 * bf_hi(h0.w);
            acc[0] += v1 * bf_lo(h1.x);
            acc[1] += v1 * bf_hi(h1.x);
            acc[2] += v1 * bf_lo(h1.y);
            acc[3] += v1 * bf_hi(h1.y);
            acc[4] += v1 * bf_lo(h1.z);
            acc[5] += v1 * bf_hi(h1.z);
            acc[6] += v1 * bf_lo(h1.w);
            acc[7] += v1 * bf_hi(h1.w);
        }
    }
    // reduce the 4 edge-subsets (lanes differing in bits 4..5)
    #pragma unroll
    for (int i = 0; i < 8; ++i) {
        acc[i] += __shfl_xor(acc[i], 16);
        acc[i] += __shfl_xor(acc[i], 32);
    }
    if (p == 0) {
        size_t o16 = (size_t)wave * 16 + q;
        if (MODE == 1) {
            #pragma unroll
            for (int i = 0; i < 8; ++i) acc[i] *= 0.5f;
        } else if (MODE == 2) {
            size_t of = (size_t)wave * IN_DIM + q * 8;
            float4 f0 = *(const float4*)(feats + of);
            float4 f1 = *(const float4*)(feats + of + 4);
            uint4 a = h1b4[o16];
            uint4 b = h2b4[o16];
            acc[0] += 0.5f * f0.x + bf_lo(a.x) + bf_lo(b.x);
            acc[1] += 0.5f * f0.y + bf_hi(a.x) + bf_hi(b.x);
            acc[2] += 0.5f * f0.z + bf_lo(a.y) + bf_lo(b.y);
            acc[3] += 0.5f * f0.w + bf_hi(a.y) + bf_hi(b.y);
            acc[4] += 0.5f * f1.x + bf_lo(a.z) + bf_lo(b.z);
            acc[5] += 0.5f * f1.y + bf_hi(a.z) + bf_hi(b.z);
            acc[6] += 0.5f * f1.z + bf_lo(a.w) + bf_lo(b.w);
            acc[7] += 0.5f * f1.w + bf_hi(a.w) + bf_hi(b.w);
        }
        Hout4[o16] = make_uint4(bf16pair(acc[0], acc[1]), bf16pair(acc[2], acc[3]),
                                bf16pair(acc[4], acc[5]), bf16pair(acc[6], acc[7]));
    }
}

// ---------------- GEMM1 (MFMA): H1 = relu(0.25*(ybf16 @ W1) + b1) ----------------
__global__ void gemm1_mfma(const uint4* __restrict__ yb4,
                           const uint4* __restrict__ W1frag,
                           const float* __restrict__ bias1,
                           float* __restrict__ H1) {
    __shared__ uint4 wlds[2048];   // 32 KB: this block's N-half of W1 fragments
    int tid = threadIdx.x;
    int h = blockIdx.y;
    for (int i = tid; i < 2048; i += 256)
        wlds[i] = W1frag[h * 2048 + i];
    __syncthreads();

    int wave = tid >> 6, lane = tid & 63;
    int q = lane >> 4, c16 = lane & 15;
    int row0 = blockIdx.x * 64 + wave * 16;
    int arow = row0 + c16;

    union { uint4 u; short8 v; } au[4], bu;
    if (arow < N_NODES) {
        #pragma unroll
        for (int s = 0; s < 4; ++s)
            au[s].u = yb4[(size_t)arow * 16 + 4 * s + q];
    } else {
        #pragma unroll
        for (int s = 0; s < 4; ++s)
            au[s].u = make_uint4(0u, 0u, 0u, 0u);
    }

    #pragma unroll
    for (int t = 0; t < 8; ++t) {
        floatx4 acc = {0.f, 0.f, 0.f, 0.f};
        #pragma unroll
        for (int s = 0; s < 4; ++s) {
            bu.u = wlds[(t * 4 + s) * 64 + lane];
            acc = __builtin_amdgcn_mfma_f32_16x16x32_bf16(au[s].v, bu.v, acc, 0, 0, 0);
        }
        int col = h * 128 + t * 16 + c16;
        float bs = bias1[col];
        #pragma unroll
        for (int r = 0; r < 4; ++r) {
            int crow = row0 + q * 4 + r;
            if (crow < N_NODES) {
                float v = 0.25f * acc[r] + bs;
                H1[(size_t)crow * HID + col] = v > 0.f ? v : 0.f;
            }
        }
    }
}

// ---------------- GEMM2 (K-split x2): partial = H1[:, khalf] @ W2[khalf, :] ----------------
#define G2_BM 128
#define G2_BK 32
__global__ void gemm2_kernel(const float* __restrict__ H1,
                             const float* __restrict__ W2,
                             float* __restrict__ part0,
                             float* __restrict__ part1) {
    __shared__ float As[G2_BK][G2_BM + 4];   // transposed A
    __shared__ float Bs[G2_BK][44];          // 32 x 40, row pad to 44
    int tid = threadIdx.x;                   // 256
    int rt = tid >> 3;                       // 0..31, 4 rows each
    int ct = tid & 7;                        // 0..7, 5 cols each
    int row0 = blockIdx.x * G2_BM;
    int kbase = blockIdx.y * (HID / 2);      // 0 or 128
    float* outp = blockIdx.y ? part1 : part0;
    float acc[4][5] = {};
    for (int kt = 0; kt < HID / 2; kt += G2_BK) {    // 4 k-tiles
        int k0 = kbase + kt;
        #pragma unroll
        for (int i = tid; i < 1024; i += 256) {
            int r = i >> 3, u = i & 7;
            int gr = row0 + r;
            float4 v = make_float4(0.f, 0.f, 0.f, 0.f);
            if (gr < N_NODES)
                v = *(const float4*)(H1 + (size_t)gr * HID + k0 + u * 4);
            int kb = u * 4;
            As[kb + 0][r] = v.x;
            As[kb + 1][r] = v.y;
            As[kb + 2][r] = v.z;
            As[kb + 3][r] = v.w;
        }
        for (int i = tid; i < 320; i += 256) {
            int r = i / 10, cg = i % 10;
            float4 w = *(const float4*)(W2 + (size_t)(k0 + r) * NCLASS + cg * 4);
            *(float4*)&Bs[r][cg * 4] = w;
        }
        __syncthreads();
        #pragma unroll
        for (int kk = 0; kk < G2_BK; ++kk) {
            float4 a0 = *(const float4*)&As[kk][rt * 4];
            float a[4] = {a0.x, a0.y, a0.z, a0.w};
            float b[5];
            #pragma unroll
            for (int j = 0; j < 5; ++j) b[j] = Bs[kk][ct * 5 + j];
            #pragma unroll
            for (int i = 0; i < 4; ++i)
                #pragma unroll
                for (int j = 0; j < 5; ++j)
                    acc[i][j] += a[i] * b[j];
        }
        __syncthreads();
    }
    #pragma unroll
    for (int i = 0; i < 4; ++i) {
        int gr = row0 + rt * 4 + i;
        if (gr >= N_NODES) continue;
        float* dst = outp + (size_t)gr * NCLASS + ct * 5;
        #pragma unroll
        for (int j = 0; j < 5; ++j)
            dst[j] = acc[i][j];
    }
}

// ---------------- double log_softmax (sums K-split partials + bias) ----------------
__global__ void lsm_kernel(const float* __restrict__ part0,
                           const float* __restrict__ part1,
                           const float* __restrict__ b2,
                           float* __restrict__ Out) {
    int wave = threadIdx.x >> 6;
    int lane = threadIdx.x & 63;
    int row = blockIdx.x * 4 + wave;
    if (row >= N_NODES) return;

    float acc = -INFINITY;
    if (lane < NCLASS) {
        size_t idx = (size_t)row * NCLASS + lane;
        acc = part0[idx] + part1[idx] + b2[lane];
    }

    float m = acc;
    #pragma unroll
    for (int off = 32; off >= 1; off >>= 1)
        m = fmaxf(m, __shfl_xor(m, off));
    float ex = (lane < NCLASS) ? expf(acc - m) : 0.f;
    float s = ex;
    #pragma unroll
    for (int off = 32; off >= 1; off >>= 1)
        s += __shfl_xor(s, off);
    float z1 = acc - (m + logf(s));

    float m2 = z1;
    #pragma unroll
    for (int off = 32; off >= 1; off >>= 1)
        m2 = fmaxf(m2, __shfl_xor(m2, off));
    float ex2 = (lane < NCLASS) ? expf(z1 - m2) : 0.f;
    float s2 = ex2;
    #pragma unroll
    for (int off = 32; off >= 1; off >>= 1)
        s2 += __shfl_xor(s2, off);
    float z2 = z1 - (m2 + logf(s2));

    if (lane < NCLASS)
        Out[(size_t)row * NCLASS + lane] = z2;
}

extern "C" void kernel_launch(void* const* d_in, const int* in_sizes, int n_in,
                              void* d_out, int out_size, void* d_ws, size_t ws_size,
                              hipStream_t stream) {
    const float* feats   = (const float*)d_in[0];
    const int*   e_row   = (const int*)d_in[1];
    const int*   e_col   = (const int*)d_in[2];
    const float* e_vals  = (const float*)d_in[3];
    const float* W1      = (const float*)d_in[4];
    const float* b1      = (const float*)d_in[5];
    const float* W2      = (const float*)d_in[6];
    const float* b2      = (const float*)d_in[7];
    float* out = (float*)d_out;

    // Workspace (19.2M floats proven):
    //   ybf   : [0, 3.2M)           y in bf16 (MLP input, written by hop3)
    //   W1frag: [3.2M, 3.216M)      W1 bf16 MFMA fragments (64 KB)
    //   fb16  : [6.4M, 9.6M)        feats in bf16
    //   h1b   : [9.6M, 12.8M)       hop1 out, bf16
    //   h2b   : [12.8M, 16M)        hop2 out, bf16
    //   counts: [16M, 16.05M)       compact counters (dead after scan)
    //   cursor: [16.8M, 17.6M)      line-padded cursors (dead after scatter)
    //   hid   : [6.4M, 19.2M)       gemm1 out fp32 (all above dead by then)
    //   part0 : [0, 2M)  part1: [2M, 4M)
    float* ws    = (float*)d_ws;
    uint4* ybf4  = (uint4*)ws;
    uint4* W1frag = (uint4*)(ws + (size_t)N_NODES * IN_DIM / 2);
    uint4* fb16_4 = (uint4*)(ws + (size_t)N_NODES * IN_DIM);
    uint4* h1b4  = (uint4*)(ws + (size_t)N_NODES * IN_DIM * 3 / 2);
    uint4* h2b4  = (uint4*)(ws + (size_t)N_NODES * IN_DIM * 2);
    int*   counts = (int*)(ws + (size_t)N_NODES * IN_DIM * 5 / 2);   // 16M
    int*   cursor = counts + 800000;                                 // 16.8M
    float* hid   = ws + (size_t)N_NODES * IN_DIM;
    float* part0 = ws;
    float* part1 = ws + (size_t)N_NODES * NCLASS;

    // CSR scratch in d_out (8 MB; fully overwritten by lsm_kernel at the end).
    unsigned* csr_cv = (unsigned*)d_out;                 // packed (col<<16)|bf16(val), 800000
    int*   row_start = (int*)d_out + 2 * N_EDGES;        // [1600000, 1650001)
    int*   blockSums = row_start + N_NODES + 4;
    int*   blockOffs = blockSums + 64;                   // < 2000000

    // zero compact counts (200 KB)
    hipMemsetAsync(counts, 0, N_NODES * sizeof(int), stream);

    // prep: feats->bf16 + edge count + W1 fragment pack
    const int ELEMS4 = N_NODES * IN_DIM / 4;  // 1.6M float4s
    prep_kernel<<<ELEMS4 / 256, 256, 0, stream>>>((const float4*)feats, (uint2*)fb16_4,
                                                  e_row, counts, W1, W1frag);

    // Hierarchical scan -> row_start (compact) + cursor (padded)
    block_sum_kernel<<<SCAN_NBLK, 256, 0, stream>>>(counts, blockSums);
    block_offset_kernel<<<1, 64, 0, stream>>>(blockSums, blockOffs, row_start);
    local_scan_kernel<<<SCAN_NBLK, 256, 0, stream>>>(counts, blockOffs, row_start, cursor);

    // scatter: 8 edges per thread
    scatter_kernel<<<(N_EDGES + 2047) / 2048, 256, 0, stream>>>(e_row, e_col, e_vals,
                                                                cursor, csr_cv);

    // 3 propagation hops (quarter-wave per edge, 8-edge unrolled; hop3 emits bf16 y)
    const int SPMM_BLOCKS = N_NODES / 4;      // 12500 (4 waves/block)
    spmm_csr<1><<<SPMM_BLOCKS, 256, 0, stream>>>(row_start, csr_cv, fb16_4, h1b4,
                                                 nullptr, nullptr, nullptr);
    spmm_csr<0><<<SPMM_BLOCKS, 256, 0, stream>>>(row_start, csr_cv, h1b4, h2b4,
                                                 nullptr, nullptr, nullptr);
    spmm_csr<2><<<SPMM_BLOCKS, 256, 0, stream>>>(row_start, csr_cv, h2b4, ybf4,
                                                 feats, h1b4, h2b4);

    // GEMM1 (MFMA): hid = relu(0.25*(ybf @ W1) + b1)
    dim3 g1((N_NODES + 63) / 64, 2);          // (782, 2)
    gemm1_mfma<<<g1, 256, 0, stream>>>(ybf4, W1frag, b1, hid);

    // GEMM2 (K-split x2): partials into dead y region
    dim3 g2((N_NODES + G2_BM - 1) / G2_BM, 2);        // (391, 2)
    gemm2_kernel<<<g2, 256, 0, stream>>>(hid, W2, part0, part1);

    // double log_softmax (sums partials + bias) -> out
    lsm_kernel<<<(N_NODES + 3) / 4, 256, 0, stream>>>(part0, part1, b2, out);
}